// Round 10
// baseline (1166.797 us; speedup 1.0000x reference)
//
#include <hip/hip_runtime.h>
#include <hip/hip_bf16.h>
#include <math.h>

#define B_SZ 16
#define T_LR 2560
#define BT (B_SZ * T_LR)     // 40960 tokens
#define DM 256               // d_model
#define DI 512               // d_inner
#define DS 16                // d_state
#define DTR 16               // dt_rank
#define CH 128               // scan chunks per sequence
#define CH_LOG2 7
#define CLEN (T_LR / CH)     // 20 steps per chunk

typedef __attribute__((ext_vector_type(8))) short bf16x8;
typedef __attribute__((ext_vector_type(4))) float f32x4;

__device__ __forceinline__ float silu_f(float x) {
    return x / (1.f + __expf(-x));
}
__device__ __forceinline__ unsigned short f2bf(float v) {
    __hip_bfloat16 h = __float2bfloat16(v);
    return *(unsigned short*)&h;
}
__device__ __forceinline__ float bf2f(unsigned short u) {
    union { unsigned int i; float f; } c;
    c.i = (unsigned int)u << 16;
    return c.f;
}
__device__ __forceinline__ int seqrev(int r) {
    int s = r / T_LR, t = r % T_LR;
    return s * T_LR + (T_LR - 1 - t);
}
// softplus: log(1+e). abs err ~1e-7 (vs log1pf) — negligible vs bf16 rounding.
__device__ __forceinline__ float softplus_f(float x) {
    return (x > 20.f) ? x : __logf(1.f + __expf(x));
}
// fragment-major weight swizzle: tile (tap, n/16, c/32) stores 64 lanes x 16B
// contiguously; lane (q=c5>>3, ml=n&15) gets W[n][c...c+7].
__device__ __forceinline__ size_t wswz_idx(int tap, int n, int c, int N, int Kt) {
    return ((size_t)((tap * (N >> 4) + (n >> 4)) * (Kt >> 5) + (c >> 5)) << 9)
         + (size_t)((((c >> 3) & 3) * 16 + (n & 15)) * 8 + (c & 7));
}

// ---------------------------------------------------------------------------
// mega prep kernel: all weight transforms + input transpose, one dispatch.
// ---------------------------------------------------------------------------
__global__ __launch_bounds__(256) void k_prep(
    const float* __restrict__ enc_w1, const float* __restrict__ enc_w2,
    const float* __restrict__ convd_w, const float* __restrict__ sp_w,
    const float* __restrict__ convd_b, const float* __restrict__ bn_g,
    const float* __restrict__ bn_b, const float* __restrict__ bn_mean,
    const float* __restrict__ bn_var,
    const float* __restrict__ inW0, const float* __restrict__ inW1,
    const float* __restrict__ outW0, const float* __restrict__ outW1,
    const float* __restrict__ xW0, const float* __restrict__ xW1,
    const float* __restrict__ Alog0, const float* __restrict__ Alog1,
    const float* __restrict__ x,
    unsigned short* __restrict__ W1r, unsigned short* __restrict__ W2r,
    unsigned short* __restrict__ Wdr, unsigned short* __restrict__ Wspr,
    float* __restrict__ alpha, float* __restrict__ beta,
    unsigned short* __restrict__ inW_bf2, unsigned short* __restrict__ outW_bf2,
    unsigned short* __restrict__ xW_bc2, float* __restrict__ Aflag,
    unsigned short* __restrict__ xt)
{
    __shared__ float ts[32][33];
    __shared__ int s_ok;
    int blk = blockIdx.x;
    int tid = threadIdx.x;
    if (blk < 32) {                         // W1r: (128,64,3) -> swizzled [N=128,Kt=64]
        int i = blk * 256 + tid;
        int n = i / 64, ci = i % 64;
        #pragma unroll
        for (int k = 0; k < 3; k++)
            W1r[wswz_idx(k, n, ci, 128, 64)] = f2bf(enc_w1[((size_t)n * 64 + ci) * 3 + k]);
    } else if (blk < 160) {                 // W2r: (256,128,3) -> [N=256,Kt=128]
        int i = (blk - 32) * 256 + tid;
        int n = i / 128, ci = i % 128;
        #pragma unroll
        for (int k = 0; k < 3; k++)
            W2r[wswz_idx(k, n, ci, 256, 128)] = f2bf(enc_w2[((size_t)n * 128 + ci) * 3 + k]);
    } else if (blk < 672) {                 // Wdr: (256,512,3) -> [N=256,Kt=512]
        int i = (blk - 160) * 256 + tid;
        int n = i / 512, ci = i % 512;
        #pragma unroll
        for (int k = 0; k < 3; k++)
            Wdr[wswz_idx(k, n, ci, 256, 512)] = f2bf(convd_w[((size_t)n * 512 + ci) * 3 + k]);
    } else if (blk < 800) {                 // Wspr: (128,256,3) -> [N=128,Kt=256]
        int i = (blk - 672) * 256 + tid;
        int n = i / 256, ci = i % 256;
        #pragma unroll
        for (int k = 0; k < 3; k++)
            Wspr[wswz_idx(k, n, ci, 128, 256)] = f2bf(sp_w[((size_t)n * 256 + ci) * 3 + k]);
    } else if (blk < 801) {                 // bnfold
        int c = tid;
        float a = bn_g[c] * rsqrtf(bn_var[c] + 1e-5f);
        alpha[c] = a;
        beta[c] = (convd_b[c] - bn_mean[c]) * a + bn_b[c];
    } else if (blk < 1825) {                // inW cast, both dirs (262144 each)
        int i = (blk - 801) * 256 + tid;
        inW_bf2[i] = f2bf(inW0[i]);
        inW_bf2[262144 + i] = f2bf(inW1[i]);
    } else if (blk < 2337) {                // outW cast (131072 each)
        int i = (blk - 1825) * 256 + tid;
        outW_bf2[i] = f2bf(outW0[i]);
        outW_bf2[131072 + i] = f2bf(outW1[i]);
    } else if (blk < 2433) {                // xW[0:48] cast (24576 each dir)
        int i = (blk - 2337) * 256 + tid;
        xW_bc2[i] = f2bf(xW0[i]);
        xW_bc2[24576 + i] = f2bf(xW1[i]);
    } else if (blk < 2434) {                // Alog structure check: A[d][n] == A[d][0]*(n+1)?
        if (tid == 0) s_ok = 1;
        __syncthreads();
        int ok = 1;
        for (int i = tid; i < DI * DS; i += 256) {
            int d = i >> 4, n = i & 15;
            float a0f = __expf(Alog0[d * DS]);
            float anf = __expf(Alog0[d * DS + n]);
            if (fabsf(anf - (float)(n + 1) * a0f) > 1e-3f * (float)(n + 1)) ok = 0;
            float a0b = __expf(Alog1[d * DS]);
            float anb = __expf(Alog1[d * DS + n]);
            if (fabsf(anb - (float)(n + 1) * a0b) > 1e-3f * (float)(n + 1)) ok = 0;
        }
        if (!ok) atomicAnd(&s_ok, 0);
        __syncthreads();
        if (tid == 0) Aflag[0] = s_ok ? 1.f : 0.f;
    } else {                                // transpose x (b,64,T) f32 -> xt (b,T,64) bf16
        int idx = blk - 2434;               // b(16) x c0(2) x t0(80)
        int t0 = (idx % 80) * 32;
        int c0 = ((idx / 80) & 1) * 32;
        int b = idx / 160;
        int tx = tid & 31, ty = tid >> 5;
        #pragma unroll
        for (int j = 0; j < 4; j++) {
            int c = c0 + ty + j * 8;
            ts[ty + j * 8][tx] = x[((size_t)b * 64 + c) * T_LR + t0 + tx];
        }
        __syncthreads();
        #pragma unroll
        for (int j = 0; j < 4; j++) {
            int t = t0 + ty + j * 8;
            xt[((size_t)b * T_LR + t) * 64 + c0 + tx] = f2bf(ts[tx][ty + j * 8]);
        }
    }
}

// ---------------------------------------------------------------------------
// implicit-GEMM k=3 "same" conv via MFMA (encoder/decoder convs).
// R10: B tiles double-buffered in LDS via global_load_lds (contiguous 1KB
// fragments from the swizzled weights match the wave-uniform-base + lane*16
// HW pattern exactly), issued ONE K-STEP AHEAD so the ~300-500cy L2 latency
// hides under the 48-MFMA compute phase. Compute reads only LDS. As is
// single-buffered (2 barriers/step); the compiler's vmcnt(0)-before-barrier
// drain provides all load/read ordering.
// ---------------------------------------------------------------------------
__global__ __launch_bounds__(256, 2) void k_conv3_bf(const unsigned short* __restrict__ A1, int K1,
                                                  const unsigned short* __restrict__ A2, int K2,
                                                  const unsigned short* __restrict__ Wz,
                                                  const float* __restrict__ alpha,
                                                  const float* __restrict__ beta,
                                                  float* __restrict__ outf,
                                                  unsigned short* __restrict__ outb,
                                                  int N, int dosilu, int pixsh) {
    int Kt = K1 + K2;
    __shared__ __align__(16) unsigned short sA[130][40];          // 10.4 KB
    __shared__ __align__(16) unsigned short sB[2][2][12][512];    // 48 KB
    float* sC = (float*)&sB[0][0][0][0];                          // epilogue overlay
    int tid = threadIdx.x;
    int wave = tid >> 6, lane = tid & 63;
    int wm = (wave >> 1) * 64, wg = wave & 1;
    int wn = wg * 64;
    int m0 = blockIdx.x * 128, n0 = blockIdx.y * 128;
    int b = m0 / T_LR, t0 = m0 % T_LR;
    int q = lane >> 4, ml = lane & 15;
    int Nb16 = N >> 4, Kb32 = Kt >> 5;
    int nb0 = n0 >> 4;
    const unsigned short* wlane = Wz + (size_t)lane * 8;
    f32x4 acc[4][4] = {};
    int cq = tid & 3;
    int r0 = tid >> 2, r1 = r0 + 64, r2 = r0 + 128;
    bool has2 = (tid < 8);
    int ta0 = t0 - 1 + r0, ta1 = t0 - 1 + r1, ta2 = t0 - 1 + r2;
    bool va0 = (ta0 >= 0) && (ta0 < T_LR);
    bool va1 = (ta1 < T_LR);
    bool va2 = has2 && (ta2 < T_LR);
    uint4 v0, v1, v2;
    #define LOADA(vv, valid, t, col) { vv = make_uint4(0u,0u,0u,0u); if (valid) { \
        const unsigned short* src = ((col) < K1) \
            ? A1 + (size_t)(b * T_LR + (t)) * K1 + (col) \
            : A2 + (size_t)(b * T_LR + (t)) * K2 + ((col) - K1); \
        vv = *(const uint4*)src; } }
    // issue this wave's 6 B-fragment DMA loads for k-step kk into buffer buf
    #define ISSUEB(kk, buf) { \
        _Pragma("unroll") \
        for (int j = 0; j < 6; j++) { \
            int f = wave * 6 + j; \
            int g = (f >= 12) ? 1 : 0; \
            int rem = f - g * 12; \
            int tap = rem >> 2, ni = rem & 3; \
            const unsigned short* gsrc = wlane + \
                ((size_t)((tap * Nb16 + nb0 + g * 4 + ni) * Kb32 + (kk)) << 9); \
            unsigned short* ldst = &sB[buf][g][tap * 4 + ni][0]; \
            __builtin_amdgcn_global_load_lds( \
                (const __attribute__((address_space(1))) unsigned int*)gsrc, \
                (__attribute__((address_space(3))) unsigned int*)ldst, 16, 0, 0); \
        } }
    // prologue: A(0) -> regs, B(0) -> sB[0]
    LOADA(v0, va0, ta0, cq * 8);
    LOADA(v1, va1, ta1, cq * 8);
    LOADA(v2, va2, ta2, cq * 8);
    ISSUEB(0, 0);
    int nk = Kb32;
    for (int kk = 0; kk < nk; kk++) {
        int cur = kk & 1;
        __syncthreads();                   // prev compute done; drains A regs + B DMA
        *(uint4*)&sA[r0][cq * 8] = v0;
        *(uint4*)&sA[r1][cq * 8] = v1;
        if (has2) *(uint4*)&sA[r2][cq * 8] = v2;
        __syncthreads();                   // sA ready; sB[cur] complete
        if (kk + 1 < nk) {
            int col = ((kk + 1) << 5) + cq * 8;
            LOADA(v0, va0, ta0, col);
            LOADA(v1, va1, ta1, col);
            LOADA(v2, va2, ta2, col);
            ISSUEB(kk + 1, cur ^ 1);
        }
        #pragma unroll
        for (int tap = 0; tap < 3; tap++) {
            bf16x8 bfr[4];
            #pragma unroll
            for (int ni = 0; ni < 4; ni++)
                bfr[ni] = *(const bf16x8*)&sB[cur][wg][tap * 4 + ni][lane * 8];
            #pragma unroll
            for (int mi = 0; mi < 4; mi++) {
                bf16x8 af = *(const bf16x8*)&sA[wm + mi * 16 + ml + tap][q * 8];
                #pragma unroll
                for (int ni = 0; ni < 4; ni++)
                    acc[mi][ni] = __builtin_amdgcn_mfma_f32_16x16x32_bf16(af, bfr[ni], acc[mi][ni], 0, 0, 0);
            }
        }
    }
    #undef ISSUEB
    #undef LOADA
    // epilogue: 4 passes of 32 rows through LDS (overlays sB), coalesced stores
    int rowoff = m0 - b * T_LR;   // local t of row 0
    #pragma unroll
    for (int p = 0; p < 4; p++) {
        __syncthreads();
        if ((wave >> 1) == (p >> 1)) {
            int mib = (p & 1) * 2;
            #pragma unroll
            for (int m2 = 0; m2 < 2; m2++) {
                int mi = mib + m2;
                int rl = mi * 16 + q * 4 - (p & 1) * 32;
                #pragma unroll
                for (int r = 0; r < 4; r++)
                    #pragma unroll
                    for (int ni = 0; ni < 4; ni++)
                        sC[(rl + r) * 140 + wn + ni * 16 + ml] = acc[mi][ni][r];
            }
        }
        __syncthreads();
        if (pixsh) {
            // N=128, n0=0: col=2*c2+rr -> out[((b*64+c2)*T + t)*2 + rr]
            int row = tid & 31, c2g = tid >> 5;
            int t = rowoff + p * 32 + row;
            float* dst = outf + ((size_t)b * 64 * T_LR + t) * 2;
            #pragma unroll
            for (int j = 0; j < 8; j++) {
                int c2 = c2g + j * 8;
                float va = sC[row * 140 + 2 * c2]     + beta[2 * c2];
                float vb = sC[row * 140 + 2 * c2 + 1] + beta[2 * c2 + 1];
                *(float2*)&dst[(size_t)c2 * T_LR * 2] = make_float2(va, vb);
            }
        } else {
            #pragma unroll
            for (int gi = 0; gi < 2; gi++) {
                int g = tid + gi * 256;
                int row = g >> 4;
                int colg = (g & 15) * 8;
                int mr = m0 + p * 32 + row;
                const float* src = sC + row * 140 + colg;
                float vv[8];
                *(float4*)&vv[0] = *(const float4*)src;
                *(float4*)&vv[4] = *(const float4*)(src + 4);
                unsigned short ob[8];
                #pragma unroll
                for (int jj = 0; jj < 8; jj++) {
                    int col = n0 + colg + jj;
                    float a = alpha ? alpha[col] : 1.f;
                    float v = vv[jj] * a + beta[col];
                    if (dosilu) v = silu_f(v);
                    vv[jj] = v;
                    ob[jj] = f2bf(v);
                }
                if (outf) {
                    *(float4*)(outf + (size_t)mr * N + n0 + colg) = *(float4*)&vv[0];
                    *(float4*)(outf + (size_t)mr * N + n0 + colg + 4) = *(float4*)&vv[4];
                }
                if (outb)
                    *(uint4*)(outb + (size_t)mr * N + n0 + colg) = *(uint4*)ob;
            }
        }
    }
}

// ---------------------------------------------------------------------------
// fused in_proj (xc half) + causal depthwise conv k=4 + silu -> xcs bf16.
// BOTH directions in one dispatch: dir = blockIdx.z selects weights/output.
// ---------------------------------------------------------------------------
__global__ __launch_bounds__(256) void k_inproj_conv(const unsigned short* __restrict__ xn,
                                                     const unsigned short* __restrict__ inW2,
                                                     const float* __restrict__ cw0,
                                                     const float* __restrict__ cw1,
                                                     const float* __restrict__ cb0,
                                                     const float* __restrict__ cb1,
                                                     unsigned short* __restrict__ xcs,
                                                     long long dsXcs) {
    __shared__ unsigned short As[128][40];
    __shared__ unsigned short Bs[128][40];
    __shared__ unsigned short Ct[131][136];   // rows: internal t0-3 .. t0+127
    int dir = blockIdx.z;
    int arev = dir;
    const unsigned short* inW = inW2 + (size_t)dir * 1024 * DM;
    const float* cw = dir ? cw1 : cw0;
    const float* cb = dir ? cb1 : cb0;
    xcs += (size_t)dir * dsXcs;
    int tid = threadIdx.x;
    int wave = tid >> 6, lane = tid & 63;
    int wm = (wave >> 1) * 64, wn = (wave & 1) * 64;
    int m0 = blockIdx.x * 128, n0 = blockIdx.y * 128;
    int b = m0 / T_LR, t0 = m0 % T_LR;
    int sc = tid & 3, sr = tid >> 2;
    int ar0 = m0 + sr, ar1 = m0 + sr + 64;
    if (arev) { ar0 = seqrev(ar0); ar1 = seqrev(ar1); }
    const unsigned short* ap0 = xn + (size_t)ar0 * DM + sc * 8;
    const unsigned short* ap1 = xn + (size_t)ar1 * DM + sc * 8;
    const unsigned short* bp0 = inW + (size_t)(n0 + sr) * DM + sc * 8;
    const unsigned short* bp1 = inW + (size_t)(n0 + sr + 64) * DM + sc * 8;
    f32x4 acc[4][4] = {};
    int q = lane >> 4, ml = lane & 15;
    for (int k0 = 0; k0 < DM; k0 += 32) {
        uint4 a0 = *(const uint4*)(ap0 + k0);
        uint4 a1 = *(const uint4*)(ap1 + k0);
        uint4 b0 = *(const uint4*)(bp0 + k0);
        uint4 b1 = *(const uint4*)(bp1 + k0);
        __syncthreads();
        *(uint4*)&As[sr][sc * 8]      = a0;
        *(uint4*)&As[sr + 64][sc * 8] = a1;
        *(uint4*)&Bs[sr][sc * 8]      = b0;
        *(uint4*)&Bs[sr + 64][sc * 8] = b1;
        __syncthreads();
        bf16x8 af[4], bfr[4];
        #pragma unroll
        for (int mi = 0; mi < 4; mi++)
            af[mi] = *(const bf16x8*)&As[wm + mi * 16 + ml][q * 8];
        #pragma unroll
        for (int ni = 0; ni < 4; ni++)
            bfr[ni] = *(const bf16x8*)&Bs[wn + ni * 16 + ml][q * 8];
        #pragma unroll
        for (int mi = 0; mi < 4; mi++)
            #pragma unroll
            for (int ni = 0; ni < 4; ni++)
                acc[mi][ni] = __builtin_amdgcn_mfma_f32_16x16x32_bf16(af[mi], bfr[ni], acc[mi][ni], 0, 0, 0);
    }
    // main tile -> Ct rows 3..130
    #pragma unroll
    for (int mi = 0; mi < 4; mi++)
        #pragma unroll
        for (int r = 0; r < 4; r++)
            #pragma unroll
            for (int ni = 0; ni < 4; ni++)
                Ct[3 + wm + mi * 16 + q * 4 + r][wn + ni * 16 + ml] = f2bf(acc[mi][ni][r]);
    // halo rows 0..2 via direct dot — 384 items on 256 threads
    for (int i = tid; i < 384; i += 256) {
        int hr = i >> 7, c = i & 127;
        int tr = t0 - 3 + hr;
        float v = 0.f;
        if (tr >= 0) {
            int src = b * T_LR + (arev ? (T_LR - 1 - tr) : tr);
            const unsigned short* xr = xn + (size_t)src * DM;
            const unsigned short* wr = inW + (size_t)(n0 + c) * DM;
            for (int k = 0; k < DM; k += 8) {
                uint4 xa = *(const uint4*)(xr + k);
                uint4 wa = *(const uint4*)(wr + k);
                const unsigned short* xs = (const unsigned short*)&xa;
                const unsigned short* wsp = (const unsigned short*)&wa;
                #pragma unroll
                for (int j = 0; j < 8; j++) v += bf2f(xs[j]) * bf2f(wsp[j]);
            }
        }
        Ct[hr][c] = f2bf(v);
    }
    __syncthreads();
    // causal conv k=4 + silu, write xcs bf16
    int col = tid & 127;
    int d = n0 + col;
    float w0 = cw[d * 4 + 0], w1 = cw[d * 4 + 1], w2 = cw[d * 4 + 2], w3 = cw[d * 4 + 3];
    float bi = cb[d];
    int rbase = tid >> 7;
    for (int j = 0; j < 64; j++) {
        int row = rbase + 2 * j;
        float v = bi + bf2f(Ct[row][col]) * w0 + bf2f(Ct[row + 1][col]) * w1
                     + bf2f(Ct[row + 2][col]) * w2 + bf2f(Ct[row + 3][col]) * w3;
        xcs[(size_t)(m0 + row) * DI + d] = f2bf(silu_f(v));
    }
}

// ---------------------------------------------------------------------------
// rmsnorm over last dim (256). One wave per token. Optional second input
// summed in (mo + mo1). fp32 and/or bf16 out.
// ---------------------------------------------------------------------------
__global__ __launch_bounds__(256) void k_rmsnorm(const float* __restrict__ in1,
                                                 const float* __restrict__ in2,
                                                 const float* __restrict__ w,
                                                 float* __restrict__ out,
                                                 unsigned short* __restrict__ out_bf,
                                                 int ntok) {
    int tok = (blockIdx.x * 256 + threadIdx.x) >> 6;
    int lane = threadIdx.x & 63;
    if (tok >= ntok) return;
    float4 v = ((const float4*)(in1 + (size_t)tok * DM))[lane];
    if (in2) {
        float4 u = ((const float4*)(in2 + (size_t)tok * DM))[lane];
        v.x += u.x; v.y += u.y; v.z += u.z; v.w += u.w;
    }
    float ss = v.x * v.x + v.y * v.y + v.z * v.z + v.w * v.w;
    #pragma unroll
    for (int off = 32; off > 0; off >>= 1) ss += __shfl_xor(ss, off);
    float sc = rsqrtf(ss * (1.f / 256.f) + 1e-6f);
    float4 wv = ((const float4*)w)[lane];
    float4 o;
    o.x = v.x * sc * wv.x; o.y = v.y * sc * wv.y;
    o.z = v.z * sc * wv.z; o.w = v.w * sc * wv.w;
    if (out) ((float4*)(out + (size_t)tok * DM))[lane] = o;
    if (out_bf) {
        ushort4 ob;
        ob.x = f2bf(o.x); ob.y = f2bf(o.y); ob.z = f2bf(o.z); ob.w = f2bf(o.w);
        ((ushort4*)(out_bf + (size_t)tok * DM))[lane] = ob;
    }
}

// ---------------------------------------------------------------------------
// bf16 MFMA GEMM, fp32 out + optional residual (db and out_proj).
// BOTH directions per dispatch: dir = blockIdx.z applies element strides.
// crevmode: 0 = never reverse output rows, 2 = reverse iff dir==1.
// ---------------------------------------------------------------------------
__global__ __launch_bounds__(256) void k_gemm_bf(const unsigned short* __restrict__ A, int lda, long long dsA,
                                                 const unsigned short* __restrict__ Bw, long long dsB,
                                                 float* Cf, long long dsCf, int ldc,
                                                 const float* __restrict__ res,
                                                 int K, int Nout, int crevmode) {
    __shared__ unsigned short As[128][40];
    __shared__ unsigned short Bs[128][40];
    int dir = blockIdx.z;
    A += (long long)dir * dsA;
    Bw += (long long)dir * dsB;
    Cf += (long long)dir * dsCf;
    int crev = (crevmode == 2) ? dir : crevmode;
    int tid = threadIdx.x;
    int wave = tid >> 6, lane = tid & 63;
    int wm = (wave >> 1) * 64, wn = (wave & 1) * 64;
    int m0 = blockIdx.x * 128, n0 = blockIdx.y * 128;
    int sc = tid & 3, sr = tid >> 2;
    const unsigned short* ap0 = A + (size_t)(m0 + sr) * lda + sc * 8;
    const unsigned short* ap1 = A + (size_t)(m0 + sr + 64) * lda + sc * 8;
    bool bv0 = (n0 + sr) < Nout;
    bool bv1 = (n0 + sr + 64) < Nout;
    const unsigned short* bp0 = Bw + (size_t)(n0 + sr) * K + sc * 8;
    const unsigned short* bp1 = Bw + (size_t)(n0 + sr + 64) * K + sc * 8;
    f32x4 acc[4][4] = {};
    int q = lane >> 4, ml = lane & 15;
    for (int k0 = 0; k0 < K; k0 += 32) {
        uint4 a0 = *(const uint4*)(ap0 + k0);
        uint4 a1 = *(const uint4*)(ap1 + k0);
        uint4 b0 = make_uint4(0u, 0u, 0u, 0u), b1 = make_uint4(0u, 0u, 0u, 0u);
        if (bv0) b0 = *(const uint4*)(bp0 + k0);
        if (bv1) b1 = *(const uint4*)(bp1 + k0);
        __syncthreads();
        *(uint4*)&As[sr][sc * 8]      = a0;
        *(uint4*)&As[sr + 64][sc * 8] = a1;
        *(uint4*)&Bs[sr][sc * 8]      = b0;
        *(uint4*)&Bs[sr + 64][sc * 8] = b1;
        __syncthreads();
        bf16x8 af[4], bfr[4];
        #pragma unroll
        for (int mi = 0; mi < 4; mi++)
            af[mi] = *(const bf16x8*)&As[wm + mi * 16 + ml][q * 8];
        #pragma unroll
        for (int ni = 0; ni < 4; ni++)
            bfr[ni] = *(const bf16x8*)&Bs[wn + ni * 16 + ml][q * 8];
        #pragma unroll
        for (int mi = 0; mi < 4; mi++)
            #pragma unroll
            for (int ni = 0; ni < 4; ni++)
                acc[mi][ni] = __builtin_amdgcn_mfma_f32_16x16x32_bf16(af[mi], bfr[ni], acc[mi][ni], 0, 0, 0);
    }
    #pragma unroll
    for (int mi = 0; mi < 4; mi++) {
        #pragma unroll
        for (int r = 0; r < 4; r++) {
            int mr = m0 + wm + mi * 16 + q * 4 + r;
            int orow = crev ? seqrev(mr) : mr;
            #pragma unroll
            for (int ni = 0; ni < 4; ni++) {
                int col = n0 + wn + ni * 16 + ml;
                if (col < Nout) {
                    float v = acc[mi][ni][r];
                    if (res) v += res[(size_t)orow * ldc + col];
                    Cf[(size_t)orow * ldc + col] = v;
                }
            }
        }
    }
}

// ---------------------------------------------------------------------------
// bf16-out MFMA GEMM with LDS-transposed vectorized epilogue (z-gate).
// BOTH directions per dispatch: dir = blockIdx.z; A (xn) shared; arev = dir.
// ---------------------------------------------------------------------------
__global__ __launch_bounds__(256) void k_gemm_bf_cb(const unsigned short* __restrict__ A, int lda,
                                                    const unsigned short* __restrict__ Bw, long long dsB,
                                                    unsigned short* __restrict__ Cb, int ldc, long long dsCb,
                                                    const unsigned short* __restrict__ gate, long long dsGate,
                                                    int K) {
    __shared__ __align__(16) unsigned short smem[2 * 128 * 40];   // 20480 B
    unsigned short (*As)[40] = (unsigned short(*)[40])smem;
    unsigned short (*Bs)[40] = (unsigned short(*)[40])(smem + 128 * 40);
    float* sC = (float*)smem;                                     // 32 x 140 f32
    int dir = blockIdx.z;
    int arev = dir;
    Bw += (long long)dir * dsB;
    Cb += (long long)dir * dsCb;
    gate += (long long)dir * dsGate;
    int tid = threadIdx.x;
    int wave = tid >> 6, lane = tid & 63;
    int wm = (wave >> 1) * 64, wn = (wave & 1) * 64;
    int m0 = blockIdx.x * 128, n0 = blockIdx.y * 128;
    int sc = tid & 3, sr = tid >> 2;
    int ar0 = m0 + sr, ar1 = m0 + sr + 64;
    if (arev) { ar0 = seqrev(ar0); ar1 = seqrev(ar1); }
    const unsigned short* ap0 = A + (size_t)ar0 * lda + sc * 8;
    const unsigned short* ap1 = A + (size_t)ar1 * lda + sc * 8;
    const unsigned short* bp0 = Bw + (size_t)(n0 + sr) * K + sc * 8;
    const unsigned short* bp1 = Bw + (size_t)(n0 + sr + 64) * K + sc * 8;
    f32x4 acc[4][4] = {};
    int q = lane >> 4, ml = lane & 15;
    for (int k0 = 0; k0 < K; k0 += 32) {
        uint4 a0 = *(const uint4*)(ap0 + k0);
        uint4 a1 = *(const uint4*)(ap1 + k0);
        uint4 b0 = *(const uint4*)(bp0 + k0);
        uint4 b1 = *(const uint4*)(bp1 + k0);
        __syncthreads();
        *(uint4*)&As[sr][sc * 8]      = a0;
        *(uint4*)&As[sr + 64][sc * 8] = a1;
        *(uint4*)&Bs[sr][sc * 8]      = b0;
        *(uint4*)&Bs[sr + 64][sc * 8] = b1;
        __syncthreads();
        bf16x8 af[4], bfr[4];
        #pragma unroll
        for (int mi = 0; mi < 4; mi++)
            af[mi] = *(const bf16x8*)&As[wm + mi * 16 + ml][q * 8];
        #pragma unroll
        for (int ni = 0; ni < 4; ni++)
            bfr[ni] = *(const bf16x8*)&Bs[wn + ni * 16 + ml][q * 8];
        #pragma unroll
        for (int mi = 0; mi < 4; mi++)
            #pragma unroll
            for (int ni = 0; ni < 4; ni++)
                acc[mi][ni] = __builtin_amdgcn_mfma_f32_16x16x32_bf16(af[mi], bfr[ni], acc[mi][ni], 0, 0, 0);
    }
    // epilogue: 4 passes of 32 rows through LDS (stride 140 f32)
    #pragma unroll
    for (int p = 0; p < 4; p++) {
        __syncthreads();
        if ((wave >> 1) == (p >> 1)) {
            int mib = (p & 1) * 2;
            #pragma unroll
            for (int m2 = 0; m2 < 2; m2++) {
                int mi = mib + m2;
                int rl = mi * 16 + q * 4 - (p & 1) * 32;
                #pragma unroll
                for (int r = 0; r < 4; r++)
                    #pragma unroll
                    for (int ni = 0; ni < 4; ni++)
                        sC[(rl + r) * 140 + wn + ni * 16 + ml] = acc[mi][ni][r];
            }
        }
        __syncthreads();
        #pragma unroll
        for (int gi = 0; gi < 2; gi++) {
            int g = tid + gi * 256;
            int row = g >> 4;
            int colg = (g & 15) * 8;
            int grow = m0 + p * 32 + row;
            const float* src = sC + row * 140 + colg;
            float4 v0 = *(const float4*)src;
            float4 v1 = *(const float4*)(src + 4);
            float vv[8] = {v0.x, v0.y, v0.z, v0.w, v1.x, v1.y, v1.z, v1.w};
            unsigned short gu[8];
            *(uint4*)gu = *(const uint4*)(gate + (size_t)grow * ldc + n0 + colg);
            unsigned short o[8];
            #pragma unroll
            for (int jj = 0; jj < 8; jj++) {
                float v = vv[jj];
                v = silu_f(v) * bf2f(gu[jj]);
                o[jj] = f2bf(v);
            }
            *(uint4*)(Cb + (size_t)grow * ldc + n0 + colg) = *(uint4*)o;
        }
    }
}

// ---------------------------------------------------------------------------
// scan phase 1: per (dir*bl, chunk, d) thread. Both dirs in one dispatch:
// buffers laid [2*Bc][...]; dir = (bl >= Bc) selects the weight set.
// dt computed in-line (low-rank); fast path when Aflag set.
// ---------------------------------------------------------------------------
__global__ __launch_bounds__(256) void k_scan_p1(const unsigned short* __restrict__ x,
                                                 const float* __restrict__ db,
                                                 const float* __restrict__ dtW0, const float* __restrict__ dtW1,
                                                 const float* __restrict__ dtb0, const float* __restrict__ dtb1,
                                                 const float* __restrict__ Alog0, const float* __restrict__ Alog1,
                                                 const float* __restrict__ Aflag,
                                                 float* __restrict__ hS,
                                                 float* __restrict__ csum, int Bc) {
    __shared__ float dbs[CLEN * 48];
    int tid = threadIdx.x;
    int gid = blockIdx.x * 256 + tid;   // ((dir*Bc+bl)*CH + c)*DI + d
    int d = gid & (DI - 1);
    int bcix = gid >> 9;
    int c = bcix & (CH - 1);
    int bl = bcix >> CH_LOG2;           // [0, 2*Bc)
    int dir = (bl >= Bc) ? 1 : 0;
    const float* dtW  = dir ? dtW1  : dtW0;
    const float* dtb  = dir ? dtb1  : dtb0;
    const float* Alog = dir ? Alog1 : Alog0;
    int tbase = c * CLEN;
    const float* dbp = db + ((size_t)bl * T_LR + tbase) * 48;
    if (tid < 240) *(float4*)&dbs[tid * 4] = *(const float4*)(dbp + tid * 4);
    bool fast = (Aflag[0] != 0.f);
    float A0 = -__expf(Alog[d * DS]);
    float Av[DS], h[DS];
    #pragma unroll
    for (int n = 0; n < DS; n++) h[n] = 0.f;
    if (!fast) {
        #pragma unroll
        for (int n = 0; n < DS; n++) Av[n] = -__expf(Alog[d * DS + n]);
    }
    const float4* wp = (const float4*)(dtW + d * 16);
    float4 w0 = wp[0], w1 = wp[1], w2 = wp[2], w3 = wp[3];
    float bias = dtb[d];
    const unsigned short* xp = x + ((size_t)bl * T_LR + tbase) * DI + d;
    float S = 0.f;
    __syncthreads();
    for (int t = 0; t < CLEN; t++) {
        const float* bc = dbs + t * 48;
        float dl = bias
            + bc[0] * w0.x + bc[1] * w0.y + bc[2] * w0.z + bc[3] * w0.w
            + bc[4] * w1.x + bc[5] * w1.y + bc[6] * w1.z + bc[7] * w1.w
            + bc[8] * w2.x + bc[9] * w2.y + bc[10] * w2.z + bc[11] * w2.w
            + bc[12] * w3.x + bc[13] * w3.y + bc[14] * w3.z + bc[15] * w3.w;
        float dtv = softplus_f(dl);
        float xv  = bf2f(xp[(size_t)t * DI]);
        float dtx = dtv * xv;
        S += dtv;
        if (fast) {
            float e1 = __expf(dtv * A0);
            float e = e1;
            #pragma unroll
            for (int n = 0; n < DS; n++) {
                h[n] = e * h[n] + dtx * bc[16 + n];
                e *= e1;
            }
        } else {
            #pragma unroll
            for (int n = 0; n < DS; n++)
                h[n] = __expf(dtv * Av[n]) * h[n] + dtx * bc[16 + n];
        }
    }
    float* hp = hS + (size_t)gid * DS;
    #pragma unroll
    for (int n = 0; n < DS; n++) hp[n] = h[n];
    csum[gid] = S;
}

// ---------------------------------------------------------------------------
// scan phase 2: per (dir*bl, d, n) thread; sequential over CH chunks.
// ---------------------------------------------------------------------------
__global__ __launch_bounds__(256) void k_scan_p2(float* __restrict__ hS,
                                                 const float* __restrict__ csum,
                                                 const float* __restrict__ Alog0,
                                                 const float* __restrict__ Alog1, int Bc) {
    int gid = blockIdx.x * 256 + threadIdx.x;   // ((dir*Bc+bl)*DI + d)*DS + n
    int n = gid & (DS - 1);
    int d = (gid >> 4) & (DI - 1);
    int bl = gid >> 13;                         // [0, 2*Bc)
    const float* Alog = (bl >= Bc) ? Alog1 : Alog0;
    float An = -__expf(Alog[d * DS + n]);
    float hs = 0.f;
    for (int c = 0; c < CH; c++) {
        size_t base = ((size_t)(bl * CH + c) * DI + d);
        float he = hS[base * DS + n];
        float S  = csum[base];
        hS[base * DS + n] = hs;
        hs = __expf(An * S) * hs + he;
    }
}

// ---------------------------------------------------------------------------
// scan phase 3: corrected chunk-start state; y bf16 in place over x.
// ---------------------------------------------------------------------------
__global__ __launch_bounds__(256) void k_scan_p3(unsigned short* __restrict__ x,
                                                 const float* __restrict__ db,
                                                 const float* __restrict__ dtW0, const float* __restrict__ dtW1,
                                                 const float* __restrict__ dtb0, const float* __restrict__ dtb1,
                                                 const float* __restrict__ Alog0, const float* __restrict__ Alog1,
                                                 const float* __restrict__ Aflag,
                                                 const float* __restrict__ Dp0, const float* __restrict__ Dp1,
                                                 const float* __restrict__ hS, int Bc) {
    __shared__ float dbs[CLEN * 48];
    int tid = threadIdx.x;
    int gid = blockIdx.x * 256 + tid;
    int d = gid & (DI - 1);
    int bcix = gid >> 9;
    int c = bcix & (CH - 1);
    int bl = bcix >> CH_LOG2;
    int dir = (bl >= Bc) ? 1 : 0;
    const float* dtW  = dir ? dtW1  : dtW0;
    const float* dtb  = dir ? dtb1  : dtb0;
    const float* Alog = dir ? Alog1 : Alog0;
    const float* Dp   = dir ? Dp1   : Dp0;
    int tbase = c * CLEN;
    const float* dbp = db + ((size_t)bl * T_LR + tbase) * 48;
    if (tid < 240) *(float4*)&dbs[tid * 4] = *(const float4*)(dbp + tid * 4);
    bool fast = (Aflag[0] != 0.f);
    float A0 = -__expf(Alog[d * DS]);
    float Av[DS], h[DS];
    const float* hp = hS + (size_t)gid * DS;
    #pragma unroll
    for (int n = 0; n < DS; n++) h[n] = hp[n];
    if (!fast) {
        #pragma unroll
        for (int n = 0; n < DS; n++) Av[n] = -__expf(Alog[d * DS + n]);
    }
    const float4* wp = (const float4*)(dtW + d * 16);
    float4 w0 = wp[0], w1 = wp[1], w2 = wp[2], w3 = wp[3];
    float bias = dtb[d];
    float Dd = Dp[d];
    unsigned short* xp = x + ((size_t)bl * T_LR + tbase) * DI + d;
    __syncthreads();
    for (int t = 0; t < CLEN; t++) {
        const float* bc = dbs + t * 48;
        float dl = bias
            + bc[0] * w0.x + bc[1] * w0.y + bc[2] * w0.z + bc[3] * w0.w
            + bc[4] * w1.x + bc[5] * w1.y + bc[6] * w1.z + bc[7] * w1.w
            + bc[8] * w2.x + bc[9] * w2.y + bc[10] * w2.z + bc[11] * w2.w
            + bc[12] * w3.x + bc[13] * w3.y + bc[14] * w3.z + bc[15] * w3.w;
        float dtv = softplus_f(dl);
        float xv  = bf2f(xp[(size_t)t * DI]);
        float dtx = dtv * xv;
        float acc = 0.f;
        if (fast) {
            float e1 = __expf(dtv * A0);
            float e = e1;
            #pragma unroll
            for (int n = 0; n < DS; n++) {
                h[n] = e * h[n] + dtx * bc[16 + n];
                acc += h[n] * bc[32 + n];
                e *= e1;
            }
        } else {
            #pragma unroll
            for (int n = 0; n < DS; n++) {
                h[n] = __expf(dtv * Av[n]) * h[n] + dtx * bc[16 + n];
                acc += h[n] * bc[32 + n];
            }
        }
        xp[(size_t)t * DI] = f2bf(acc + xv * Dd);
    }
}

// ---------------------------------------------------------------------------
extern "C" void kernel_launch(void* const* d_in, const int* in_sizes, int n_in,
                              void* d_out, int out_size, void* d_ws, size_t ws_size,
                              hipStream_t stream) {
    const float* x       = (const float*)d_in[0];
    const float* enc_w1  = (const float*)d_in[1];
    const float* enc_b1  = (const float*)d_in[2];
    const float* enc_w2  = (const float*)d_in[3];
    const float* enc_b2  = (const float*)d_in[4];
    const float* norm1_w = (const float*)d_in[5];
    const float* norm2_w = (const float*)d_in[6];
    const float* convd_w = (const float*)d_in[25];
    const float* convd_b = (const float*)d_in[26];
    const float* bn_g    = (const float*)d_in[27];
    const float* bn_b    = (const float*)d_in[28];
    const float* bn_mean = (const float*)d_in[29];
    const float* bn_var  = (const float*)d_in[30];
    const float* sp_w    = (const float*)d_in[31];
    const float* sp_b    = (const float*)d_in[32];
    float* out = (float*)d_out;

    const float* inW0   = (const float*)d_in[7];
    const float* cw0    = (const float*)d_in[8];
    const float* cb0    = (const float*)d_in[9];
    const float* xW0    = (const float*)d_in[10];
    const float* dtW0   = (const float*)d_in[11];
    const float* dtb0   = (const float*)d_in[12];
    const float* Alog0  = (const float*)d_in[13];
    const float* Dp0    = (const float*)d_in[14];
    const float* outW0  = (const float*)d_in[15];
    const float* inW1   = (const float*)d_in[16];
    const float* cw1    = (const float*)d_in[17];
    const float* cb1    = (const float*)d_in[18];
    const float* xW1    = (const float*)d_in[19];
    const float* dtW1   = (const float*)d_in[20];
    const float* dtb1   = (const float*)d_in[21];
    const float* Alog1  = (const float*)d_in[22];
    const float* Dp1    = (const float*)d_in[23];
    const float* outW1  = (const float*)d_in[24];

    // ---- workspace layout (float slots) ----
    float* ws = (float*)d_ws;
    size_t availf = ws_size / sizeof(float);
    size_t o = 0;
    float* t_buf  = ws + o; o += (size_t)BT * DM;       // enc f32; later mo1
    float* xn_buf = ws + o; o += (size_t)BT * DM;       // later: comb_bf overlay
    float* mo     = ws + o; o += (size_t)BT * DM;       // early: xt/e1t; late: d_bf overlay
    unsigned short* xn_bf = (unsigned short*)(ws + o); o += (size_t)BT * DM / 2;
    unsigned short* tb_bf = (unsigned short*)(ws + o); o += (size_t)BT * DM / 2;
    unsigned short* inW_bf2  = (unsigned short*)(ws + o); o += (size_t)1024 * DM;   // 2 dirs
    unsigned short* outW_bf2 = (unsigned short*)(ws + o); o += (size_t)DM * DI;     // 2 dirs
    unsigned short* xW_bc2   = (unsigned short*)(ws + o); o += (size_t)48 * DI;     // 2 dirs x 48x512
    unsigned short* W1r  = (unsigned short*)(ws + o); o += (3 * 128 * 64) / 2;
    unsigned short* W2r  = (unsigned short*)(ws + o); o += (3 * 256 * 128) / 2;
    unsigned short* Wdr  = (unsigned short*)(ws + o); o += (3 * 256 * 512) / 2;
    unsigned short* Wspr = (unsigned short*)(ws + o); o += (3 * 128 * 256) / 2;
    float* alpha_d = ws + o; o += 256;
    float* beta_d  = ws + o; o += 256;
    float* Aflag_d = ws + o; o += 4;
    size_t persist = o;
    float* scratch = ws + persist;
    size_t scratch_avail = (availf > persist) ? (availf - persist) : 0;
    // per-batch scratch for BOTH dirs (float slots)
    size_t per_b2 = 2 * ((size_t)T_LR * DI / 2 * 2 + (size_t)T_LR * 48
                         + (size_t)CH * DI * (DS + 1));
    int Bc = 16;
    while (Bc > 1 && (size_t)Bc * per_b2 > scratch_avail) Bc >>= 1;

    // encoder temporaries overlay mo (dead until out_proj)
    unsigned short* xt  = (unsigned short*)mo;                         // (b,T,64) bf16
    unsigned short* e1t = (unsigned short*)(mo + (size_t)BT * 64 / 2); // (b,T,128) bf16
    unsigned short* comb_bf = (unsigned short*)xn_buf;   // overlay after xn dead
    unsigned short* d_bf = (unsigned short*)mo;          // overlay after mo dead

    // single mega prep dispatch
    k_prep<<<4994, 256, 0, stream>>>(enc_w1, enc_w2, convd_w, sp_w,
                                     convd_b, bn_g, bn_b, bn_mean, bn_var,
                                     inW0, inW1, outW0, outW1, xW0, xW1,
                                     Alog0, Alog1,
                                     x, W1r, W2r, Wdr, Wspr, alpha_d, beta_d,
                                     inW_bf2, outW_bf2, xW_bc2, Aflag_d, xt);

    // encoder (M-tile = 128 rows)
    k_conv3_bf<<<dim3(BT / 128, 1), 256, 0, stream>>>(xt, 64, nullptr, 0, W1r,
                                                      nullptr, enc_b1, nullptr, e1t, 128, 1, 0);
    k_conv3_bf<<<dim3(BT / 128, 2), 256, 0, stream>>>(e1t, 128, nullptr, 0, W2r,
                                                      nullptr, enc_b2, t_buf, tb_bf, 256, 1, 0);
    k_rmsnorm<<<BT / 4, 256, 0, stream>>>(t_buf, nullptr, norm1_w, xn_buf, xn_bf, BT);

    // mamba: both directions per dispatch (dir = blockIdx.z / doubled bl).
    long long dsMo1 = (long long)(t_buf - mo);
    for (int b0 = 0; b0 < B_SZ; b0 += Bc) {
        int Tc = Bc * T_LR;
        long long TcDI = (long long)Tc * DI;
        unsigned short* xcs = (unsigned short*)scratch;              // [2][Tc][DI] bf16
        unsigned short* ygb = xcs + (size_t)2 * Tc * DI;             // [2][Tc][DI] bf16
        float* db   = (float*)(ygb + (size_t)2 * Tc * DI);           // [2][Tc][48]
        float* hS   = db + (size_t)2 * Tc * 48;                      // [2Bc][CH][DI][DS]
        float* csum = hS + (size_t)2 * Bc * CH * DI * DS;            // [2Bc][CH][DI]
        const float*          xnC  = xn_buf + (size_t)b0 * T_LR * DM;
        const unsigned short* xnbC = xn_bf  + (size_t)b0 * T_LR * DM;
        float*                moC  = mo     + (size_t)b0 * T_LR * DM;
        // fused in_proj(xc) + causal dwconv + silu -> xcs bf16 (both dirs)
        k_inproj_conv<<<dim3(Tc / 128, DI / 128, 2), 256, 0, stream>>>(
            xnbC, inW_bf2, cw0, cw1, cb0, cb1, xcs, TcDI);
        // db (dt_low,B,C) = xcs @ xW[0:48]^T -> fp32 (both dirs)
        k_gemm_bf<<<dim3(Tc / 128, 1, 2), 256, 0, stream>>>(
            xcs, DI, TcDI, xW_bc2, (long long)48 * DI,
            db, (long long)Tc * 48, 48, nullptr, DI, 48, 0);
        // chunked scan, both dirs
        k_scan_p1<<<(2 * Bc * CH * DI) / 256, 256, 0, stream>>>(
            xcs, db, dtW0, dtW1, dtb0, dtb1, Alog0, Alog1, Aflag_d, hS, csum, Bc);
        k_scan_p2<<<(2 * Bc * DI * DS) / 256, 256, 0, stream>>>(
            hS, csum, Alog0, Alog1, Bc);
        k_scan_p3<<<(2 * Bc * CH * DI) / 256, 256, 0, stream>>>(
            xcs, db, dtW0, dtW1, dtb0, dtb1, Alog0, Alog1, Aflag_d, Dp0, Dp1, hS, Bc);
        // z GEMM + gate: yg = bf16(silu(z) * y), both dirs
        k_gemm_bf_cb<<<dim3(Tc / 128, DI / 128, 2), 256, 0, stream>>>(
            xnbC, DM, inW_bf2 + (size_t)DI * DM, (long long)1024 * DM,
            ygb, DI, TcDI, xcs, TcDI, DM);
        // out_proj: dir0 -> mo = yg@outW^T + xn; dir1 -> mo1 (crev)
        k_gemm_bf<<<dim3(Tc / 128, DM / 128, 2), 256, 0, stream>>>(
            ygb, DI, TcDI, outW_bf2, (long long)DM * DI,
            moC, dsMo1, DM, xnC, DI, DM, 2);
    }

    // combined = rmsnorm(mo + mo1) -> comb_bf (xn_buf overlay)
    k_rmsnorm<<<BT / 4, 256, 0, stream>>>(mo, t_buf, norm2_w, nullptr, comb_bf, BT);
    // convd + bn + silu -> d_bf (mo overlay)
    k_conv3_bf<<<dim3(BT / 128, 2), 256, 0, stream>>>(comb_bf, 256, tb_bf, 256, Wdr,
                                                      alpha_d, beta_d, nullptr, d_bf, 256, 1, 0);
    // sp conv + pixel shuffle -> out
    k_conv3_bf<<<dim3(BT / 128, 1), 256, 0, stream>>>(d_bf, 256, nullptr, 0, Wspr,
                                                      nullptr, sp_b, out, nullptr, 128, 0, 1);
}

// Round 11
// 1158.921 us; speedup vs baseline: 1.0068x; 1.0068x over previous
//
#include <hip/hip_runtime.h>
#include <hip/hip_bf16.h>
#include <math.h>

#define B_SZ 16
#define T_LR 2560
#define BT (B_SZ * T_LR)     // 40960 tokens
#define DM 256               // d_model
#define DI 512               // d_inner
#define DS 16                // d_state
#define DTR 16               // dt_rank
#define CH 128               // scan chunks per sequence
#define CH_LOG2 7
#define CLEN (T_LR / CH)     // 20 steps per chunk

typedef __attribute__((ext_vector_type(8))) short bf16x8;
typedef __attribute__((ext_vector_type(4))) float f32x4;

__device__ __forceinline__ float silu_f(float x) {
    return x / (1.f + __expf(-x));
}
__device__ __forceinline__ unsigned short f2bf(float v) {
    __hip_bfloat16 h = __float2bfloat16(v);
    return *(unsigned short*)&h;
}
__device__ __forceinline__ float bf2f(unsigned short u) {
    union { unsigned int i; float f; } c;
    c.i = (unsigned int)u << 16;
    return c.f;
}
__device__ __forceinline__ int seqrev(int r) {
    int s = r / T_LR, t = r % T_LR;
    return s * T_LR + (T_LR - 1 - t);
}
// softplus: log(1+e). abs err ~1e-7 (vs log1pf) — negligible vs bf16 rounding.
__device__ __forceinline__ float softplus_f(float x) {
    return (x > 20.f) ? x : __logf(1.f + __expf(x));
}
// fragment-major weight swizzle: tile (tap, n/16, c/32) stores 64 lanes x 16B
// contiguously; lane (q=c5>>3, ml=n&15) gets W[n][c...c+7]. One B-fragment
// load becomes a contiguous 1KB burst (16 full lines) instead of 16 scattered
// 1KB-apart probes.
__device__ __forceinline__ size_t wswz_idx(int tap, int n, int c, int N, int Kt) {
    return ((size_t)((tap * (N >> 4) + (n >> 4)) * (Kt >> 5) + (c >> 5)) << 9)
         + (size_t)((((c >> 3) & 3) * 16 + (n & 15)) * 8 + (c & 7));
}

// ---------------------------------------------------------------------------
// mega prep kernel: all weight transforms + input transpose, one dispatch.
// ---------------------------------------------------------------------------
__global__ __launch_bounds__(256) void k_prep(
    const float* __restrict__ enc_w1, const float* __restrict__ enc_w2,
    const float* __restrict__ convd_w, const float* __restrict__ sp_w,
    const float* __restrict__ convd_b, const float* __restrict__ bn_g,
    const float* __restrict__ bn_b, const float* __restrict__ bn_mean,
    const float* __restrict__ bn_var,
    const float* __restrict__ inW0, const float* __restrict__ inW1,
    const float* __restrict__ outW0, const float* __restrict__ outW1,
    const float* __restrict__ xW0, const float* __restrict__ xW1,
    const float* __restrict__ Alog0, const float* __restrict__ Alog1,
    const float* __restrict__ x,
    unsigned short* __restrict__ W1r, unsigned short* __restrict__ W2r,
    unsigned short* __restrict__ Wdr, unsigned short* __restrict__ Wspr,
    float* __restrict__ alpha, float* __restrict__ beta,
    unsigned short* __restrict__ inW_bf2, unsigned short* __restrict__ outW_bf2,
    unsigned short* __restrict__ xW_bc2, float* __restrict__ Aflag,
    unsigned short* __restrict__ xt)
{
    __shared__ float ts[32][33];
    __shared__ int s_ok;
    int blk = blockIdx.x;
    int tid = threadIdx.x;
    if (blk < 32) {                         // W1r: (128,64,3) -> swizzled [N=128,Kt=64]
        int i = blk * 256 + tid;
        int n = i / 64, ci = i % 64;
        #pragma unroll
        for (int k = 0; k < 3; k++)
            W1r[wswz_idx(k, n, ci, 128, 64)] = f2bf(enc_w1[((size_t)n * 64 + ci) * 3 + k]);
    } else if (blk < 160) {                 // W2r: (256,128,3) -> [N=256,Kt=128]
        int i = (blk - 32) * 256 + tid;
        int n = i / 128, ci = i % 128;
        #pragma unroll
        for (int k = 0; k < 3; k++)
            W2r[wswz_idx(k, n, ci, 256, 128)] = f2bf(enc_w2[((size_t)n * 128 + ci) * 3 + k]);
    } else if (blk < 672) {                 // Wdr: (256,512,3) -> [N=256,Kt=512]
        int i = (blk - 160) * 256 + tid;
        int n = i / 512, ci = i % 512;
        #pragma unroll
        for (int k = 0; k < 3; k++)
            Wdr[wswz_idx(k, n, ci, 256, 512)] = f2bf(convd_w[((size_t)n * 512 + ci) * 3 + k]);
    } else if (blk < 800) {                 // Wspr: (128,256,3) -> [N=128,Kt=256]
        int i = (blk - 672) * 256 + tid;
        int n = i / 256, ci = i % 256;
        #pragma unroll
        for (int k = 0; k < 3; k++)
            Wspr[wswz_idx(k, n, ci, 128, 256)] = f2bf(sp_w[((size_t)n * 256 + ci) * 3 + k]);
    } else if (blk < 801) {                 // bnfold
        int c = tid;
        float a = bn_g[c] * rsqrtf(bn_var[c] + 1e-5f);
        alpha[c] = a;
        beta[c] = (convd_b[c] - bn_mean[c]) * a + bn_b[c];
    } else if (blk < 1825) {                // inW cast, both dirs (262144 each)
        int i = (blk - 801) * 256 + tid;
        inW_bf2[i] = f2bf(inW0[i]);
        inW_bf2[262144 + i] = f2bf(inW1[i]);
    } else if (blk < 2337) {                // outW cast (131072 each)
        int i = (blk - 1825) * 256 + tid;
        outW_bf2[i] = f2bf(outW0[i]);
        outW_bf2[131072 + i] = f2bf(outW1[i]);
    } else if (blk < 2433) {                // xW[0:48] cast (24576 each dir)
        int i = (blk - 2337) * 256 + tid;
        xW_bc2[i] = f2bf(xW0[i]);
        xW_bc2[24576 + i] = f2bf(xW1[i]);
    } else if (blk < 2434) {                // Alog structure check: A[d][n] == A[d][0]*(n+1)?
        if (tid == 0) s_ok = 1;
        __syncthreads();
        int ok = 1;
        for (int i = tid; i < DI * DS; i += 256) {
            int d = i >> 4, n = i & 15;
            float a0f = __expf(Alog0[d * DS]);
            float anf = __expf(Alog0[d * DS + n]);
            if (fabsf(anf - (float)(n + 1) * a0f) > 1e-3f * (float)(n + 1)) ok = 0;
            float a0b = __expf(Alog1[d * DS]);
            float anb = __expf(Alog1[d * DS + n]);
            if (fabsf(anb - (float)(n + 1) * a0b) > 1e-3f * (float)(n + 1)) ok = 0;
        }
        if (!ok) atomicAnd(&s_ok, 0);
        __syncthreads();
        if (tid == 0) Aflag[0] = s_ok ? 1.f : 0.f;
    } else {                                // transpose x (b,64,T) f32 -> xt (b,T,64) bf16
        int idx = blk - 2434;               // b(16) x c0(2) x t0(80)
        int t0 = (idx % 80) * 32;
        int c0 = ((idx / 80) & 1) * 32;
        int b = idx / 160;
        int tx = tid & 31, ty = tid >> 5;
        #pragma unroll
        for (int j = 0; j < 4; j++) {
            int c = c0 + ty + j * 8;
            ts[ty + j * 8][tx] = x[((size_t)b * 64 + c) * T_LR + t0 + tx];
        }
        __syncthreads();
        #pragma unroll
        for (int j = 0; j < 4; j++) {
            int t = t0 + ty + j * 8;
            xt[((size_t)b * T_LR + t) * 64 + c0 + tx] = f2bf(ts[tx][ty + j * 8]);
        }
    }
}

// ---------------------------------------------------------------------------
// implicit-GEMM k=3 "same" conv via MFMA (encoder/decoder convs).
// M-tile = 128 rows; As double-buffered, one barrier per k-step.
// R9 (proven best, 76us convd): (1) B loads from fragment-major swizzled
// weights — contiguous 1KB per load instruction, L1-friendly; (2) epilogue
// transposes through LDS for coalesced vectorized stores. R10's
// global_load_lds variant regressed (59.9KB LDS cut occupancy; DMA bypassed
// L1 dedup, FETCH +7.5MB) — reverted.
// ---------------------------------------------------------------------------
__global__ __launch_bounds__(256, 3) void k_conv3_bf(const unsigned short* __restrict__ A1, int K1,
                                                  const unsigned short* __restrict__ A2, int K2,
                                                  const unsigned short* __restrict__ Wz,
                                                  const float* __restrict__ alpha,
                                                  const float* __restrict__ beta,
                                                  float* __restrict__ outf,
                                                  unsigned short* __restrict__ outb,
                                                  int N, int dosilu, int pixsh) {
    int Kt = K1 + K2;
    __shared__ __align__(16) unsigned short smem[2 * 130 * 40];   // 20800 B
    unsigned short (*As)[130][40] = (unsigned short (*)[130][40])smem;
    float* sC = (float*)smem;                                     // 32 x 140 f32 (17920 B)
    int tid = threadIdx.x;
    int wave = tid >> 6, lane = tid & 63;
    int wm = (wave >> 1) * 64, wn = (wave & 1) * 64;
    int m0 = blockIdx.x * 128, n0 = blockIdx.y * 128;
    int b = m0 / T_LR, t0 = m0 % T_LR;
    int q = lane >> 4, ml = lane & 15;
    int Nb16 = N >> 4, Kb32 = Kt >> 5;
    int nb0 = (n0 + wn) >> 4;
    const unsigned short* wl = Wz + (size_t)lane * 8;
    f32x4 acc[4][4] = {};
    int cq = tid & 3;
    int r0 = tid >> 2;
    int r1 = r0 + 64;
    int r2 = r0 + 128;
    bool has2 = (tid < 8);
    int ta0 = t0 - 1 + r0, ta1 = t0 - 1 + r1, ta2 = t0 - 1 + r2;
    bool va0 = (ta0 >= 0) && (ta0 < T_LR);
    bool va1 = (ta1 < T_LR);
    bool va2 = has2 && (ta2 < T_LR);
    uint4 v0, v1, v2;
    #define LOADA(vv, valid, t, col) { vv = make_uint4(0u,0u,0u,0u); if (valid) { \
        const unsigned short* src = ((col) < K1) \
            ? A1 + (size_t)(b * T_LR + (t)) * K1 + (col) \
            : A2 + (size_t)(b * T_LR + (t)) * K2 + ((col) - K1); \
        vv = *(const uint4*)src; } }
    LOADA(v0, va0, ta0, cq * 8);
    LOADA(v1, va1, ta1, cq * 8);
    LOADA(v2, va2, ta2, cq * 8);
    *(uint4*)&As[0][r0][cq * 8] = v0;
    *(uint4*)&As[0][r1][cq * 8] = v1;
    if (has2) *(uint4*)&As[0][r2][cq * 8] = v2;
    int nk = Kb32;
    for (int kk = 0; kk < nk; kk++) {
        __syncthreads();
        int cur = kk & 1;
        if (kk + 1 < nk) {
            int col = ((kk + 1) << 5) + cq * 8;
            LOADA(v0, va0, ta0, col);
            LOADA(v1, va1, ta1, col);
            LOADA(v2, va2, ta2, col);
        }
        #pragma unroll
        for (int tap = 0; tap < 3; tap++) {
            int tb = tap * Nb16 + nb0;
            bf16x8 bfr[4];
            #pragma unroll
            for (int ni = 0; ni < 4; ni++)
                bfr[ni] = *(const bf16x8*)(wl + ((size_t)((tb + ni) * Kb32 + kk) << 9));
            #pragma unroll
            for (int mi = 0; mi < 4; mi++) {
                bf16x8 af = *(const bf16x8*)&As[cur][wm + mi * 16 + ml + tap][q * 8];
                #pragma unroll
                for (int ni = 0; ni < 4; ni++)
                    acc[mi][ni] = __builtin_amdgcn_mfma_f32_16x16x32_bf16(af, bfr[ni], acc[mi][ni], 0, 0, 0);
            }
        }
        if (kk + 1 < nk) {
            *(uint4*)&As[cur ^ 1][r0][cq * 8] = v0;
            *(uint4*)&As[cur ^ 1][r1][cq * 8] = v1;
            if (has2) *(uint4*)&As[cur ^ 1][r2][cq * 8] = v2;
        }
    }
    #undef LOADA
    // epilogue: 4 passes of 32 rows through LDS (reuses As space), coalesced
    // vectorized stores.
    int rowoff = m0 - b * T_LR;   // local t of row 0
    #pragma unroll
    for (int p = 0; p < 4; p++) {
        __syncthreads();
        if ((wave >> 1) == (p >> 1)) {
            int mib = (p & 1) * 2;
            #pragma unroll
            for (int m2 = 0; m2 < 2; m2++) {
                int mi = mib + m2;
                int rl = mi * 16 + q * 4 - (p & 1) * 32;
                #pragma unroll
                for (int r = 0; r < 4; r++)
                    #pragma unroll
                    for (int ni = 0; ni < 4; ni++)
                        sC[(rl + r) * 140 + wn + ni * 16 + ml] = acc[mi][ni][r];
            }
        }
        __syncthreads();
        if (pixsh) {
            // N=128, n0=0: col=2*c2+rr -> out[((b*64+c2)*T + t)*2 + rr]
            int row = tid & 31, c2g = tid >> 5;
            int t = rowoff + p * 32 + row;
            float* dst = outf + ((size_t)b * 64 * T_LR + t) * 2;
            #pragma unroll
            for (int j = 0; j < 8; j++) {
                int c2 = c2g + j * 8;
                float va = sC[row * 140 + 2 * c2]     + beta[2 * c2];
                float vb = sC[row * 140 + 2 * c2 + 1] + beta[2 * c2 + 1];
                *(float2*)&dst[(size_t)c2 * T_LR * 2] = make_float2(va, vb);
            }
        } else {
            #pragma unroll
            for (int gi = 0; gi < 2; gi++) {
                int g = tid + gi * 256;
                int row = g >> 4;
                int colg = (g & 15) * 8;
                int mr = m0 + p * 32 + row;
                const float* src = sC + row * 140 + colg;
                float vv[8];
                *(float4*)&vv[0] = *(const float4*)src;
                *(float4*)&vv[4] = *(const float4*)(src + 4);
                unsigned short ob[8];
                #pragma unroll
                for (int jj = 0; jj < 8; jj++) {
                    int col = n0 + colg + jj;
                    float a = alpha ? alpha[col] : 1.f;
                    float v = vv[jj] * a + beta[col];
                    if (dosilu) v = silu_f(v);
                    vv[jj] = v;
                    ob[jj] = f2bf(v);
                }
                if (outf) {
                    *(float4*)(outf + (size_t)mr * N + n0 + colg) = *(float4*)&vv[0];
                    *(float4*)(outf + (size_t)mr * N + n0 + colg + 4) = *(float4*)&vv[4];
                }
                if (outb)
                    *(uint4*)(outb + (size_t)mr * N + n0 + colg) = *(uint4*)ob;
            }
        }
    }
}

// ---------------------------------------------------------------------------
// fused in_proj (xc half) + causal depthwise conv k=4 + silu -> xcs bf16.
// BOTH directions in one dispatch: dir = blockIdx.z selects weights/output.
// ---------------------------------------------------------------------------
__global__ __launch_bounds__(256) void k_inproj_conv(const unsigned short* __restrict__ xn,
                                                     const unsigned short* __restrict__ inW2,
                                                     const float* __restrict__ cw0,
                                                     const float* __restrict__ cw1,
                                                     const float* __restrict__ cb0,
                                                     const float* __restrict__ cb1,
                                                     unsigned short* __restrict__ xcs,
                                                     long long dsXcs) {
    __shared__ unsigned short As[128][40];
    __shared__ unsigned short Bs[128][40];
    __shared__ unsigned short Ct[131][136];   // rows: internal t0-3 .. t0+127
    int dir = blockIdx.z;
    int arev = dir;
    const unsigned short* inW = inW2 + (size_t)dir * 1024 * DM;
    const float* cw = dir ? cw1 : cw0;
    const float* cb = dir ? cb1 : cb0;
    xcs += (size_t)dir * dsXcs;
    int tid = threadIdx.x;
    int wave = tid >> 6, lane = tid & 63;
    int wm = (wave >> 1) * 64, wn = (wave & 1) * 64;
    int m0 = blockIdx.x * 128, n0 = blockIdx.y * 128;
    int b = m0 / T_LR, t0 = m0 % T_LR;
    int sc = tid & 3, sr = tid >> 2;
    int ar0 = m0 + sr, ar1 = m0 + sr + 64;
    if (arev) { ar0 = seqrev(ar0); ar1 = seqrev(ar1); }
    const unsigned short* ap0 = xn + (size_t)ar0 * DM + sc * 8;
    const unsigned short* ap1 = xn + (size_t)ar1 * DM + sc * 8;
    const unsigned short* bp0 = inW + (size_t)(n0 + sr) * DM + sc * 8;
    const unsigned short* bp1 = inW + (size_t)(n0 + sr + 64) * DM + sc * 8;
    f32x4 acc[4][4] = {};
    int q = lane >> 4, ml = lane & 15;
    for (int k0 = 0; k0 < DM; k0 += 32) {
        uint4 a0 = *(const uint4*)(ap0 + k0);
        uint4 a1 = *(const uint4*)(ap1 + k0);
        uint4 b0 = *(const uint4*)(bp0 + k0);
        uint4 b1 = *(const uint4*)(bp1 + k0);
        __syncthreads();
        *(uint4*)&As[sr][sc * 8]      = a0;
        *(uint4*)&As[sr + 64][sc * 8] = a1;
        *(uint4*)&Bs[sr][sc * 8]      = b0;
        *(uint4*)&Bs[sr + 64][sc * 8] = b1;
        __syncthreads();
        bf16x8 af[4], bfr[4];
        #pragma unroll
        for (int mi = 0; mi < 4; mi++)
            af[mi] = *(const bf16x8*)&As[wm + mi * 16 + ml][q * 8];
        #pragma unroll
        for (int ni = 0; ni < 4; ni++)
            bfr[ni] = *(const bf16x8*)&Bs[wn + ni * 16 + ml][q * 8];
        #pragma unroll
        for (int mi = 0; mi < 4; mi++)
            #pragma unroll
            for (int ni = 0; ni < 4; ni++)
                acc[mi][ni] = __builtin_amdgcn_mfma_f32_16x16x32_bf16(af[mi], bfr[ni], acc[mi][ni], 0, 0, 0);
    }
    // main tile -> Ct rows 3..130
    #pragma unroll
    for (int mi = 0; mi < 4; mi++)
        #pragma unroll
        for (int r = 0; r < 4; r++)
            #pragma unroll
            for (int ni = 0; ni < 4; ni++)
                Ct[3 + wm + mi * 16 + q * 4 + r][wn + ni * 16 + ml] = f2bf(acc[mi][ni][r]);
    // halo rows 0..2 via direct dot — 384 items on 256 threads
    for (int i = tid; i < 384; i += 256) {
        int hr = i >> 7, c = i & 127;
        int tr = t0 - 3 + hr;
        float v = 0.f;
        if (tr >= 0) {
            int src = b * T_LR + (arev ? (T_LR - 1 - tr) : tr);
            const unsigned short* xr = xn + (size_t)src * DM;
            const unsigned short* wr = inW + (size_t)(n0 + c) * DM;
            for (int k = 0; k < DM; k += 8) {
                uint4 xa = *(const uint4*)(xr + k);
                uint4 wa = *(const uint4*)(wr + k);
                const unsigned short* xs = (const unsigned short*)&xa;
                const unsigned short* wsp = (const unsigned short*)&wa;
                #pragma unroll
                for (int j = 0; j < 8; j++) v += bf2f(xs[j]) * bf2f(wsp[j]);
            }
        }
        Ct[hr][c] = f2bf(v);
    }
    __syncthreads();
    // causal conv k=4 + silu, write xcs bf16
    int col = tid & 127;
    int d = n0 + col;
    float w0 = cw[d * 4 + 0], w1 = cw[d * 4 + 1], w2 = cw[d * 4 + 2], w3 = cw[d * 4 + 3];
    float bi = cb[d];
    int rbase = tid >> 7;
    for (int j = 0; j < 64; j++) {
        int row = rbase + 2 * j;
        float v = bi + bf2f(Ct[row][col]) * w0 + bf2f(Ct[row + 1][col]) * w1
                     + bf2f(Ct[row + 2][col]) * w2 + bf2f(Ct[row + 3][col]) * w3;
        xcs[(size_t)(m0 + row) * DI + d] = f2bf(silu_f(v));
    }
}

// ---------------------------------------------------------------------------
// rmsnorm over last dim (256). One wave per token. Optional second input
// summed in (mo + mo1). fp32 and/or bf16 out.
// ---------------------------------------------------------------------------
__global__ __launch_bounds__(256) void k_rmsnorm(const float* __restrict__ in1,
                                                 const float* __restrict__ in2,
                                                 const float* __restrict__ w,
                                                 float* __restrict__ out,
                                                 unsigned short* __restrict__ out_bf,
                                                 int ntok) {
    int tok = (blockIdx.x * 256 + threadIdx.x) >> 6;
    int lane = threadIdx.x & 63;
    if (tok >= ntok) return;
    float4 v = ((const float4*)(in1 + (size_t)tok * DM))[lane];
    if (in2) {
        float4 u = ((const float4*)(in2 + (size_t)tok * DM))[lane];
        v.x += u.x; v.y += u.y; v.z += u.z; v.w += u.w;
    }
    float ss = v.x * v.x + v.y * v.y + v.z * v.z + v.w * v.w;
    #pragma unroll
    for (int off = 32; off > 0; off >>= 1) ss += __shfl_xor(ss, off);
    float sc = rsqrtf(ss * (1.f / 256.f) + 1e-6f);
    float4 wv = ((const float4*)w)[lane];
    float4 o;
    o.x = v.x * sc * wv.x; o.y = v.y * sc * wv.y;
    o.z = v.z * sc * wv.z; o.w = v.w * sc * wv.w;
    if (out) ((float4*)(out + (size_t)tok * DM))[lane] = o;
    if (out_bf) {
        ushort4 ob;
        ob.x = f2bf(o.x); ob.y = f2bf(o.y); ob.z = f2bf(o.z); ob.w = f2bf(o.w);
        ((ushort4*)(out_bf + (size_t)tok * DM))[lane] = ob;
    }
}

// ---------------------------------------------------------------------------
// bf16 MFMA GEMM, fp32 out + optional residual (db and out_proj).
// BOTH directions per dispatch: dir = blockIdx.z applies element strides.
// crevmode: 0 = never reverse output rows, 2 = reverse iff dir==1.
// ---------------------------------------------------------------------------
__global__ __launch_bounds__(256) void k_gemm_bf(const unsigned short* __restrict__ A, int lda, long long dsA,
                                                 const unsigned short* __restrict__ Bw, long long dsB,
                                                 float* Cf, long long dsCf, int ldc,
                                                 const float* __restrict__ res,
                                                 int K, int Nout, int crevmode) {
    __shared__ unsigned short As[128][40];
    __shared__ unsigned short Bs[128][40];
    int dir = blockIdx.z;
    A += (long long)dir * dsA;
    Bw += (long long)dir * dsB;
    Cf += (long long)dir * dsCf;
    int crev = (crevmode == 2) ? dir : crevmode;
    int tid = threadIdx.x;
    int wave = tid >> 6, lane = tid & 63;
    int wm = (wave >> 1) * 64, wn = (wave & 1) * 64;
    int m0 = blockIdx.x * 128, n0 = blockIdx.y * 128;
    int sc = tid & 3, sr = tid >> 2;
    const unsigned short* ap0 = A + (size_t)(m0 + sr) * lda + sc * 8;
    const unsigned short* ap1 = A + (size_t)(m0 + sr + 64) * lda + sc * 8;
    bool bv0 = (n0 + sr) < Nout;
    bool bv1 = (n0 + sr + 64) < Nout;
    const unsigned short* bp0 = Bw + (size_t)(n0 + sr) * K + sc * 8;
    const unsigned short* bp1 = Bw + (size_t)(n0 + sr + 64) * K + sc * 8;
    f32x4 acc[4][4] = {};
    int q = lane >> 4, ml = lane & 15;
    for (int k0 = 0; k0 < K; k0 += 32) {
        uint4 a0 = *(const uint4*)(ap0 + k0);
        uint4 a1 = *(const uint4*)(ap1 + k0);
        uint4 b0 = make_uint4(0u, 0u, 0u, 0u), b1 = make_uint4(0u, 0u, 0u, 0u);
        if (bv0) b0 = *(const uint4*)(bp0 + k0);
        if (bv1) b1 = *(const uint4*)(bp1 + k0);
        __syncthreads();
        *(uint4*)&As[sr][sc * 8]      = a0;
        *(uint4*)&As[sr + 64][sc * 8] = a1;
        *(uint4*)&Bs[sr][sc * 8]      = b0;
        *(uint4*)&Bs[sr + 64][sc * 8] = b1;
        __syncthreads();
        bf16x8 af[4], bfr[4];
        #pragma unroll
        for (int mi = 0; mi < 4; mi++)
            af[mi] = *(const bf16x8*)&As[wm + mi * 16 + ml][q * 8];
        #pragma unroll
        for (int ni = 0; ni < 4; ni++)
            bfr[ni] = *(const bf16x8*)&Bs[wn + ni * 16 + ml][q * 8];
        #pragma unroll
        for (int mi = 0; mi < 4; mi++)
            #pragma unroll
            for (int ni = 0; ni < 4; ni++)
                acc[mi][ni] = __builtin_amdgcn_mfma_f32_16x16x32_bf16(af[mi], bfr[ni], acc[mi][ni], 0, 0, 0);
    }
    #pragma unroll
    for (int mi = 0; mi < 4; mi++) {
        #pragma unroll
        for (int r = 0; r < 4; r++) {
            int mr = m0 + wm + mi * 16 + q * 4 + r;
            int orow = crev ? seqrev(mr) : mr;
            #pragma unroll
            for (int ni = 0; ni < 4; ni++) {
                int col = n0 + wn + ni * 16 + ml;
                if (col < Nout) {
                    float v = acc[mi][ni][r];
                    if (res) v += res[(size_t)orow * ldc + col];
                    Cf[(size_t)orow * ldc + col] = v;
                }
            }
        }
    }
}

// ---------------------------------------------------------------------------
// bf16-out MFMA GEMM with LDS-transposed vectorized epilogue (z-gate).
// BOTH directions per dispatch: dir = blockIdx.z; A (xn) shared; arev = dir.
// ---------------------------------------------------------------------------
__global__ __launch_bounds__(256) void k_gemm_bf_cb(const unsigned short* __restrict__ A, int lda,
                                                    const unsigned short* __restrict__ Bw, long long dsB,
                                                    unsigned short* __restrict__ Cb, int ldc, long long dsCb,
                                                    const unsigned short* __restrict__ gate, long long dsGate,
                                                    int K) {
    __shared__ __align__(16) unsigned short smem[2 * 128 * 40];   // 20480 B
    unsigned short (*As)[40] = (unsigned short(*)[40])smem;
    unsigned short (*Bs)[40] = (unsigned short(*)[40])(smem + 128 * 40);
    float* sC = (float*)smem;                                     // 32 x 140 f32
    int dir = blockIdx.z;
    int arev = dir;
    Bw += (long long)dir * dsB;
    Cb += (long long)dir * dsCb;
    gate += (long long)dir * dsGate;
    int tid = threadIdx.x;
    int wave = tid >> 6, lane = tid & 63;
    int wm = (wave >> 1) * 64, wn = (wave & 1) * 64;
    int m0 = blockIdx.x * 128, n0 = blockIdx.y * 128;
    int sc = tid & 3, sr = tid >> 2;
    int ar0 = m0 + sr, ar1 = m0 + sr + 64;
    if (arev) { ar0 = seqrev(ar0); ar1 = seqrev(ar1); }
    const unsigned short* ap0 = A + (size_t)ar0 * lda + sc * 8;
    const unsigned short* ap1 = A + (size_t)ar1 * lda + sc * 8;
    const unsigned short* bp0 = Bw + (size_t)(n0 + sr) * K + sc * 8;
    const unsigned short* bp1 = Bw + (size_t)(n0 + sr + 64) * K + sc * 8;
    f32x4 acc[4][4] = {};
    int q = lane >> 4, ml = lane & 15;
    for (int k0 = 0; k0 < K; k0 += 32) {
        uint4 a0 = *(const uint4*)(ap0 + k0);
        uint4 a1 = *(const uint4*)(ap1 + k0);
        uint4 b0 = *(const uint4*)(bp0 + k0);
        uint4 b1 = *(const uint4*)(bp1 + k0);
        __syncthreads();
        *(uint4*)&As[sr][sc * 8]      = a0;
        *(uint4*)&As[sr + 64][sc * 8] = a1;
        *(uint4*)&Bs[sr][sc * 8]      = b0;
        *(uint4*)&Bs[sr + 64][sc * 8] = b1;
        __syncthreads();
        bf16x8 af[4], bfr[4];
        #pragma unroll
        for (int mi = 0; mi < 4; mi++)
            af[mi] = *(const bf16x8*)&As[wm + mi * 16 + ml][q * 8];
        #pragma unroll
        for (int ni = 0; ni < 4; ni++)
            bfr[ni] = *(const bf16x8*)&Bs[wn + ni * 16 + ml][q * 8];
        #pragma unroll
        for (int mi = 0; mi < 4; mi++)
            #pragma unroll
            for (int ni = 0; ni < 4; ni++)
                acc[mi][ni] = __builtin_amdgcn_mfma_f32_16x16x32_bf16(af[mi], bfr[ni], acc[mi][ni], 0, 0, 0);
    }
    // epilogue: 4 passes of 32 rows through LDS (stride 140 f32)
    #pragma unroll
    for (int p = 0; p < 4; p++) {
        __syncthreads();
        if ((wave >> 1) == (p >> 1)) {
            int mib = (p & 1) * 2;
            #pragma unroll
            for (int m2 = 0; m2 < 2; m2++) {
                int mi = mib + m2;
                int rl = mi * 16 + q * 4 - (p & 1) * 32;
                #pragma unroll
                for (int r = 0; r < 4; r++)
                    #pragma unroll
                    for (int ni = 0; ni < 4; ni++)
                        sC[(rl + r) * 140 + wn + ni * 16 + ml] = acc[mi][ni][r];
            }
        }
        __syncthreads();
        #pragma unroll
        for (int gi = 0; gi < 2; gi++) {
            int g = tid + gi * 256;
            int row = g >> 4;
            int colg = (g & 15) * 8;
            int grow = m0 + p * 32 + row;
            const float* src = sC + row * 140 + colg;
            float4 v0 = *(const float4*)src;
            float4 v1 = *(const float4*)(src + 4);
            float vv[8] = {v0.x, v0.y, v0.z, v0.w, v1.x, v1.y, v1.z, v1.w};
            unsigned short gu[8];
            *(uint4*)gu = *(const uint4*)(gate + (size_t)grow * ldc + n0 + colg);
            unsigned short o[8];
            #pragma unroll
            for (int jj = 0; jj < 8; jj++) {
                float v = vv[jj];
                v = silu_f(v) * bf2f(gu[jj]);
                o[jj] = f2bf(v);
            }
            *(uint4*)(Cb + (size_t)grow * ldc + n0 + colg) = *(uint4*)o;
        }
    }
}

// ---------------------------------------------------------------------------
// scan phase 1: per (dir*bl, chunk, d) thread. Both dirs in one dispatch:
// buffers laid [2*Bc][...]; dir = (bl >= Bc) selects the weight set.
// dt computed in-line (low-rank); fast path when Aflag set.
// ---------------------------------------------------------------------------
__global__ __launch_bounds__(256) void k_scan_p1(const unsigned short* __restrict__ x,
                                                 const float* __restrict__ db,
                                                 const float* __restrict__ dtW0, const float* __restrict__ dtW1,
                                                 const float* __restrict__ dtb0, const float* __restrict__ dtb1,
                                                 const float* __restrict__ Alog0, const float* __restrict__ Alog1,
                                                 const float* __restrict__ Aflag,
                                                 float* __restrict__ hS,
                                                 float* __restrict__ csum, int Bc) {
    __shared__ float dbs[CLEN * 48];
    int tid = threadIdx.x;
    int gid = blockIdx.x * 256 + tid;   // ((dir*Bc+bl)*CH + c)*DI + d
    int d = gid & (DI - 1);
    int bcix = gid >> 9;
    int c = bcix & (CH - 1);
    int bl = bcix >> CH_LOG2;           // [0, 2*Bc)
    int dir = (bl >= Bc) ? 1 : 0;
    const float* dtW  = dir ? dtW1  : dtW0;
    const float* dtb  = dir ? dtb1  : dtb0;
    const float* Alog = dir ? Alog1 : Alog0;
    int tbase = c * CLEN;
    const float* dbp = db + ((size_t)bl * T_LR + tbase) * 48;
    if (tid < 240) *(float4*)&dbs[tid * 4] = *(const float4*)(dbp + tid * 4);
    bool fast = (Aflag[0] != 0.f);
    float A0 = -__expf(Alog[d * DS]);
    float Av[DS], h[DS];
    #pragma unroll
    for (int n = 0; n < DS; n++) h[n] = 0.f;
    if (!fast) {
        #pragma unroll
        for (int n = 0; n < DS; n++) Av[n] = -__expf(Alog[d * DS + n]);
    }
    const float4* wp = (const float4*)(dtW + d * 16);
    float4 w0 = wp[0], w1 = wp[1], w2 = wp[2], w3 = wp[3];
    float bias = dtb[d];
    const unsigned short* xp = x + ((size_t)bl * T_LR + tbase) * DI + d;
    float S = 0.f;
    __syncthreads();
    for (int t = 0; t < CLEN; t++) {
        const float* bc = dbs + t * 48;
        float dl = bias
            + bc[0] * w0.x + bc[1] * w0.y + bc[2] * w0.z + bc[3] * w0.w
            + bc[4] * w1.x + bc[5] * w1.y + bc[6] * w1.z + bc[7] * w1.w
            + bc[8] * w2.x + bc[9] * w2.y + bc[10] * w2.z + bc[11] * w2.w
            + bc[12] * w3.x + bc[13] * w3.y + bc[14] * w3.z + bc[15] * w3.w;
        float dtv = softplus_f(dl);
        float xv  = bf2f(xp[(size_t)t * DI]);
        float dtx = dtv * xv;
        S += dtv;
        if (fast) {
            float e1 = __expf(dtv * A0);
            float e = e1;
            #pragma unroll
            for (int n = 0; n < DS; n++) {
                h[n] = e * h[n] + dtx * bc[16 + n];
                e *= e1;
            }
        } else {
            #pragma unroll
            for (int n = 0; n < DS; n++)
                h[n] = __expf(dtv * Av[n]) * h[n] + dtx * bc[16 + n];
        }
    }
    float* hp = hS + (size_t)gid * DS;
    #pragma unroll
    for (int n = 0; n < DS; n++) hp[n] = h[n];
    csum[gid] = S;
}

// ---------------------------------------------------------------------------
// scan phase 2: per (dir*bl, d, n) thread; sequential over CH chunks.
// ---------------------------------------------------------------------------
__global__ __launch_bounds__(256) void k_scan_p2(float* __restrict__ hS,
                                                 const float* __restrict__ csum,
                                                 const float* __restrict__ Alog0,
                                                 const float* __restrict__ Alog1, int Bc) {
    int gid = blockIdx.x * 256 + threadIdx.x;   // ((dir*Bc+bl)*DI + d)*DS + n
    int n = gid & (DS - 1);
    int d = (gid >> 4) & (DI - 1);
    int bl = gid >> 13;                         // [0, 2*Bc)
    const float* Alog = (bl >= Bc) ? Alog1 : Alog0;
    float An = -__expf(Alog[d * DS + n]);
    float hs = 0.f;
    for (int c = 0; c < CH; c++) {
        size_t base = ((size_t)(bl * CH + c) * DI + d);
        float he = hS[base * DS + n];
        float S  = csum[base];
        hS[base * DS + n] = hs;
        hs = __expf(An * S) * hs + he;
    }
}

// ---------------------------------------------------------------------------
// scan phase 3: corrected chunk-start state; y bf16 in place over x.
// ---------------------------------------------------------------------------
__global__ __launch_bounds__(256) void k_scan_p3(unsigned short* __restrict__ x,
                                                 const float* __restrict__ db,
                                                 const float* __restrict__ dtW0, const float* __restrict__ dtW1,
                                                 const float* __restrict__ dtb0, const float* __restrict__ dtb1,
                                                 const float* __restrict__ Alog0, const float* __restrict__ Alog1,
                                                 const float* __restrict__ Aflag,
                                                 const float* __restrict__ Dp0, const float* __restrict__ Dp1,
                                                 const float* __restrict__ hS, int Bc) {
    __shared__ float dbs[CLEN * 48];
    int tid = threadIdx.x;
    int gid = blockIdx.x * 256 + tid;
    int d = gid & (DI - 1);
    int bcix = gid >> 9;
    int c = bcix & (CH - 1);
    int bl = bcix >> CH_LOG2;
    int dir = (bl >= Bc) ? 1 : 0;
    const float* dtW  = dir ? dtW1  : dtW0;
    const float* dtb  = dir ? dtb1  : dtb0;
    const float* Alog = dir ? Alog1 : Alog0;
    const float* Dp   = dir ? Dp1   : Dp0;
    int tbase = c * CLEN;
    const float* dbp = db + ((size_t)bl * T_LR + tbase) * 48;
    if (tid < 240) *(float4*)&dbs[tid * 4] = *(const float4*)(dbp + tid * 4);
    bool fast = (Aflag[0] != 0.f);
    float A0 = -__expf(Alog[d * DS]);
    float Av[DS], h[DS];
    const float* hp = hS + (size_t)gid * DS;
    #pragma unroll
    for (int n = 0; n < DS; n++) h[n] = hp[n];
    if (!fast) {
        #pragma unroll
        for (int n = 0; n < DS; n++) Av[n] = -__expf(Alog[d * DS + n]);
    }
    const float4* wp = (const float4*)(dtW + d * 16);
    float4 w0 = wp[0], w1 = wp[1], w2 = wp[2], w3 = wp[3];
    float bias = dtb[d];
    float Dd = Dp[d];
    unsigned short* xp = x + ((size_t)bl * T_LR + tbase) * DI + d;
    __syncthreads();
    for (int t = 0; t < CLEN; t++) {
        const float* bc = dbs + t * 48;
        float dl = bias
            + bc[0] * w0.x + bc[1] * w0.y + bc[2] * w0.z + bc[3] * w0.w
            + bc[4] * w1.x + bc[5] * w1.y + bc[6] * w1.z + bc[7] * w1.w
            + bc[8] * w2.x + bc[9] * w2.y + bc[10] * w2.z + bc[11] * w2.w
            + bc[12] * w3.x + bc[13] * w3.y + bc[14] * w3.z + bc[15] * w3.w;
        float dtv = softplus_f(dl);
        float xv  = bf2f(xp[(size_t)t * DI]);
        float dtx = dtv * xv;
        float acc = 0.f;
        if (fast) {
            float e1 = __expf(dtv * A0);
            float e = e1;
            #pragma unroll
            for (int n = 0; n < DS; n++) {
                h[n] = e * h[n] + dtx * bc[16 + n];
                acc += h[n] * bc[32 + n];
                e *= e1;
            }
        } else {
            #pragma unroll
            for (int n = 0; n < DS; n++) {
                h[n] = __expf(dtv * Av[n]) * h[n] + dtx * bc[16 + n];
                acc += h[n] * bc[32 + n];
            }
        }
        xp[(size_t)t * DI] = f2bf(acc + xv * Dd);
    }
}

// ---------------------------------------------------------------------------
extern "C" void kernel_launch(void* const* d_in, const int* in_sizes, int n_in,
                              void* d_out, int out_size, void* d_ws, size_t ws_size,
                              hipStream_t stream) {
    const float* x       = (const float*)d_in[0];
    const float* enc_w1  = (const float*)d_in[1];
    const float* enc_b1  = (const float*)d_in[2];
    const float* enc_w2  = (const float*)d_in[3];
    const float* enc_b2  = (const float*)d_in[4];
    const float* norm1_w = (const float*)d_in[5];
    const float* norm2_w = (const float*)d_in[6];
    const float* convd_w = (const float*)d_in[25];
    const float* convd_b = (const float*)d_in[26];
    const float* bn_g    = (const float*)d_in[27];
    const float* bn_b    = (const float*)d_in[28];
    const float* bn_mean = (const float*)d_in[29];
    const float* bn_var  = (const float*)d_in[30];
    const float* sp_w    = (const float*)d_in[31];
    const float* sp_b    = (const float*)d_in[32];
    float* out = (float*)d_out;

    const float* inW0   = (const float*)d_in[7];
    const float* cw0    = (const float*)d_in[8];
    const float* cb0    = (const float*)d_in[9];
    const float* xW0    = (const float*)d_in[10];
    const float* dtW0   = (const float*)d_in[11];
    const float* dtb0   = (const float*)d_in[12];
    const float* Alog0  = (const float*)d_in[13];
    const float* Dp0    = (const float*)d_in[14];
    const float* outW0  = (const float*)d_in[15];
    const float* inW1   = (const float*)d_in[16];
    const float* cw1    = (const float*)d_in[17];
    const float* cb1    = (const float*)d_in[18];
    const float* xW1    = (const float*)d_in[19];
    const float* dtW1   = (const float*)d_in[20];
    const float* dtb1   = (const float*)d_in[21];
    const float* Alog1  = (const float*)d_in[22];
    const float* Dp1    = (const float*)d_in[23];
    const float* outW1  = (const float*)d_in[24];

    // ---- workspace layout (float slots) ----
    float* ws = (float*)d_ws;
    size_t availf = ws_size / sizeof(float);
    size_t o = 0;
    float* t_buf  = ws + o; o += (size_t)BT * DM;       // enc f32; later mo1
    float* xn_buf = ws + o; o += (size_t)BT * DM;       // later: comb_bf overlay
    float* mo     = ws + o; o += (size_t)BT * DM;       // early: xt/e1t; late: d_bf overlay
    unsigned short* xn_bf = (unsigned short*)(ws + o); o += (size_t)BT * DM / 2;
    unsigned short* tb_bf = (unsigned short*)(ws + o); o += (size_t)BT * DM / 2;
    unsigned short* inW_bf2  = (unsigned short*)(ws + o); o += (size_t)1024 * DM;   // 2 dirs
    unsigned short* outW_bf2 = (unsigned short*)(ws + o); o += (size_t)DM * DI;     // 2 dirs
    unsigned short* xW_bc2   = (unsigned short*)(ws + o); o += (size_t)48 * DI;     // 2 dirs x 48x512
    unsigned short* W1r  = (unsigned short*)(ws + o); o += (3 * 128 * 64) / 2;
    unsigned short* W2r  = (unsigned short*)(ws + o); o += (3 * 256 * 128) / 2;
    unsigned short* Wdr  = (unsigned short*)(ws + o); o += (3 * 256 * 512) / 2;
    unsigned short* Wspr = (unsigned short*)(ws + o); o += (3 * 128 * 256) / 2;
    float* alpha_d = ws + o; o += 256;
    float* beta_d  = ws + o; o += 256;
    float* Aflag_d = ws + o; o += 4;
    size_t persist = o;
    float* scratch = ws + persist;
    size_t scratch_avail = (availf > persist) ? (availf - persist) : 0;
    // per-batch scratch for BOTH dirs (float slots)
    size_t per_b2 = 2 * ((size_t)T_LR * DI / 2 * 2 + (size_t)T_LR * 48
                         + (size_t)CH * DI * (DS + 1));
    int Bc = 16;
    while (Bc > 1 && (size_t)Bc * per_b2 > scratch_avail) Bc >>= 1;

    // encoder temporaries overlay mo (dead until out_proj)
    unsigned short* xt  = (unsigned short*)mo;                         // (b,T,64) bf16
    unsigned short* e1t = (unsigned short*)(mo + (size_t)BT * 64 / 2); // (b,T,128) bf16
    unsigned short* comb_bf = (unsigned short*)xn_buf;   // overlay after xn dead
    unsigned short* d_bf = (unsigned short*)mo;          // overlay after mo dead

    // single mega prep dispatch
    k_prep<<<4994, 256, 0, stream>>>(enc_w1, enc_w2, convd_w, sp_w,
                                     convd_b, bn_g, bn_b, bn_mean, bn_var,
                                     inW0, inW1, outW0, outW1, xW0, xW1,
                                     Alog0, Alog1,
                                     x, W1r, W2r, Wdr, Wspr, alpha_d, beta_d,
                                     inW_bf2, outW_bf2, xW_bc2, Aflag_d, xt);

    // encoder (M-tile = 128 rows)
    k_conv3_bf<<<dim3(BT / 128, 1), 256, 0, stream>>>(xt, 64, nullptr, 0, W1r,
                                                      nullptr, enc_b1, nullptr, e1t, 128, 1, 0);
    k_conv3_bf<<<dim3(BT / 128, 2), 256, 0, stream>>>(e1t, 128, nullptr, 0, W2r,
                                                      nullptr, enc_b2, t_buf, tb_bf, 256, 1, 0);
    k_rmsnorm<<<BT / 4, 256, 0, stream>>>(t_buf, nullptr, norm1_w, xn_buf, xn_bf, BT);

    // mamba: both directions per dispatch (dir = blockIdx.z / doubled bl).
    long long dsMo1 = (long long)(t_buf - mo);
    for (int b0 = 0; b0 < B_SZ; b0 += Bc) {
        int Tc = Bc * T_LR;
        long long TcDI = (long long)Tc * DI;
        unsigned short* xcs = (unsigned short*)scratch;              // [2][Tc][DI] bf16
        unsigned short* ygb = xcs + (size_t)2 * Tc * DI;             // [2][Tc][DI] bf16
        float* db   = (float*)(ygb + (size_t)2 * Tc * DI);           // [2][Tc][48]
        float* hS   = db + (size_t)2 * Tc * 48;                      // [2Bc][CH][DI][DS]
        float* csum = hS + (size_t)2 * Bc * CH * DI * DS;            // [2Bc][CH][DI]
        const float*          xnC  = xn_buf + (size_t)b0 * T_LR * DM;
        const unsigned short* xnbC = xn_bf  + (size_t)b0 * T_LR * DM;
        float*                moC  = mo     + (size_t)b0 * T_LR * DM;
        // fused in_proj(xc) + causal dwconv + silu -> xcs bf16 (both dirs)
        k_inproj_conv<<<dim3(Tc / 128, DI / 128, 2), 256, 0, stream>>>(
            xnbC, inW_bf2, cw0, cw1, cb0, cb1, xcs, TcDI);
        // db (dt_low,B,C) = xcs @ xW[0:48]^T -> fp32 (both dirs)
        k_gemm_bf<<<dim3(Tc / 128, 1, 2), 256, 0, stream>>>(
            xcs, DI, TcDI, xW_bc2, (long long)48 * DI,
            db, (long long)Tc * 48, 48, nullptr, DI, 48, 0);
        // chunked scan, both dirs
        k_scan_p1<<<(2 * Bc * CH * DI) / 256, 256, 0, stream>>>(
            xcs, db, dtW0, dtW1, dtb0, dtb1, Alog0, Alog1, Aflag_d, hS, csum, Bc);
        k_scan_p2<<<(2 * Bc * DI * DS) / 256, 256, 0, stream>>>(
            hS, csum, Alog0, Alog1, Bc);
        k_scan_p3<<<(2 * Bc * CH * DI) / 256, 256, 0, stream>>>(
            xcs, db, dtW0, dtW1, dtb0, dtb1, Alog0, Alog1, Aflag_d, Dp0, Dp1, hS, Bc);
        // z GEMM + gate: yg = bf16(silu(z) * y), both dirs
        k_gemm_bf_cb<<<dim3(Tc / 128, DI / 128, 2), 256, 0, stream>>>(
            xnbC, DM, inW_bf2 + (size_t)DI * DM, (long long)1024 * DM,
            ygb, DI, TcDI, xcs, TcDI, DM);
        // out_proj: dir0 -> mo = yg@outW^T + xn; dir1 -> mo1 (crev)
        k_gemm_bf<<<dim3(Tc / 128, DM / 128, 2), 256, 0, stream>>>(
            ygb, DI, TcDI, outW_bf2, (long long)DM * DI,
            moC, dsMo1, DM, xnC, DI, DM, 2);
    }

    // combined = rmsnorm(mo + mo1) -> comb_bf (xn_buf overlay)
    k_rmsnorm<<<BT / 4, 256, 0, stream>>>(mo, t_buf, norm2_w, nullptr, comb_bf, BT);
    // convd + bn + silu -> d_bf (mo overlay)
    k_conv3_bf<<<dim3(BT / 128, 2), 256, 0, stream>>>(comb_bf, 256, tb_bf, 256, Wdr,
                                                      alpha_d, beta_d, nullptr, d_bf, 256, 1, 0);
    // sp conv + pixel shuffle -> out
    k_conv3_bf<<<dim3(BT / 128, 1), 256, 0, stream>>>(d_bf, 256, nullptr, 0, Wspr,
                                                      nullptr, sp_b, out, nullptr, 128, 0, 1);
}

// Round 12
// 1155.911 us; speedup vs baseline: 1.0094x; 1.0026x over previous
//
#include <hip/hip_runtime.h>
#include <hip/hip_bf16.h>
#include <math.h>

#define B_SZ 16
#define T_LR 2560
#define BT (B_SZ * T_LR)     // 40960 tokens
#define DM 256               // d_model
#define DI 512               // d_inner
#define DS 16                // d_state
#define DTR 16               // dt_rank
#define CH 64                // scan chunks per sequence (R12: 128->64, halves hS/csum traffic)
#define CH_LOG2 6
#define CLEN (T_LR / CH)     // 40 steps per chunk

typedef __attribute__((ext_vector_type(8))) short bf16x8;
typedef __attribute__((ext_vector_type(4))) float f32x4;

__device__ __forceinline__ float silu_f(float x) {
    return x / (1.f + __expf(-x));
}
__device__ __forceinline__ unsigned short f2bf(float v) {
    __hip_bfloat16 h = __float2bfloat16(v);
    return *(unsigned short*)&h;
}
__device__ __forceinline__ float bf2f(unsigned short u) {
    union { unsigned int i; float f; } c;
    c.i = (unsigned int)u << 16;
    return c.f;
}
__device__ __forceinline__ int seqrev(int r) {
    int s = r / T_LR, t = r % T_LR;
    return s * T_LR + (T_LR - 1 - t);
}
// softplus: log(1+e). abs err ~1e-7 (vs log1pf) — negligible vs bf16 rounding.
__device__ __forceinline__ float softplus_f(float x) {
    return (x > 20.f) ? x : __logf(1.f + __expf(x));
}
// fragment-major weight swizzle: tile (tap, n/16, c/32) stores 64 lanes x 16B
// contiguously; lane (q=c5>>3, ml=n&15) gets W[n][c...c+7]. One B-fragment
// load becomes a contiguous 1KB burst (16 full lines) instead of 16 scattered
// 1KB-apart probes.
__device__ __forceinline__ size_t wswz_idx(int tap, int n, int c, int N, int Kt) {
    return ((size_t)((tap * (N >> 4) + (n >> 4)) * (Kt >> 5) + (c >> 5)) << 9)
         + (size_t)((((c >> 3) & 3) * 16 + (n & 15)) * 8 + (c & 7));
}

// ---------------------------------------------------------------------------
// mega prep kernel: all weight transforms + input transpose, one dispatch.
// ---------------------------------------------------------------------------
__global__ __launch_bounds__(256) void k_prep(
    const float* __restrict__ enc_w1, const float* __restrict__ enc_w2,
    const float* __restrict__ convd_w, const float* __restrict__ sp_w,
    const float* __restrict__ convd_b, const float* __restrict__ bn_g,
    const float* __restrict__ bn_b, const float* __restrict__ bn_mean,
    const float* __restrict__ bn_var,
    const float* __restrict__ inW0, const float* __restrict__ inW1,
    const float* __restrict__ outW0, const float* __restrict__ outW1,
    const float* __restrict__ xW0, const float* __restrict__ xW1,
    const float* __restrict__ Alog0, const float* __restrict__ Alog1,
    const float* __restrict__ x,
    unsigned short* __restrict__ W1r, unsigned short* __restrict__ W2r,
    unsigned short* __restrict__ Wdr, unsigned short* __restrict__ Wspr,
    float* __restrict__ alpha, float* __restrict__ beta,
    unsigned short* __restrict__ inW_bf2, unsigned short* __restrict__ outW_bf2,
    unsigned short* __restrict__ xW_bc2, float* __restrict__ Aflag,
    unsigned short* __restrict__ xt)
{
    __shared__ float ts[32][33];
    __shared__ int s_ok;
    int blk = blockIdx.x;
    int tid = threadIdx.x;
    if (blk < 32) {                         // W1r: (128,64,3) -> swizzled [N=128,Kt=64]
        int i = blk * 256 + tid;
        int n = i / 64, ci = i % 64;
        #pragma unroll
        for (int k = 0; k < 3; k++)
            W1r[wswz_idx(k, n, ci, 128, 64)] = f2bf(enc_w1[((size_t)n * 64 + ci) * 3 + k]);
    } else if (blk < 160) {                 // W2r: (256,128,3) -> [N=256,Kt=128]
        int i = (blk - 32) * 256 + tid;
        int n = i / 128, ci = i % 128;
        #pragma unroll
        for (int k = 0; k < 3; k++)
            W2r[wswz_idx(k, n, ci, 256, 128)] = f2bf(enc_w2[((size_t)n * 128 + ci) * 3 + k]);
    } else if (blk < 672) {                 // Wdr: (256,512,3) -> [N=256,Kt=512]
        int i = (blk - 160) * 256 + tid;
        int n = i / 512, ci = i % 512;
        #pragma unroll
        for (int k = 0; k < 3; k++)
            Wdr[wswz_idx(k, n, ci, 256, 512)] = f2bf(convd_w[((size_t)n * 512 + ci) * 3 + k]);
    } else if (blk < 800) {                 // Wspr: (128,256,3) -> [N=128,Kt=256]
        int i = (blk - 672) * 256 + tid;
        int n = i / 256, ci = i % 256;
        #pragma unroll
        for (int k = 0; k < 3; k++)
            Wspr[wswz_idx(k, n, ci, 128, 256)] = f2bf(sp_w[((size_t)n * 256 + ci) * 3 + k]);
    } else if (blk < 801) {                 // bnfold
        int c = tid;
        float a = bn_g[c] * rsqrtf(bn_var[c] + 1e-5f);
        alpha[c] = a;
        beta[c] = (convd_b[c] - bn_mean[c]) * a + bn_b[c];
    } else if (blk < 1825) {                // inW cast, both dirs (262144 each)
        int i = (blk - 801) * 256 + tid;
        inW_bf2[i] = f2bf(inW0[i]);
        inW_bf2[262144 + i] = f2bf(inW1[i]);
    } else if (blk < 2337) {                // outW cast (131072 each)
        int i = (blk - 1825) * 256 + tid;
        outW_bf2[i] = f2bf(outW0[i]);
        outW_bf2[131072 + i] = f2bf(outW1[i]);
    } else if (blk < 2433) {                // xW[0:48] cast (24576 each dir)
        int i = (blk - 2337) * 256 + tid;
        xW_bc2[i] = f2bf(xW0[i]);
        xW_bc2[24576 + i] = f2bf(xW1[i]);
    } else if (blk < 2434) {                // Alog structure check: A[d][n] == A[d][0]*(n+1)?
        if (tid == 0) s_ok = 1;
        __syncthreads();
        int ok = 1;
        for (int i = tid; i < DI * DS; i += 256) {
            int d = i >> 4, n = i & 15;
            float a0f = __expf(Alog0[d * DS]);
            float anf = __expf(Alog0[d * DS + n]);
            if (fabsf(anf - (float)(n + 1) * a0f) > 1e-3f * (float)(n + 1)) ok = 0;
            float a0b = __expf(Alog1[d * DS]);
            float anb = __expf(Alog1[d * DS + n]);
            if (fabsf(anb - (float)(n + 1) * a0b) > 1e-3f * (float)(n + 1)) ok = 0;
        }
        if (!ok) atomicAnd(&s_ok, 0);
        __syncthreads();
        if (tid == 0) Aflag[0] = s_ok ? 1.f : 0.f;
    } else {                                // transpose x (b,64,T) f32 -> xt (b,T,64) bf16
        int idx = blk - 2434;               // b(16) x c0(2) x t0(80)
        int t0 = (idx % 80) * 32;
        int c0 = ((idx / 80) & 1) * 32;
        int b = idx / 160;
        int tx = tid & 31, ty = tid >> 5;
        #pragma unroll
        for (int j = 0; j < 4; j++) {
            int c = c0 + ty + j * 8;
            ts[ty + j * 8][tx] = x[((size_t)b * 64 + c) * T_LR + t0 + tx];
        }
        __syncthreads();
        #pragma unroll
        for (int j = 0; j < 4; j++) {
            int t = t0 + ty + j * 8;
            xt[((size_t)b * T_LR + t) * 64 + c0 + tx] = f2bf(ts[tx][ty + j * 8]);
        }
    }
}

// ---------------------------------------------------------------------------
// implicit-GEMM k=3 "same" conv via MFMA (encoder/decoder convs).
// M-tile = 128 rows; As double-buffered, one barrier per k-step.
// R9 (proven best, 76us convd): (1) B loads from fragment-major swizzled
// weights — contiguous 1KB per load instruction, L1-friendly; (2) epilogue
// transposes through LDS for coalesced vectorized stores.
// ---------------------------------------------------------------------------
__global__ __launch_bounds__(256, 3) void k_conv3_bf(const unsigned short* __restrict__ A1, int K1,
                                                  const unsigned short* __restrict__ A2, int K2,
                                                  const unsigned short* __restrict__ Wz,
                                                  const float* __restrict__ alpha,
                                                  const float* __restrict__ beta,
                                                  float* __restrict__ outf,
                                                  unsigned short* __restrict__ outb,
                                                  int N, int dosilu, int pixsh) {
    int Kt = K1 + K2;
    __shared__ __align__(16) unsigned short smem[2 * 130 * 40];   // 20800 B
    unsigned short (*As)[130][40] = (unsigned short (*)[130][40])smem;
    float* sC = (float*)smem;                                     // 32 x 140 f32 (17920 B)
    int tid = threadIdx.x;
    int wave = tid >> 6, lane = tid & 63;
    int wm = (wave >> 1) * 64, wn = (wave & 1) * 64;
    int m0 = blockIdx.x * 128, n0 = blockIdx.y * 128;
    int b = m0 / T_LR, t0 = m0 % T_LR;
    int q = lane >> 4, ml = lane & 15;
    int Nb16 = N >> 4, Kb32 = Kt >> 5;
    int nb0 = (n0 + wn) >> 4;
    const unsigned short* wl = Wz + (size_t)lane * 8;
    f32x4 acc[4][4] = {};
    int cq = tid & 3;
    int r0 = tid >> 2;
    int r1 = r0 + 64;
    int r2 = r0 + 128;
    bool has2 = (tid < 8);
    int ta0 = t0 - 1 + r0, ta1 = t0 - 1 + r1, ta2 = t0 - 1 + r2;
    bool va0 = (ta0 >= 0) && (ta0 < T_LR);
    bool va1 = (ta1 < T_LR);
    bool va2 = has2 && (ta2 < T_LR);
    uint4 v0, v1, v2;
    #define LOADA(vv, valid, t, col) { vv = make_uint4(0u,0u,0u,0u); if (valid) { \
        const unsigned short* src = ((col) < K1) \
            ? A1 + (size_t)(b * T_LR + (t)) * K1 + (col) \
            : A2 + (size_t)(b * T_LR + (t)) * K2 + ((col) - K1); \
        vv = *(const uint4*)src; } }
    LOADA(v0, va0, ta0, cq * 8);
    LOADA(v1, va1, ta1, cq * 8);
    LOADA(v2, va2, ta2, cq * 8);
    *(uint4*)&As[0][r0][cq * 8] = v0;
    *(uint4*)&As[0][r1][cq * 8] = v1;
    if (has2) *(uint4*)&As[0][r2][cq * 8] = v2;
    int nk = Kb32;
    for (int kk = 0; kk < nk; kk++) {
        __syncthreads();
        int cur = kk & 1;
        if (kk + 1 < nk) {
            int col = ((kk + 1) << 5) + cq * 8;
            LOADA(v0, va0, ta0, col);
            LOADA(v1, va1, ta1, col);
            LOADA(v2, va2, ta2, col);
        }
        #pragma unroll
        for (int tap = 0; tap < 3; tap++) {
            int tb = tap * Nb16 + nb0;
            bf16x8 bfr[4];
            #pragma unroll
            for (int ni = 0; ni < 4; ni++)
                bfr[ni] = *(const bf16x8*)(wl + ((size_t)((tb + ni) * Kb32 + kk) << 9));
            #pragma unroll
            for (int mi = 0; mi < 4; mi++) {
                bf16x8 af = *(const bf16x8*)&As[cur][wm + mi * 16 + ml + tap][q * 8];
                #pragma unroll
                for (int ni = 0; ni < 4; ni++)
                    acc[mi][ni] = __builtin_amdgcn_mfma_f32_16x16x32_bf16(af, bfr[ni], acc[mi][ni], 0, 0, 0);
            }
        }
        if (kk + 1 < nk) {
            *(uint4*)&As[cur ^ 1][r0][cq * 8] = v0;
            *(uint4*)&As[cur ^ 1][r1][cq * 8] = v1;
            if (has2) *(uint4*)&As[cur ^ 1][r2][cq * 8] = v2;
        }
    }
    #undef LOADA
    // epilogue: 4 passes of 32 rows through LDS (reuses As space), coalesced
    // vectorized stores.
    int rowoff = m0 - b * T_LR;   // local t of row 0
    #pragma unroll
    for (int p = 0; p < 4; p++) {
        __syncthreads();
        if ((wave >> 1) == (p >> 1)) {
            int mib = (p & 1) * 2;
            #pragma unroll
            for (int m2 = 0; m2 < 2; m2++) {
                int mi = mib + m2;
                int rl = mi * 16 + q * 4 - (p & 1) * 32;
                #pragma unroll
                for (int r = 0; r < 4; r++)
                    #pragma unroll
                    for (int ni = 0; ni < 4; ni++)
                        sC[(rl + r) * 140 + wn + ni * 16 + ml] = acc[mi][ni][r];
            }
        }
        __syncthreads();
        if (pixsh) {
            // N=128, n0=0: col=2*c2+rr -> out[((b*64+c2)*T + t)*2 + rr]
            int row = tid & 31, c2g = tid >> 5;
            int t = rowoff + p * 32 + row;
            float* dst = outf + ((size_t)b * 64 * T_LR + t) * 2;
            #pragma unroll
            for (int j = 0; j < 8; j++) {
                int c2 = c2g + j * 8;
                float va = sC[row * 140 + 2 * c2]     + beta[2 * c2];
                float vb = sC[row * 140 + 2 * c2 + 1] + beta[2 * c2 + 1];
                *(float2*)&dst[(size_t)c2 * T_LR * 2] = make_float2(va, vb);
            }
        } else {
            #pragma unroll
            for (int gi = 0; gi < 2; gi++) {
                int g = tid + gi * 256;
                int row = g >> 4;
                int colg = (g & 15) * 8;
                int mr = m0 + p * 32 + row;
                const float* src = sC + row * 140 + colg;
                float vv[8];
                *(float4*)&vv[0] = *(const float4*)src;
                *(float4*)&vv[4] = *(const float4*)(src + 4);
                unsigned short ob[8];
                #pragma unroll
                for (int jj = 0; jj < 8; jj++) {
                    int col = n0 + colg + jj;
                    float a = alpha ? alpha[col] : 1.f;
                    float v = vv[jj] * a + beta[col];
                    if (dosilu) v = silu_f(v);
                    vv[jj] = v;
                    ob[jj] = f2bf(v);
                }
                if (outf) {
                    *(float4*)(outf + (size_t)mr * N + n0 + colg) = *(float4*)&vv[0];
                    *(float4*)(outf + (size_t)mr * N + n0 + colg + 4) = *(float4*)&vv[4];
                }
                if (outb)
                    *(uint4*)(outb + (size_t)mr * N + n0 + colg) = *(uint4*)ob;
            }
        }
    }
}

// ---------------------------------------------------------------------------
// fused in_proj (xc half) + causal depthwise conv k=4 + silu -> xcs bf16.
// BOTH directions in one dispatch: dir = blockIdx.z selects weights/output.
// ---------------------------------------------------------------------------
__global__ __launch_bounds__(256) void k_inproj_conv(const unsigned short* __restrict__ xn,
                                                     const unsigned short* __restrict__ inW2,
                                                     const float* __restrict__ cw0,
                                                     const float* __restrict__ cw1,
                                                     const float* __restrict__ cb0,
                                                     const float* __restrict__ cb1,
                                                     unsigned short* __restrict__ xcs,
                                                     long long dsXcs) {
    __shared__ unsigned short As[128][40];
    __shared__ unsigned short Bs[128][40];
    __shared__ unsigned short Ct[131][136];   // rows: internal t0-3 .. t0+127
    int dir = blockIdx.z;
    int arev = dir;
    const unsigned short* inW = inW2 + (size_t)dir * 1024 * DM;
    const float* cw = dir ? cw1 : cw0;
    const float* cb = dir ? cb1 : cb0;
    xcs += (size_t)dir * dsXcs;
    int tid = threadIdx.x;
    int wave = tid >> 6, lane = tid & 63;
    int wm = (wave >> 1) * 64, wn = (wave & 1) * 64;
    int m0 = blockIdx.x * 128, n0 = blockIdx.y * 128;
    int b = m0 / T_LR, t0 = m0 % T_LR;
    int sc = tid & 3, sr = tid >> 2;
    int ar0 = m0 + sr, ar1 = m0 + sr + 64;
    if (arev) { ar0 = seqrev(ar0); ar1 = seqrev(ar1); }
    const unsigned short* ap0 = xn + (size_t)ar0 * DM + sc * 8;
    const unsigned short* ap1 = xn + (size_t)ar1 * DM + sc * 8;
    const unsigned short* bp0 = inW + (size_t)(n0 + sr) * DM + sc * 8;
    const unsigned short* bp1 = inW + (size_t)(n0 + sr + 64) * DM + sc * 8;
    f32x4 acc[4][4] = {};
    int q = lane >> 4, ml = lane & 15;
    for (int k0 = 0; k0 < DM; k0 += 32) {
        uint4 a0 = *(const uint4*)(ap0 + k0);
        uint4 a1 = *(const uint4*)(ap1 + k0);
        uint4 b0 = *(const uint4*)(bp0 + k0);
        uint4 b1 = *(const uint4*)(bp1 + k0);
        __syncthreads();
        *(uint4*)&As[sr][sc * 8]      = a0;
        *(uint4*)&As[sr + 64][sc * 8] = a1;
        *(uint4*)&Bs[sr][sc * 8]      = b0;
        *(uint4*)&Bs[sr + 64][sc * 8] = b1;
        __syncthreads();
        bf16x8 af[4], bfr[4];
        #pragma unroll
        for (int mi = 0; mi < 4; mi++)
            af[mi] = *(const bf16x8*)&As[wm + mi * 16 + ml][q * 8];
        #pragma unroll
        for (int ni = 0; ni < 4; ni++)
            bfr[ni] = *(const bf16x8*)&Bs[wn + ni * 16 + ml][q * 8];
        #pragma unroll
        for (int mi = 0; mi < 4; mi++)
            #pragma unroll
            for (int ni = 0; ni < 4; ni++)
                acc[mi][ni] = __builtin_amdgcn_mfma_f32_16x16x32_bf16(af[mi], bfr[ni], acc[mi][ni], 0, 0, 0);
    }
    // main tile -> Ct rows 3..130
    #pragma unroll
    for (int mi = 0; mi < 4; mi++)
        #pragma unroll
        for (int r = 0; r < 4; r++)
            #pragma unroll
            for (int ni = 0; ni < 4; ni++)
                Ct[3 + wm + mi * 16 + q * 4 + r][wn + ni * 16 + ml] = f2bf(acc[mi][ni][r]);
    // halo rows 0..2 via direct dot — 384 items on 256 threads
    for (int i = tid; i < 384; i += 256) {
        int hr = i >> 7, c = i & 127;
        int tr = t0 - 3 + hr;
        float v = 0.f;
        if (tr >= 0) {
            int src = b * T_LR + (arev ? (T_LR - 1 - tr) : tr);
            const unsigned short* xr = xn + (size_t)src * DM;
            const unsigned short* wr = inW + (size_t)(n0 + c) * DM;
            for (int k = 0; k < DM; k += 8) {
                uint4 xa = *(const uint4*)(xr + k);
                uint4 wa = *(const uint4*)(wr + k);
                const unsigned short* xs = (const unsigned short*)&xa;
                const unsigned short* wsp = (const unsigned short*)&wa;
                #pragma unroll
                for (int j = 0; j < 8; j++) v += bf2f(xs[j]) * bf2f(wsp[j]);
            }
        }
        Ct[hr][c] = f2bf(v);
    }
    __syncthreads();
    // causal conv k=4 + silu, write xcs bf16
    int col = tid & 127;
    int d = n0 + col;
    float w0 = cw[d * 4 + 0], w1 = cw[d * 4 + 1], w2 = cw[d * 4 + 2], w3 = cw[d * 4 + 3];
    float bi = cb[d];
    int rbase = tid >> 7;
    for (int j = 0; j < 64; j++) {
        int row = rbase + 2 * j;
        float v = bi + bf2f(Ct[row][col]) * w0 + bf2f(Ct[row + 1][col]) * w1
                     + bf2f(Ct[row + 2][col]) * w2 + bf2f(Ct[row + 3][col]) * w3;
        xcs[(size_t)(m0 + row) * DI + d] = f2bf(silu_f(v));
    }
}

// ---------------------------------------------------------------------------
// rmsnorm over last dim (256). One wave per token. Optional second input
// summed in (mo + mo1). fp32 and/or bf16 out.
// ---------------------------------------------------------------------------
__global__ __launch_bounds__(256) void k_rmsnorm(const float* __restrict__ in1,
                                                 const float* __restrict__ in2,
                                                 const float* __restrict__ w,
                                                 float* __restrict__ out,
                                                 unsigned short* __restrict__ out_bf,
                                                 int ntok) {
    int tok = (blockIdx.x * 256 + threadIdx.x) >> 6;
    int lane = threadIdx.x & 63;
    if (tok >= ntok) return;
    float4 v = ((const float4*)(in1 + (size_t)tok * DM))[lane];
    if (in2) {
        float4 u = ((const float4*)(in2 + (size_t)tok * DM))[lane];
        v.x += u.x; v.y += u.y; v.z += u.z; v.w += u.w;
    }
    float ss = v.x * v.x + v.y * v.y + v.z * v.z + v.w * v.w;
    #pragma unroll
    for (int off = 32; off > 0; off >>= 1) ss += __shfl_xor(ss, off);
    float sc = rsqrtf(ss * (1.f / 256.f) + 1e-6f);
    float4 wv = ((const float4*)w)[lane];
    float4 o;
    o.x = v.x * sc * wv.x; o.y = v.y * sc * wv.y;
    o.z = v.z * sc * wv.z; o.w = v.w * sc * wv.w;
    if (out) ((float4*)(out + (size_t)tok * DM))[lane] = o;
    if (out_bf) {
        ushort4 ob;
        ob.x = f2bf(o.x); ob.y = f2bf(o.y); ob.z = f2bf(o.z); ob.w = f2bf(o.w);
        ((ushort4*)(out_bf + (size_t)tok * DM))[lane] = ob;
    }
}

// ---------------------------------------------------------------------------
// bf16 MFMA GEMM, fp32 out + optional residual (db and out_proj).
// BOTH directions per dispatch: dir = blockIdx.z applies element strides.
// crevmode: 0 = never reverse output rows, 2 = reverse iff dir==1.
// ---------------------------------------------------------------------------
__global__ __launch_bounds__(256) void k_gemm_bf(const unsigned short* __restrict__ A, int lda, long long dsA,
                                                 const unsigned short* __restrict__ Bw, long long dsB,
                                                 float* Cf, long long dsCf, int ldc,
                                                 const float* __restrict__ res,
                                                 int K, int Nout, int crevmode) {
    __shared__ unsigned short As[128][40];
    __shared__ unsigned short Bs[128][40];
    int dir = blockIdx.z;
    A += (long long)dir * dsA;
    Bw += (long long)dir * dsB;
    Cf += (long long)dir * dsCf;
    int crev = (crevmode == 2) ? dir : crevmode;
    int tid = threadIdx.x;
    int wave = tid >> 6, lane = tid & 63;
    int wm = (wave >> 1) * 64, wn = (wave & 1) * 64;
    int m0 = blockIdx.x * 128, n0 = blockIdx.y * 128;
    int sc = tid & 3, sr = tid >> 2;
    const unsigned short* ap0 = A + (size_t)(m0 + sr) * lda + sc * 8;
    const unsigned short* ap1 = A + (size_t)(m0 + sr + 64) * lda + sc * 8;
    bool bv0 = (n0 + sr) < Nout;
    bool bv1 = (n0 + sr + 64) < Nout;
    const unsigned short* bp0 = Bw + (size_t)(n0 + sr) * K + sc * 8;
    const unsigned short* bp1 = Bw + (size_t)(n0 + sr + 64) * K + sc * 8;
    f32x4 acc[4][4] = {};
    int q = lane >> 4, ml = lane & 15;
    for (int k0 = 0; k0 < K; k0 += 32) {
        uint4 a0 = *(const uint4*)(ap0 + k0);
        uint4 a1 = *(const uint4*)(ap1 + k0);
        uint4 b0 = make_uint4(0u, 0u, 0u, 0u), b1 = make_uint4(0u, 0u, 0u, 0u);
        if (bv0) b0 = *(const uint4*)(bp0 + k0);
        if (bv1) b1 = *(const uint4*)(bp1 + k0);
        __syncthreads();
        *(uint4*)&As[sr][sc * 8]      = a0;
        *(uint4*)&As[sr + 64][sc * 8] = a1;
        *(uint4*)&Bs[sr][sc * 8]      = b0;
        *(uint4*)&Bs[sr + 64][sc * 8] = b1;
        __syncthreads();
        bf16x8 af[4], bfr[4];
        #pragma unroll
        for (int mi = 0; mi < 4; mi++)
            af[mi] = *(const bf16x8*)&As[wm + mi * 16 + ml][q * 8];
        #pragma unroll
        for (int ni = 0; ni < 4; ni++)
            bfr[ni] = *(const bf16x8*)&Bs[wn + ni * 16 + ml][q * 8];
        #pragma unroll
        for (int mi = 0; mi < 4; mi++)
            #pragma unroll
            for (int ni = 0; ni < 4; ni++)
                acc[mi][ni] = __builtin_amdgcn_mfma_f32_16x16x32_bf16(af[mi], bfr[ni], acc[mi][ni], 0, 0, 0);
    }
    #pragma unroll
    for (int mi = 0; mi < 4; mi++) {
        #pragma unroll
        for (int r = 0; r < 4; r++) {
            int mr = m0 + wm + mi * 16 + q * 4 + r;
            int orow = crev ? seqrev(mr) : mr;
            #pragma unroll
            for (int ni = 0; ni < 4; ni++) {
                int col = n0 + wn + ni * 16 + ml;
                if (col < Nout) {
                    float v = acc[mi][ni][r];
                    if (res) v += res[(size_t)orow * ldc + col];
                    Cf[(size_t)orow * ldc + col] = v;
                }
            }
        }
    }
}

// ---------------------------------------------------------------------------
// bf16-out MFMA GEMM with LDS-transposed vectorized epilogue (z-gate).
// BOTH directions per dispatch: dir = blockIdx.z; A (xn) shared; arev = dir.
// ---------------------------------------------------------------------------
__global__ __launch_bounds__(256) void k_gemm_bf_cb(const unsigned short* __restrict__ A, int lda,
                                                    const unsigned short* __restrict__ Bw, long long dsB,
                                                    unsigned short* __restrict__ Cb, int ldc, long long dsCb,
                                                    const unsigned short* __restrict__ gate, long long dsGate,
                                                    int K) {
    __shared__ __align__(16) unsigned short smem[2 * 128 * 40];   // 20480 B
    unsigned short (*As)[40] = (unsigned short(*)[40])smem;
    unsigned short (*Bs)[40] = (unsigned short(*)[40])(smem + 128 * 40);
    float* sC = (float*)smem;                                     // 32 x 140 f32
    int dir = blockIdx.z;
    int arev = dir;
    Bw += (long long)dir * dsB;
    Cb += (long long)dir * dsCb;
    gate += (long long)dir * dsGate;
    int tid = threadIdx.x;
    int wave = tid >> 6, lane = tid & 63;
    int wm = (wave >> 1) * 64, wn = (wave & 1) * 64;
    int m0 = blockIdx.x * 128, n0 = blockIdx.y * 128;
    int sc = tid & 3, sr = tid >> 2;
    int ar0 = m0 + sr, ar1 = m0 + sr + 64;
    if (arev) { ar0 = seqrev(ar0); ar1 = seqrev(ar1); }
    const unsigned short* ap0 = A + (size_t)ar0 * lda + sc * 8;
    const unsigned short* ap1 = A + (size_t)ar1 * lda + sc * 8;
    const unsigned short* bp0 = Bw + (size_t)(n0 + sr) * K + sc * 8;
    const unsigned short* bp1 = Bw + (size_t)(n0 + sr + 64) * K + sc * 8;
    f32x4 acc[4][4] = {};
    int q = lane >> 4, ml = lane & 15;
    for (int k0 = 0; k0 < K; k0 += 32) {
        uint4 a0 = *(const uint4*)(ap0 + k0);
        uint4 a1 = *(const uint4*)(ap1 + k0);
        uint4 b0 = *(const uint4*)(bp0 + k0);
        uint4 b1 = *(const uint4*)(bp1 + k0);
        __syncthreads();
        *(uint4*)&As[sr][sc * 8]      = a0;
        *(uint4*)&As[sr + 64][sc * 8] = a1;
        *(uint4*)&Bs[sr][sc * 8]      = b0;
        *(uint4*)&Bs[sr + 64][sc * 8] = b1;
        __syncthreads();
        bf16x8 af[4], bfr[4];
        #pragma unroll
        for (int mi = 0; mi < 4; mi++)
            af[mi] = *(const bf16x8*)&As[wm + mi * 16 + ml][q * 8];
        #pragma unroll
        for (int ni = 0; ni < 4; ni++)
            bfr[ni] = *(const bf16x8*)&Bs[wn + ni * 16 + ml][q * 8];
        #pragma unroll
        for (int mi = 0; mi < 4; mi++)
            #pragma unroll
            for (int ni = 0; ni < 4; ni++)
                acc[mi][ni] = __builtin_amdgcn_mfma_f32_16x16x32_bf16(af[mi], bfr[ni], acc[mi][ni], 0, 0, 0);
    }
    // epilogue: 4 passes of 32 rows through LDS (stride 140 f32)
    #pragma unroll
    for (int p = 0; p < 4; p++) {
        __syncthreads();
        if ((wave >> 1) == (p >> 1)) {
            int mib = (p & 1) * 2;
            #pragma unroll
            for (int m2 = 0; m2 < 2; m2++) {
                int mi = mib + m2;
                int rl = mi * 16 + q * 4 - (p & 1) * 32;
                #pragma unroll
                for (int r = 0; r < 4; r++)
                    #pragma unroll
                    for (int ni = 0; ni < 4; ni++)
                        sC[(rl + r) * 140 + wn + ni * 16 + ml] = acc[mi][ni][r];
            }
        }
        __syncthreads();
        #pragma unroll
        for (int gi = 0; gi < 2; gi++) {
            int g = tid + gi * 256;
            int row = g >> 4;
            int colg = (g & 15) * 8;
            int grow = m0 + p * 32 + row;
            const float* src = sC + row * 140 + colg;
            float4 v0 = *(const float4*)src;
            float4 v1 = *(const float4*)(src + 4);
            float vv[8] = {v0.x, v0.y, v0.z, v0.w, v1.x, v1.y, v1.z, v1.w};
            unsigned short gu[8];
            *(uint4*)gu = *(const uint4*)(gate + (size_t)grow * ldc + n0 + colg);
            unsigned short o[8];
            #pragma unroll
            for (int jj = 0; jj < 8; jj++) {
                float v = vv[jj];
                v = silu_f(v) * bf2f(gu[jj]);
                o[jj] = f2bf(v);
            }
            *(uint4*)(Cb + (size_t)grow * ldc + n0 + colg) = *(uint4*)o;
        }
    }
}

// ---------------------------------------------------------------------------
// scan phase 1: per (dir*bl, chunk, d) thread. Both dirs in one dispatch:
// buffers laid [2*Bc][...]; dir = (bl >= Bc) selects the weight set.
// dt computed in-line (low-rank); fast path when Aflag set.
// ---------------------------------------------------------------------------
__global__ __launch_bounds__(256) void k_scan_p1(const unsigned short* __restrict__ x,
                                                 const float* __restrict__ db,
                                                 const float* __restrict__ dtW0, const float* __restrict__ dtW1,
                                                 const float* __restrict__ dtb0, const float* __restrict__ dtb1,
                                                 const float* __restrict__ Alog0, const float* __restrict__ Alog1,
                                                 const float* __restrict__ Aflag,
                                                 float* __restrict__ hS,
                                                 float* __restrict__ csum, int Bc) {
    __shared__ float dbs[CLEN * 48];
    int tid = threadIdx.x;
    int gid = blockIdx.x * 256 + tid;   // ((dir*Bc+bl)*CH + c)*DI + d
    int d = gid & (DI - 1);
    int bcix = gid >> 9;
    int c = bcix & (CH - 1);
    int bl = bcix >> CH_LOG2;           // [0, 2*Bc)
    int dir = (bl >= Bc) ? 1 : 0;
    const float* dtW  = dir ? dtW1  : dtW0;
    const float* dtb  = dir ? dtb1  : dtb0;
    const float* Alog = dir ? Alog1 : Alog0;
    int tbase = c * CLEN;
    const float* dbp = db + ((size_t)bl * T_LR + tbase) * 48;
    for (int i = tid; i < (CLEN * 48) / 4; i += 256)
        *(float4*)&dbs[i * 4] = *(const float4*)(dbp + i * 4);
    bool fast = (Aflag[0] != 0.f);
    float A0 = -__expf(Alog[d * DS]);
    float Av[DS], h[DS];
    #pragma unroll
    for (int n = 0; n < DS; n++) h[n] = 0.f;
    if (!fast) {
        #pragma unroll
        for (int n = 0; n < DS; n++) Av[n] = -__expf(Alog[d * DS + n]);
    }
    const float4* wp = (const float4*)(dtW + d * 16);
    float4 w0 = wp[0], w1 = wp[1], w2 = wp[2], w3 = wp[3];
    float bias = dtb[d];
    const unsigned short* xp = x + ((size_t)bl * T_LR + tbase) * DI + d;
    float S = 0.f;
    __syncthreads();
    for (int t = 0; t < CLEN; t++) {
        const float* bc = dbs + t * 48;
        float dl = bias
            + bc[0] * w0.x + bc[1] * w0.y + bc[2] * w0.z + bc[3] * w0.w
            + bc[4] * w1.x + bc[5] * w1.y + bc[6] * w1.z + bc[7] * w1.w
            + bc[8] * w2.x + bc[9] * w2.y + bc[10] * w2.z + bc[11] * w2.w
            + bc[12] * w3.x + bc[13] * w3.y + bc[14] * w3.z + bc[15] * w3.w;
        float dtv = softplus_f(dl);
        float xv  = bf2f(xp[(size_t)t * DI]);
        float dtx = dtv * xv;
        S += dtv;
        if (fast) {
            float e1 = __expf(dtv * A0);
            float e = e1;
            #pragma unroll
            for (int n = 0; n < DS; n++) {
                h[n] = e * h[n] + dtx * bc[16 + n];
                e *= e1;
            }
        } else {
            #pragma unroll
            for (int n = 0; n < DS; n++)
                h[n] = __expf(dtv * Av[n]) * h[n] + dtx * bc[16 + n];
        }
    }
    float* hp = hS + (size_t)gid * DS;
    #pragma unroll
    for (int n = 0; n < DS; n++) hp[n] = h[n];
    csum[gid] = S;
}

// ---------------------------------------------------------------------------
// scan phase 2: per (dir*bl, d, n) thread; sequential over CH chunks.
// ---------------------------------------------------------------------------
__global__ __launch_bounds__(256) void k_scan_p2(float* __restrict__ hS,
                                                 const float* __restrict__ csum,
                                                 const float* __restrict__ Alog0,
                                                 const float* __restrict__ Alog1, int Bc) {
    int gid = blockIdx.x * 256 + threadIdx.x;   // ((dir*Bc+bl)*DI + d)*DS + n
    int n = gid & (DS - 1);
    int d = (gid >> 4) & (DI - 1);
    int bl = gid >> 13;                         // [0, 2*Bc)
    const float* Alog = (bl >= Bc) ? Alog1 : Alog0;
    float An = -__expf(Alog[d * DS + n]);
    float hs = 0.f;
    for (int c = 0; c < CH; c++) {
        size_t base = ((size_t)(bl * CH + c) * DI + d);
        float he = hS[base * DS + n];
        float S  = csum[base];
        hS[base * DS + n] = hs;
        hs = __expf(An * S) * hs + he;
    }
}

// ---------------------------------------------------------------------------
// scan phase 3: corrected chunk-start state; y bf16 in place over x.
// ---------------------------------------------------------------------------
__global__ __launch_bounds__(256) void k_scan_p3(unsigned short* __restrict__ x,
                                                 const float* __restrict__ db,
                                                 const float* __restrict__ dtW0, const float* __restrict__ dtW1,
                                                 const float* __restrict__ dtb0, const float* __restrict__ dtb1,
                                                 const float* __restrict__ Alog0, const float* __restrict__ Alog1,
                                                 const float* __restrict__ Aflag,
                                                 const float* __restrict__ Dp0, const float* __restrict__ Dp1,
                                                 const float* __restrict__ hS, int Bc) {
    __shared__ float dbs[CLEN * 48];
    int tid = threadIdx.x;
    int gid = blockIdx.x * 256 + tid;
    int d = gid & (DI - 1);
    int bcix = gid >> 9;
    int c = bcix & (CH - 1);
    int bl = bcix >> CH_LOG2;
    int dir = (bl >= Bc) ? 1 : 0;
    const float* dtW  = dir ? dtW1  : dtW0;
    const float* dtb  = dir ? dtb1  : dtb0;
    const float* Alog = dir ? Alog1 : Alog0;
    const float* Dp   = dir ? Dp1   : Dp0;
    int tbase = c * CLEN;
    const float* dbp = db + ((size_t)bl * T_LR + tbase) * 48;
    for (int i = tid; i < (CLEN * 48) / 4; i += 256)
        *(float4*)&dbs[i * 4] = *(const float4*)(dbp + i * 4);
    bool fast = (Aflag[0] != 0.f);
    float A0 = -__expf(Alog[d * DS]);
    float Av[DS], h[DS];
    const float* hp = hS + (size_t)gid * DS;
    #pragma unroll
    for (int n = 0; n < DS; n++) h[n] = hp[n];
    if (!fast) {
        #pragma unroll
        for (int n = 0; n < DS; n++) Av[n] = -__expf(Alog[d * DS + n]);
    }
    const float4* wp = (const float4*)(dtW + d * 16);
    float4 w0 = wp[0], w1 = wp[1], w2 = wp[2], w3 = wp[3];
    float bias = dtb[d];
    float Dd = Dp[d];
    unsigned short* xp = x + ((size_t)bl * T_LR + tbase) * DI + d;
    __syncthreads();
    for (int t = 0; t < CLEN; t++) {
        const float* bc = dbs + t * 48;
        float dl = bias
            + bc[0] * w0.x + bc[1] * w0.y + bc[2] * w0.z + bc[3] * w0.w
            + bc[4] * w1.x + bc[5] * w1.y + bc[6] * w1.z + bc[7] * w1.w
            + bc[8] * w2.x + bc[9] * w2.y + bc[10] * w2.z + bc[11] * w2.w
            + bc[12] * w3.x + bc[13] * w3.y + bc[14] * w3.z + bc[15] * w3.w;
        float dtv = softplus_f(dl);
        float xv  = bf2f(xp[(size_t)t * DI]);
        float dtx = dtv * xv;
        float acc = 0.f;
        if (fast) {
            float e1 = __expf(dtv * A0);
            float e = e1;
            #pragma unroll
            for (int n = 0; n < DS; n++) {
                h[n] = e * h[n] + dtx * bc[16 + n];
                acc += h[n] * bc[32 + n];
                e *= e1;
            }
        } else {
            #pragma unroll
            for (int n = 0; n < DS; n++) {
                h[n] = __expf(dtv * Av[n]) * h[n] + dtx * bc[16 + n];
                acc += h[n] * bc[32 + n];
            }
        }
        xp[(size_t)t * DI] = f2bf(acc + xv * Dd);
    }
}

// ---------------------------------------------------------------------------
extern "C" void kernel_launch(void* const* d_in, const int* in_sizes, int n_in,
                              void* d_out, int out_size, void* d_ws, size_t ws_size,
                              hipStream_t stream) {
    const float* x       = (const float*)d_in[0];
    const float* enc_w1  = (const float*)d_in[1];
    const float* enc_b1  = (const float*)d_in[2];
    const float* enc_w2  = (const float*)d_in[3];
    const float* enc_b2  = (const float*)d_in[4];
    const float* norm1_w = (const float*)d_in[5];
    const float* norm2_w = (const float*)d_in[6];
    const float* convd_w = (const float*)d_in[25];
    const float* convd_b = (const float*)d_in[26];
    const float* bn_g    = (const float*)d_in[27];
    const float* bn_b    = (const float*)d_in[28];
    const float* bn_mean = (const float*)d_in[29];
    const float* bn_var  = (const float*)d_in[30];
    const float* sp_w    = (const float*)d_in[31];
    const float* sp_b    = (const float*)d_in[32];
    float* out = (float*)d_out;

    const float* inW0   = (const float*)d_in[7];
    const float* cw0    = (const float*)d_in[8];
    const float* cb0    = (const float*)d_in[9];
    const float* xW0    = (const float*)d_in[10];
    const float* dtW0   = (const float*)d_in[11];
    const float* dtb0   = (const float*)d_in[12];
    const float* Alog0  = (const float*)d_in[13];
    const float* Dp0    = (const float*)d_in[14];
    const float* outW0  = (const float*)d_in[15];
    const float* inW1   = (const float*)d_in[16];
    const float* cw1    = (const float*)d_in[17];
    const float* cb1    = (const float*)d_in[18];
    const float* xW1    = (const float*)d_in[19];
    const float* dtW1   = (const float*)d_in[20];
    const float* dtb1   = (const float*)d_in[21];
    const float* Alog1  = (const float*)d_in[22];
    const float* Dp1    = (const float*)d_in[23];
    const float* outW1  = (const float*)d_in[24];

    // ---- workspace layout (float slots) ----
    float* ws = (float*)d_ws;
    size_t availf = ws_size / sizeof(float);
    size_t o = 0;
    float* t_buf  = ws + o; o += (size_t)BT * DM;       // enc f32; later mo1
    float* xn_buf = ws + o; o += (size_t)BT * DM;       // later: comb_bf overlay
    float* mo     = ws + o; o += (size_t)BT * DM;       // early: xt/e1t; late: d_bf overlay
    unsigned short* xn_bf = (unsigned short*)(ws + o); o += (size_t)BT * DM / 2;
    unsigned short* tb_bf = (unsigned short*)(ws + o); o += (size_t)BT * DM / 2;
    unsigned short* inW_bf2  = (unsigned short*)(ws + o); o += (size_t)1024 * DM;   // 2 dirs
    unsigned short* outW_bf2 = (unsigned short*)(ws + o); o += (size_t)DM * DI;     // 2 dirs
    unsigned short* xW_bc2   = (unsigned short*)(ws + o); o += (size_t)48 * DI;     // 2 dirs x 48x512
    unsigned short* W1r  = (unsigned short*)(ws + o); o += (3 * 128 * 64) / 2;
    unsigned short* W2r  = (unsigned short*)(ws + o); o += (3 * 256 * 128) / 2;
    unsigned short* Wdr  = (unsigned short*)(ws + o); o += (3 * 256 * 512) / 2;
    unsigned short* Wspr = (unsigned short*)(ws + o); o += (3 * 128 * 256) / 2;
    float* alpha_d = ws + o; o += 256;
    float* beta_d  = ws + o; o += 256;
    float* Aflag_d = ws + o; o += 4;
    size_t persist = o;
    float* scratch = ws + persist;
    size_t scratch_avail = (availf > persist) ? (availf - persist) : 0;
    // per-batch scratch for BOTH dirs (float slots)
    size_t per_b2 = 2 * ((size_t)T_LR * DI / 2 * 2 + (size_t)T_LR * 48
                         + (size_t)CH * DI * (DS + 1));
    int Bc = 16;
    while (Bc > 1 && (size_t)Bc * per_b2 > scratch_avail) Bc >>= 1;

    // encoder temporaries overlay mo (dead until out_proj)
    unsigned short* xt  = (unsigned short*)mo;                         // (b,T,64) bf16
    unsigned short* e1t = (unsigned short*)(mo + (size_t)BT * 64 / 2); // (b,T,128) bf16
    unsigned short* comb_bf = (unsigned short*)xn_buf;   // overlay after xn dead
    unsigned short* d_bf = (unsigned short*)mo;          // overlay after mo dead

    // single mega prep dispatch
    k_prep<<<4994, 256, 0, stream>>>(enc_w1, enc_w2, convd_w, sp_w,
                                     convd_b, bn_g, bn_b, bn_mean, bn_var,
                                     inW0, inW1, outW0, outW1, xW0, xW1,
                                     Alog0, Alog1,
                                     x, W1r, W2r, Wdr, Wspr, alpha_d, beta_d,
                                     inW_bf2, outW_bf2, xW_bc2, Aflag_d, xt);

    // encoder (M-tile = 128 rows)
    k_conv3_bf<<<dim3(BT / 128, 1), 256, 0, stream>>>(xt, 64, nullptr, 0, W1r,
                                                      nullptr, enc_b1, nullptr, e1t, 128, 1, 0);
    k_conv3_bf<<<dim3(BT / 128, 2), 256, 0, stream>>>(e1t, 128, nullptr, 0, W2r,
                                                      nullptr, enc_b2, t_buf, tb_bf, 256, 1, 0);
    k_rmsnorm<<<BT / 4, 256, 0, stream>>>(t_buf, nullptr, norm1_w, xn_buf, xn_bf, BT);

    // mamba: both directions per dispatch (dir = blockIdx.z / doubled bl).
    long long dsMo1 = (long long)(t_buf - mo);
    for (int b0 = 0; b0 < B_SZ; b0 += Bc) {
        int Tc = Bc * T_LR;
        long long TcDI = (long long)Tc * DI;
        unsigned short* xcs = (unsigned short*)scratch;              // [2][Tc][DI] bf16
        unsigned short* ygb = xcs + (size_t)2 * Tc * DI;             // [2][Tc][DI] bf16
        float* db   = (float*)(ygb + (size_t)2 * Tc * DI);           // [2][Tc][48]
        float* hS   = db + (size_t)2 * Tc * 48;                      // [2Bc][CH][DI][DS]
        float* csum = hS + (size_t)2 * Bc * CH * DI * DS;            // [2Bc][CH][DI]
        const float*          xnC  = xn_buf + (size_t)b0 * T_LR * DM;
        const unsigned short* xnbC = xn_bf  + (size_t)b0 * T_LR * DM;
        float*                moC  = mo     + (size_t)b0 * T_LR * DM;
        // fused in_proj(xc) + causal dwconv + silu -> xcs bf16 (both dirs)
        k_inproj_conv<<<dim3(Tc / 128, DI / 128, 2), 256, 0, stream>>>(
            xnbC, inW_bf2, cw0, cw1, cb0, cb1, xcs, TcDI);
        // db (dt_low,B,C) = xcs @ xW[0:48]^T -> fp32 (both dirs)
        k_gemm_bf<<<dim3(Tc / 128, 1, 2), 256, 0, stream>>>(
            xcs, DI, TcDI, xW_bc2, (long long)48 * DI,
            db, (long long)Tc * 48, 48, nullptr, DI, 48, 0);
        // chunked scan (CH=64, CLEN=40), both dirs
        k_scan_p1<<<(2 * Bc * CH * DI) / 256, 256, 0, stream>>>(
            xcs, db, dtW0, dtW1, dtb0, dtb1, Alog0, Alog1, Aflag_d, hS, csum, Bc);
        k_scan_p2<<<(2 * Bc * DI * DS) / 256, 256, 0, stream>>>(
            hS, csum, Alog0, Alog1, Bc);
        k_scan_p3<<<(2 * Bc * CH * DI) / 256, 256, 0, stream>>>(
            xcs, db, dtW0, dtW1, dtb0, dtb1, Alog0, Alog1, Aflag_d, Dp0, Dp1, hS, Bc);
        // z GEMM + gate: yg = bf16(silu(z) * y), both dirs
        k_gemm_bf_cb<<<dim3(Tc / 128, DI / 128, 2), 256, 0, stream>>>(
            xnbC, DM, inW_bf2 + (size_t)DI * DM, (long long)1024 * DM,
            ygb, DI, TcDI, xcs, TcDI, DM);
        // out_proj: dir0 -> mo = yg@outW^T + xn; dir1 -> mo1 (crev)
        k_gemm_bf<<<dim3(Tc / 128, DM / 128, 2), 256, 0, stream>>>(
            ygb, DI, TcDI, outW_bf2, (long long)DM * DI,
            moC, dsMo1, DM, xnC, DI, DM, 2);
    }

    // combined = rmsnorm(mo + mo1) -> comb_bf (xn_buf overlay)
    k_rmsnorm<<<BT / 4, 256, 0, stream>>>(mo, t_buf, norm2_w, nullptr, comb_bf, BT);
    // convd + bn + silu -> d_bf (mo overlay)
    k_conv3_bf<<<dim3(BT / 128, 2), 256, 0, stream>>>(comb_bf, 256, tb_bf, 256, Wdr,
                                                      alpha_d, beta_d, nullptr, d_bf, 256, 1, 0);
    // sp conv + pixel shuffle -> out
    k_conv3_bf<<<dim3(BT / 128, 1), 256, 0, stream>>>(d_bf, 256, nullptr, 0, Wspr,
                                                      nullptr, sp_b, out, nullptr, 128, 0, 1);
}

// Round 13
// 1113.418 us; speedup vs baseline: 1.0479x; 1.0382x over previous
//
#include <hip/hip_runtime.h>
#include <hip/hip_bf16.h>
#include <math.h>

#define B_SZ 16
#define T_LR 2560
#define BT (B_SZ * T_LR)     // 40960 tokens
#define DM 256               // d_model
#define DI 512               // d_inner
#define DS 16                // d_state
#define DTR 16               // dt_rank
#define CH 64                // scan chunks per sequence
#define CH_LOG2 6
#define CLEN (T_LR / CH)     // 40 steps per chunk

typedef __attribute__((ext_vector_type(8))) short bf16x8;
typedef __attribute__((ext_vector_type(4))) float f32x4;

__device__ __forceinline__ float silu_f(float x) {
    return x / (1.f + __expf(-x));
}
__device__ __forceinline__ unsigned short f2bf(float v) {
    __hip_bfloat16 h = __float2bfloat16(v);
    return *(unsigned short*)&h;
}
__device__ __forceinline__ float bf2f(unsigned short u) {
    union { unsigned int i; float f; } c;
    c.i = (unsigned int)u << 16;
    return c.f;
}
__device__ __forceinline__ int seqrev(int r) {
    int s = r / T_LR, t = r % T_LR;
    return s * T_LR + (T_LR - 1 - t);
}
// softplus: log(1+e). abs err ~1e-7 (vs log1pf) — negligible vs bf16 rounding.
__device__ __forceinline__ float softplus_f(float x) {
    return (x > 20.f) ? x : __logf(1.f + __expf(x));
}
// fragment-major weight swizzle: tile (tap, n/16, c/32) stores 64 lanes x 16B
// contiguously; lane (q=c5>>3, ml=n&15) gets W[n][c...c+7].
__device__ __forceinline__ size_t wswz_idx(int tap, int n, int c, int N, int Kt) {
    return ((size_t)((tap * (N >> 4) + (n >> 4)) * (Kt >> 5) + (c >> 5)) << 9)
         + (size_t)((((c >> 3) & 3) * 16 + (n & 15)) * 8 + (c & 7));
}

// ---------------------------------------------------------------------------
// mega prep kernel: all weight transforms + input transpose, one dispatch.
// ---------------------------------------------------------------------------
__global__ __launch_bounds__(256) void k_prep(
    const float* __restrict__ enc_w1, const float* __restrict__ enc_w2,
    const float* __restrict__ convd_w, const float* __restrict__ sp_w,
    const float* __restrict__ convd_b, const float* __restrict__ bn_g,
    const float* __restrict__ bn_b, const float* __restrict__ bn_mean,
    const float* __restrict__ bn_var,
    const float* __restrict__ inW0, const float* __restrict__ inW1,
    const float* __restrict__ outW0, const float* __restrict__ outW1,
    const float* __restrict__ xW0, const float* __restrict__ xW1,
    const float* __restrict__ Alog0, const float* __restrict__ Alog1,
    const float* __restrict__ x,
    unsigned short* __restrict__ W1r, unsigned short* __restrict__ W2r,
    unsigned short* __restrict__ Wdr, unsigned short* __restrict__ Wspr,
    float* __restrict__ alpha, float* __restrict__ beta,
    unsigned short* __restrict__ inW_bf2, unsigned short* __restrict__ outW_bf2,
    unsigned short* __restrict__ xW_bc2, float* __restrict__ Aflag,
    unsigned short* __restrict__ xt)
{
    __shared__ float ts[32][33];
    __shared__ int s_ok;
    int blk = blockIdx.x;
    int tid = threadIdx.x;
    if (blk < 32) {                         // W1r: (128,64,3) -> swizzled [N=128,Kt=64]
        int i = blk * 256 + tid;
        int n = i / 64, ci = i % 64;
        #pragma unroll
        for (int k = 0; k < 3; k++)
            W1r[wswz_idx(k, n, ci, 128, 64)] = f2bf(enc_w1[((size_t)n * 64 + ci) * 3 + k]);
    } else if (blk < 160) {                 // W2r: (256,128,3) -> [N=256,Kt=128]
        int i = (blk - 32) * 256 + tid;
        int n = i / 128, ci = i % 128;
        #pragma unroll
        for (int k = 0; k < 3; k++)
            W2r[wswz_idx(k, n, ci, 256, 128)] = f2bf(enc_w2[((size_t)n * 128 + ci) * 3 + k]);
    } else if (blk < 672) {                 // Wdr: (256,512,3) -> [N=256,Kt=512]
        int i = (blk - 160) * 256 + tid;
        int n = i / 512, ci = i % 512;
        #pragma unroll
        for (int k = 0; k < 3; k++)
            Wdr[wswz_idx(k, n, ci, 256, 512)] = f2bf(convd_w[((size_t)n * 512 + ci) * 3 + k]);
    } else if (blk < 800) {                 // Wspr: (128,256,3) -> [N=128,Kt=256]
        int i = (blk - 672) * 256 + tid;
        int n = i / 256, ci = i % 256;
        #pragma unroll
        for (int k = 0; k < 3; k++)
            Wspr[wswz_idx(k, n, ci, 128, 256)] = f2bf(sp_w[((size_t)n * 256 + ci) * 3 + k]);
    } else if (blk < 801) {                 // bnfold
        int c = tid;
        float a = bn_g[c] * rsqrtf(bn_var[c] + 1e-5f);
        alpha[c] = a;
        beta[c] = (convd_b[c] - bn_mean[c]) * a + bn_b[c];
    } else if (blk < 1825) {                // inW cast, both dirs (262144 each)
        int i = (blk - 801) * 256 + tid;
        inW_bf2[i] = f2bf(inW0[i]);
        inW_bf2[262144 + i] = f2bf(inW1[i]);
    } else if (blk < 2337) {                // outW cast (131072 each)
        int i = (blk - 1825) * 256 + tid;
        outW_bf2[i] = f2bf(outW0[i]);
        outW_bf2[131072 + i] = f2bf(outW1[i]);
    } else if (blk < 2433) {                // xW[0:48] cast (24576 each dir)
        int i = (blk - 2337) * 256 + tid;
        xW_bc2[i] = f2bf(xW0[i]);
        xW_bc2[24576 + i] = f2bf(xW1[i]);
    } else if (blk < 2434) {                // Alog structure check: A[d][n] == A[d][0]*(n+1)?
        if (tid == 0) s_ok = 1;
        __syncthreads();
        int ok = 1;
        for (int i = tid; i < DI * DS; i += 256) {
            int d = i >> 4, n = i & 15;
            float a0f = __expf(Alog0[d * DS]);
            float anf = __expf(Alog0[d * DS + n]);
            if (fabsf(anf - (float)(n + 1) * a0f) > 1e-3f * (float)(n + 1)) ok = 0;
            float a0b = __expf(Alog1[d * DS]);
            float anb = __expf(Alog1[d * DS + n]);
            if (fabsf(anb - (float)(n + 1) * a0b) > 1e-3f * (float)(n + 1)) ok = 0;
        }
        if (!ok) atomicAnd(&s_ok, 0);
        __syncthreads();
        if (tid == 0) Aflag[0] = s_ok ? 1.f : 0.f;
    } else {                                // transpose x (b,64,T) f32 -> xt (b,T,64) bf16
        int idx = blk - 2434;               // b(16) x c0(2) x t0(80)
        int t0 = (idx % 80) * 32;
        int c0 = ((idx / 80) & 1) * 32;
        int b = idx / 160;
        int tx = tid & 31, ty = tid >> 5;
        #pragma unroll
        for (int j = 0; j < 4; j++) {
            int c = c0 + ty + j * 8;
            ts[ty + j * 8][tx] = x[((size_t)b * 64 + c) * T_LR + t0 + tx];
        }
        __syncthreads();
        #pragma unroll
        for (int j = 0; j < 4; j++) {
            int t = t0 + ty + j * 8;
            xt[((size_t)b * T_LR + t) * 64 + c0 + tx] = f2bf(ts[tx][ty + j * 8]);
        }
    }
}

// ---------------------------------------------------------------------------
// implicit-GEMM k=3 "same" conv via MFMA (encoder/decoder convs).
// M-tile = 128 rows; As double-buffered, one barrier per k-step.
// R9 proven best: fragment-major swizzled B (contiguous 1KB bursts) +
// LDS-transposed coalesced epilogue.
// ---------------------------------------------------------------------------
__global__ __launch_bounds__(256, 3) void k_conv3_bf(const unsigned short* __restrict__ A1, int K1,
                                                  const unsigned short* __restrict__ A2, int K2,
                                                  const unsigned short* __restrict__ Wz,
                                                  const float* __restrict__ alpha,
                                                  const float* __restrict__ beta,
                                                  float* __restrict__ outf,
                                                  unsigned short* __restrict__ outb,
                                                  int N, int dosilu, int pixsh) {
    int Kt = K1 + K2;
    __shared__ __align__(16) unsigned short smem[2 * 130 * 40];   // 20800 B
    unsigned short (*As)[130][40] = (unsigned short (*)[130][40])smem;
    float* sC = (float*)smem;                                     // 32 x 140 f32 (17920 B)
    int tid = threadIdx.x;
    int wave = tid >> 6, lane = tid & 63;
    int wm = (wave >> 1) * 64, wn = (wave & 1) * 64;
    int m0 = blockIdx.x * 128, n0 = blockIdx.y * 128;
    int b = m0 / T_LR, t0 = m0 % T_LR;
    int q = lane >> 4, ml = lane & 15;
    int Nb16 = N >> 4, Kb32 = Kt >> 5;
    int nb0 = (n0 + wn) >> 4;
    const unsigned short* wl = Wz + (size_t)lane * 8;
    f32x4 acc[4][4] = {};
    int cq = tid & 3;
    int r0 = tid >> 2;
    int r1 = r0 + 64;
    int r2 = r0 + 128;
    bool has2 = (tid < 8);
    int ta0 = t0 - 1 + r0, ta1 = t0 - 1 + r1, ta2 = t0 - 1 + r2;
    bool va0 = (ta0 >= 0) && (ta0 < T_LR);
    bool va1 = (ta1 < T_LR);
    bool va2 = has2 && (ta2 < T_LR);
    uint4 v0, v1, v2;
    #define LOADA(vv, valid, t, col) { vv = make_uint4(0u,0u,0u,0u); if (valid) { \
        const unsigned short* src = ((col) < K1) \
            ? A1 + (size_t)(b * T_LR + (t)) * K1 + (col) \
            : A2 + (size_t)(b * T_LR + (t)) * K2 + ((col) - K1); \
        vv = *(const uint4*)src; } }
    LOADA(v0, va0, ta0, cq * 8);
    LOADA(v1, va1, ta1, cq * 8);
    LOADA(v2, va2, ta2, cq * 8);
    *(uint4*)&As[0][r0][cq * 8] = v0;
    *(uint4*)&As[0][r1][cq * 8] = v1;
    if (has2) *(uint4*)&As[0][r2][cq * 8] = v2;
    int nk = Kb32;
    for (int kk = 0; kk < nk; kk++) {
        __syncthreads();
        int cur = kk & 1;
        if (kk + 1 < nk) {
            int col = ((kk + 1) << 5) + cq * 8;
            LOADA(v0, va0, ta0, col);
            LOADA(v1, va1, ta1, col);
            LOADA(v2, va2, ta2, col);
        }
        #pragma unroll
        for (int tap = 0; tap < 3; tap++) {
            int tb = tap * Nb16 + nb0;
            bf16x8 bfr[4];
            #pragma unroll
            for (int ni = 0; ni < 4; ni++)
                bfr[ni] = *(const bf16x8*)(wl + ((size_t)((tb + ni) * Kb32 + kk) << 9));
            #pragma unroll
            for (int mi = 0; mi < 4; mi++) {
                bf16x8 af = *(const bf16x8*)&As[cur][wm + mi * 16 + ml + tap][q * 8];
                #pragma unroll
                for (int ni = 0; ni < 4; ni++)
                    acc[mi][ni] = __builtin_amdgcn_mfma_f32_16x16x32_bf16(af, bfr[ni], acc[mi][ni], 0, 0, 0);
            }
        }
        if (kk + 1 < nk) {
            *(uint4*)&As[cur ^ 1][r0][cq * 8] = v0;
            *(uint4*)&As[cur ^ 1][r1][cq * 8] = v1;
            if (has2) *(uint4*)&As[cur ^ 1][r2][cq * 8] = v2;
        }
    }
    #undef LOADA
    // epilogue: 4 passes of 32 rows through LDS (reuses As space), coalesced
    // vectorized stores.
    int rowoff = m0 - b * T_LR;   // local t of row 0
    #pragma unroll
    for (int p = 0; p < 4; p++) {
        __syncthreads();
        if ((wave >> 1) == (p >> 1)) {
            int mib = (p & 1) * 2;
            #pragma unroll
            for (int m2 = 0; m2 < 2; m2++) {
                int mi = mib + m2;
                int rl = mi * 16 + q * 4 - (p & 1) * 32;
                #pragma unroll
                for (int r = 0; r < 4; r++)
                    #pragma unroll
                    for (int ni = 0; ni < 4; ni++)
                        sC[(rl + r) * 140 + wn + ni * 16 + ml] = acc[mi][ni][r];
            }
        }
        __syncthreads();
        if (pixsh) {
            // N=128, n0=0: col=2*c2+rr -> out[((b*64+c2)*T + t)*2 + rr]
            int row = tid & 31, c2g = tid >> 5;
            int t = rowoff + p * 32 + row;
            float* dst = outf + ((size_t)b * 64 * T_LR + t) * 2;
            #pragma unroll
            for (int j = 0; j < 8; j++) {
                int c2 = c2g + j * 8;
                float va = sC[row * 140 + 2 * c2]     + beta[2 * c2];
                float vb = sC[row * 140 + 2 * c2 + 1] + beta[2 * c2 + 1];
                *(float2*)&dst[(size_t)c2 * T_LR * 2] = make_float2(va, vb);
            }
        } else {
            #pragma unroll
            for (int gi = 0; gi < 2; gi++) {
                int g = tid + gi * 256;
                int row = g >> 4;
                int colg = (g & 15) * 8;
                int mr = m0 + p * 32 + row;
                const float* src = sC + row * 140 + colg;
                float vv[8];
                *(float4*)&vv[0] = *(const float4*)src;
                *(float4*)&vv[4] = *(const float4*)(src + 4);
                unsigned short ob[8];
                #pragma unroll
                for (int jj = 0; jj < 8; jj++) {
                    int col = n0 + colg + jj;
                    float a = alpha ? alpha[col] : 1.f;
                    float v = vv[jj] * a + beta[col];
                    if (dosilu) v = silu_f(v);
                    vv[jj] = v;
                    ob[jj] = f2bf(v);
                }
                if (outf) {
                    *(float4*)(outf + (size_t)mr * N + n0 + colg) = *(float4*)&vv[0];
                    *(float4*)(outf + (size_t)mr * N + n0 + colg + 4) = *(float4*)&vv[4];
                }
                if (outb)
                    *(uint4*)(outb + (size_t)mr * N + n0 + colg) = *(uint4*)ob;
            }
        }
    }
}

// ---------------------------------------------------------------------------
// fused in_proj (FULL 1024 cols) + causal dwconv + silu.
// BOTH directions in one dispatch: dir = blockIdx.z.
// n0 <  512: xc half -> dwconv k=4 + silu -> xcs bf16.
// n0 >= 512: z  half -> raw bf16 z -> zb (gate applied later in scan p3).
// R13: absorbs the former z-gate GEMM's A/B work; the gate itself moved to
// scan p3 (eliminates gate-read + yg-write traffic + one 2560-block launch).
// ---------------------------------------------------------------------------
__global__ __launch_bounds__(256) void k_inproj_conv(const unsigned short* __restrict__ xn,
                                                     const unsigned short* __restrict__ inW2,
                                                     const float* __restrict__ cw0,
                                                     const float* __restrict__ cw1,
                                                     const float* __restrict__ cb0,
                                                     const float* __restrict__ cb1,
                                                     unsigned short* __restrict__ xcs,
                                                     unsigned short* __restrict__ zb,
                                                     long long dsXcs) {
    __shared__ unsigned short As[128][40];
    __shared__ unsigned short Bs[128][40];
    __shared__ unsigned short Ct[131][136];   // rows: internal t0-3 .. t0+127
    int dir = blockIdx.z;
    int arev = dir;
    const unsigned short* inW = inW2 + (size_t)dir * 1024 * DM;
    xcs += (size_t)dir * dsXcs;
    zb  += (size_t)dir * dsXcs;
    int tid = threadIdx.x;
    int wave = tid >> 6, lane = tid & 63;
    int wm = (wave >> 1) * 64, wn = (wave & 1) * 64;
    int m0 = blockIdx.x * 128, n0 = blockIdx.y * 128;   // n0 in [0,1024)
    int b = m0 / T_LR, t0 = m0 % T_LR;
    int sc = tid & 3, sr = tid >> 2;
    int ar0 = m0 + sr, ar1 = m0 + sr + 64;
    if (arev) { ar0 = seqrev(ar0); ar1 = seqrev(ar1); }
    const unsigned short* ap0 = xn + (size_t)ar0 * DM + sc * 8;
    const unsigned short* ap1 = xn + (size_t)ar1 * DM + sc * 8;
    const unsigned short* bp0 = inW + (size_t)(n0 + sr) * DM + sc * 8;
    const unsigned short* bp1 = inW + (size_t)(n0 + sr + 64) * DM + sc * 8;
    f32x4 acc[4][4] = {};
    int q = lane >> 4, ml = lane & 15;
    for (int k0 = 0; k0 < DM; k0 += 32) {
        uint4 a0 = *(const uint4*)(ap0 + k0);
        uint4 a1 = *(const uint4*)(ap1 + k0);
        uint4 b0 = *(const uint4*)(bp0 + k0);
        uint4 b1 = *(const uint4*)(bp1 + k0);
        __syncthreads();
        *(uint4*)&As[sr][sc * 8]      = a0;
        *(uint4*)&As[sr + 64][sc * 8] = a1;
        *(uint4*)&Bs[sr][sc * 8]      = b0;
        *(uint4*)&Bs[sr + 64][sc * 8] = b1;
        __syncthreads();
        bf16x8 af[4], bfr[4];
        #pragma unroll
        for (int mi = 0; mi < 4; mi++)
            af[mi] = *(const bf16x8*)&As[wm + mi * 16 + ml][q * 8];
        #pragma unroll
        for (int ni = 0; ni < 4; ni++)
            bfr[ni] = *(const bf16x8*)&Bs[wn + ni * 16 + ml][q * 8];
        #pragma unroll
        for (int mi = 0; mi < 4; mi++)
            #pragma unroll
            for (int ni = 0; ni < 4; ni++)
                acc[mi][ni] = __builtin_amdgcn_mfma_f32_16x16x32_bf16(af[mi], bfr[ni], acc[mi][ni], 0, 0, 0);
    }
    if (n0 < DI) {
        const float* cw = dir ? cw1 : cw0;
        const float* cb = dir ? cb1 : cb0;
        // main tile -> Ct rows 3..130
        #pragma unroll
        for (int mi = 0; mi < 4; mi++)
            #pragma unroll
            for (int r = 0; r < 4; r++)
                #pragma unroll
                for (int ni = 0; ni < 4; ni++)
                    Ct[3 + wm + mi * 16 + q * 4 + r][wn + ni * 16 + ml] = f2bf(acc[mi][ni][r]);
        // halo rows 0..2 via direct dot — 384 items on 256 threads
        for (int i = tid; i < 384; i += 256) {
            int hr = i >> 7, c = i & 127;
            int tr = t0 - 3 + hr;
            float v = 0.f;
            if (tr >= 0) {
                int src = b * T_LR + (arev ? (T_LR - 1 - tr) : tr);
                const unsigned short* xr = xn + (size_t)src * DM;
                const unsigned short* wr = inW + (size_t)(n0 + c) * DM;
                for (int k = 0; k < DM; k += 8) {
                    uint4 xa = *(const uint4*)(xr + k);
                    uint4 wa = *(const uint4*)(wr + k);
                    const unsigned short* xs = (const unsigned short*)&xa;
                    const unsigned short* wsp = (const unsigned short*)&wa;
                    #pragma unroll
                    for (int j = 0; j < 8; j++) v += bf2f(xs[j]) * bf2f(wsp[j]);
                }
            }
            Ct[hr][c] = f2bf(v);
        }
        __syncthreads();
        // causal conv k=4 + silu, write xcs bf16
        int col = tid & 127;
        int d = n0 + col;
        float w0 = cw[d * 4 + 0], w1 = cw[d * 4 + 1], w2 = cw[d * 4 + 2], w3 = cw[d * 4 + 3];
        float bi = cb[d];
        int rbase = tid >> 7;
        for (int j = 0; j < 64; j++) {
            int row = rbase + 2 * j;
            float v = bi + bf2f(Ct[row][col]) * w0 + bf2f(Ct[row + 1][col]) * w1
                         + bf2f(Ct[row + 2][col]) * w2 + bf2f(Ct[row + 3][col]) * w3;
            xcs[(size_t)(m0 + row) * DI + d] = f2bf(silu_f(v));
        }
    } else {
        // z half: raw bf16 store via Ct staging, coalesced uint4 writes
        #pragma unroll
        for (int mi = 0; mi < 4; mi++)
            #pragma unroll
            for (int r = 0; r < 4; r++)
                #pragma unroll
                for (int ni = 0; ni < 4; ni++)
                    Ct[wm + mi * 16 + q * 4 + r][wn + ni * 16 + ml] = f2bf(acc[mi][ni][r]);
        __syncthreads();
        int zc0 = n0 - DI;
        #pragma unroll
        for (int gi = 0; gi < 2; gi++) {
            int g = tid + gi * 256;
            int row = g >> 2;              // 0..127
            int colg = (g & 3) * 32;       // 0,32,64,96
            unsigned short* dst = zb + (size_t)(m0 + row) * DI + zc0 + colg;
            const unsigned short* srcc = &Ct[row][colg];
            *(uint4*)(dst)      = *(const uint4*)(srcc);
            *(uint4*)(dst + 8)  = *(const uint4*)(srcc + 8);
            *(uint4*)(dst + 16) = *(const uint4*)(srcc + 16);
            *(uint4*)(dst + 24) = *(const uint4*)(srcc + 24);
        }
    }
}

// ---------------------------------------------------------------------------
// rmsnorm over last dim (256). One wave per token. Optional second input
// summed in (mo + mo1). fp32 and/or bf16 out.
// ---------------------------------------------------------------------------
__global__ __launch_bounds__(256) void k_rmsnorm(const float* __restrict__ in1,
                                                 const float* __restrict__ in2,
                                                 const float* __restrict__ w,
                                                 float* __restrict__ out,
                                                 unsigned short* __restrict__ out_bf,
                                                 int ntok) {
    int tok = (blockIdx.x * 256 + threadIdx.x) >> 6;
    int lane = threadIdx.x & 63;
    if (tok >= ntok) return;
    float4 v = ((const float4*)(in1 + (size_t)tok * DM))[lane];
    if (in2) {
        float4 u = ((const float4*)(in2 + (size_t)tok * DM))[lane];
        v.x += u.x; v.y += u.y; v.z += u.z; v.w += u.w;
    }
    float ss = v.x * v.x + v.y * v.y + v.z * v.z + v.w * v.w;
    #pragma unroll
    for (int off = 32; off > 0; off >>= 1) ss += __shfl_xor(ss, off);
    float sc = rsqrtf(ss * (1.f / 256.f) + 1e-6f);
    float4 wv = ((const float4*)w)[lane];
    float4 o;
    o.x = v.x * sc * wv.x; o.y = v.y * sc * wv.y;
    o.z = v.z * sc * wv.z; o.w = v.w * sc * wv.w;
    if (out) ((float4*)(out + (size_t)tok * DM))[lane] = o;
    if (out_bf) {
        ushort4 ob;
        ob.x = f2bf(o.x); ob.y = f2bf(o.y); ob.z = f2bf(o.z); ob.w = f2bf(o.w);
        ((ushort4*)(out_bf + (size_t)tok * DM))[lane] = ob;
    }
}

// ---------------------------------------------------------------------------
// bf16 MFMA GEMM, fp32 out + optional residual (db and out_proj).
// BOTH directions per dispatch: dir = blockIdx.z applies element strides.
// crevmode: 0 = never reverse output rows, 2 = reverse iff dir==1.
// ---------------------------------------------------------------------------
__global__ __launch_bounds__(256) void k_gemm_bf(const unsigned short* __restrict__ A, int lda, long long dsA,
                                                 const unsigned short* __restrict__ Bw, long long dsB,
                                                 float* Cf, long long dsCf, int ldc,
                                                 const float* __restrict__ res,
                                                 int K, int Nout, int crevmode) {
    __shared__ unsigned short As[128][40];
    __shared__ unsigned short Bs[128][40];
    int dir = blockIdx.z;
    A += (long long)dir * dsA;
    Bw += (long long)dir * dsB;
    Cf += (long long)dir * dsCf;
    int crev = (crevmode == 2) ? dir : crevmode;
    int tid = threadIdx.x;
    int wave = tid >> 6, lane = tid & 63;
    int wm = (wave >> 1) * 64, wn = (wave & 1) * 64;
    int m0 = blockIdx.x * 128, n0 = blockIdx.y * 128;
    int sc = tid & 3, sr = tid >> 2;
    const unsigned short* ap0 = A + (size_t)(m0 + sr) * lda + sc * 8;
    const unsigned short* ap1 = A + (size_t)(m0 + sr + 64) * lda + sc * 8;
    bool bv0 = (n0 + sr) < Nout;
    bool bv1 = (n0 + sr + 64) < Nout;
    const unsigned short* bp0 = Bw + (size_t)(n0 + sr) * K + sc * 8;
    const unsigned short* bp1 = Bw + (size_t)(n0 + sr + 64) * K + sc * 8;
    f32x4 acc[4][4] = {};
    int q = lane >> 4, ml = lane & 15;
    for (int k0 = 0; k0 < K; k0 += 32) {
        uint4 a0 = *(const uint4*)(ap0 + k0);
        uint4 a1 = *(const uint4*)(ap1 + k0);
        uint4 b0 = make_uint4(0u, 0u, 0u, 0u), b1 = make_uint4(0u, 0u, 0u, 0u);
        if (bv0) b0 = *(const uint4*)(bp0 + k0);
        if (bv1) b1 = *(const uint4*)(bp1 + k0);
        __syncthreads();
        *(uint4*)&As[sr][sc * 8]      = a0;
        *(uint4*)&As[sr + 64][sc * 8] = a1;
        *(uint4*)&Bs[sr][sc * 8]      = b0;
        *(uint4*)&Bs[sr + 64][sc * 8] = b1;
        __syncthreads();
        bf16x8 af[4], bfr[4];
        #pragma unroll
        for (int mi = 0; mi < 4; mi++)
            af[mi] = *(const bf16x8*)&As[wm + mi * 16 + ml][q * 8];
        #pragma unroll
        for (int ni = 0; ni < 4; ni++)
            bfr[ni] = *(const bf16x8*)&Bs[wn + ni * 16 + ml][q * 8];
        #pragma unroll
        for (int mi = 0; mi < 4; mi++)
            #pragma unroll
            for (int ni = 0; ni < 4; ni++)
                acc[mi][ni] = __builtin_amdgcn_mfma_f32_16x16x32_bf16(af[mi], bfr[ni], acc[mi][ni], 0, 0, 0);
    }
    #pragma unroll
    for (int mi = 0; mi < 4; mi++) {
        #pragma unroll
        for (int r = 0; r < 4; r++) {
            int mr = m0 + wm + mi * 16 + q * 4 + r;
            int orow = crev ? seqrev(mr) : mr;
            #pragma unroll
            for (int ni = 0; ni < 4; ni++) {
                int col = n0 + wn + ni * 16 + ml;
                if (col < Nout) {
                    float v = acc[mi][ni][r];
                    if (res) v += res[(size_t)orow * ldc + col];
                    Cf[(size_t)orow * ldc + col] = v;
                }
            }
        }
    }
}

// ---------------------------------------------------------------------------
// scan phase 1: per (dir*bl, chunk, d) thread. Both dirs in one dispatch:
// buffers laid [2*Bc][...]; dir = (bl >= Bc) selects the weight set.
// dt computed in-line (low-rank); fast path when Aflag set.
// ---------------------------------------------------------------------------
__global__ __launch_bounds__(256) void k_scan_p1(const unsigned short* __restrict__ x,
                                                 const float* __restrict__ db,
                                                 const float* __restrict__ dtW0, const float* __restrict__ dtW1,
                                                 const float* __restrict__ dtb0, const float* __restrict__ dtb1,
                                                 const float* __restrict__ Alog0, const float* __restrict__ Alog1,
                                                 const float* __restrict__ Aflag,
                                                 float* __restrict__ hS,
                                                 float* __restrict__ csum, int Bc) {
    __shared__ float dbs[CLEN * 48];
    int tid = threadIdx.x;
    int gid = blockIdx.x * 256 + tid;   // ((dir*Bc+bl)*CH + c)*DI + d
    int d = gid & (DI - 1);
    int bcix = gid >> 9;
    int c = bcix & (CH - 1);
    int bl = bcix >> CH_LOG2;           // [0, 2*Bc)
    int dir = (bl >= Bc) ? 1 : 0;
    const float* dtW  = dir ? dtW1  : dtW0;
    const float* dtb  = dir ? dtb1  : dtb0;
    const float* Alog = dir ? Alog1 : Alog0;
    int tbase = c * CLEN;
    const float* dbp = db + ((size_t)bl * T_LR + tbase) * 48;
    for (int i = tid; i < (CLEN * 48) / 4; i += 256)
        *(float4*)&dbs[i * 4] = *(const float4*)(dbp + i * 4);
    bool fast = (Aflag[0] != 0.f);
    float A0 = -__expf(Alog[d * DS]);
    float Av[DS], h[DS];
    #pragma unroll
    for (int n = 0; n < DS; n++) h[n] = 0.f;
    if (!fast) {
        #pragma unroll
        for (int n = 0; n < DS; n++) Av[n] = -__expf(Alog[d * DS + n]);
    }
    const float4* wp = (const float4*)(dtW + d * 16);
    float4 w0 = wp[0], w1 = wp[1], w2 = wp[2], w3 = wp[3];
    float bias = dtb[d];
    const unsigned short* xp = x + ((size_t)bl * T_LR + tbase) * DI + d;
    float S = 0.f;
    __syncthreads();
    for (int t = 0; t < CLEN; t++) {
        const float* bc = dbs + t * 48;
        float dl = bias
            + bc[0] * w0.x + bc[1] * w0.y + bc[2] * w0.z + bc[3] * w0.w
            + bc[4] * w1.x + bc[5] * w1.y + bc[6] * w1.z + bc[7] * w1.w
            + bc[8] * w2.x + bc[9] * w2.y + bc[10] * w2.z + bc[11] * w2.w
            + bc[12] * w3.x + bc[13] * w3.y + bc[14] * w3.z + bc[15] * w3.w;
        float dtv = softplus_f(dl);
        float xv  = bf2f(xp[(size_t)t * DI]);
        float dtx = dtv * xv;
        S += dtv;
        if (fast) {
            float e1 = __expf(dtv * A0);
            float e = e1;
            #pragma unroll
            for (int n = 0; n < DS; n++) {
                h[n] = e * h[n] + dtx * bc[16 + n];
                e *= e1;
            }
        } else {
            #pragma unroll
            for (int n = 0; n < DS; n++)
                h[n] = __expf(dtv * Av[n]) * h[n] + dtx * bc[16 + n];
        }
    }
    float* hp = hS + (size_t)gid * DS;
    #pragma unroll
    for (int n = 0; n < DS; n++) hp[n] = h[n];
    csum[gid] = S;
}

// ---------------------------------------------------------------------------
// scan phase 2: per (dir*bl, d, n) thread; sequential over CH chunks.
// ---------------------------------------------------------------------------
__global__ __launch_bounds__(256) void k_scan_p2(float* __restrict__ hS,
                                                 const float* __restrict__ csum,
                                                 const float* __restrict__ Alog0,
                                                 const float* __restrict__ Alog1, int Bc) {
    int gid = blockIdx.x * 256 + threadIdx.x;   // ((dir*Bc+bl)*DI + d)*DS + n
    int n = gid & (DS - 1);
    int d = (gid >> 4) & (DI - 1);
    int bl = gid >> 13;                         // [0, 2*Bc)
    const float* Alog = (bl >= Bc) ? Alog1 : Alog0;
    float An = -__expf(Alog[d * DS + n]);
    float hs = 0.f;
    for (int c = 0; c < CH; c++) {
        size_t base = ((size_t)(bl * CH + c) * DI + d);
        float he = hS[base * DS + n];
        float S  = csum[base];
        hS[base * DS + n] = hs;
        hs = __expf(An * S) * hs + he;
    }
}

// ---------------------------------------------------------------------------
// scan phase 3: corrected chunk-start state; fused z-gate:
// yg = silu(z) * (y + x*D) written bf16 in place over x.
// ---------------------------------------------------------------------------
__global__ __launch_bounds__(256) void k_scan_p3(unsigned short* __restrict__ x,
                                                 const unsigned short* __restrict__ zb,
                                                 const float* __restrict__ db,
                                                 const float* __restrict__ dtW0, const float* __restrict__ dtW1,
                                                 const float* __restrict__ dtb0, const float* __restrict__ dtb1,
                                                 const float* __restrict__ Alog0, const float* __restrict__ Alog1,
                                                 const float* __restrict__ Aflag,
                                                 const float* __restrict__ Dp0, const float* __restrict__ Dp1,
                                                 const float* __restrict__ hS, int Bc) {
    __shared__ float dbs[CLEN * 48];
    int tid = threadIdx.x;
    int gid = blockIdx.x * 256 + tid;
    int d = gid & (DI - 1);
    int bcix = gid >> 9;
    int c = bcix & (CH - 1);
    int bl = bcix >> CH_LOG2;
    int dir = (bl >= Bc) ? 1 : 0;
    const float* dtW  = dir ? dtW1  : dtW0;
    const float* dtb  = dir ? dtb1  : dtb0;
    const float* Alog = dir ? Alog1 : Alog0;
    const float* Dp   = dir ? Dp1   : Dp0;
    int tbase = c * CLEN;
    const float* dbp = db + ((size_t)bl * T_LR + tbase) * 48;
    for (int i = tid; i < (CLEN * 48) / 4; i += 256)
        *(float4*)&dbs[i * 4] = *(const float4*)(dbp + i * 4);
    bool fast = (Aflag[0] != 0.f);
    float A0 = -__expf(Alog[d * DS]);
    float Av[DS], h[DS];
    const float* hp = hS + (size_t)gid * DS;
    #pragma unroll
    for (int n = 0; n < DS; n++) h[n] = hp[n];
    if (!fast) {
        #pragma unroll
        for (int n = 0; n < DS; n++) Av[n] = -__expf(Alog[d * DS + n]);
    }
    const float4* wp = (const float4*)(dtW + d * 16);
    float4 w0 = wp[0], w1 = wp[1], w2 = wp[2], w3 = wp[3];
    float bias = dtb[d];
    float Dd = Dp[d];
    unsigned short* xp = x + ((size_t)bl * T_LR + tbase) * DI + d;
    const unsigned short* zp = zb + ((size_t)bl * T_LR + tbase) * DI + d;
    __syncthreads();
    for (int t = 0; t < CLEN; t++) {
        const float* bc = dbs + t * 48;
        float dl = bias
            + bc[0] * w0.x + bc[1] * w0.y + bc[2] * w0.z + bc[3] * w0.w
            + bc[4] * w1.x + bc[5] * w1.y + bc[6] * w1.z + bc[7] * w1.w
            + bc[8] * w2.x + bc[9] * w2.y + bc[10] * w2.z + bc[11] * w2.w
            + bc[12] * w3.x + bc[13] * w3.y + bc[14] * w3.z + bc[15] * w3.w;
        float dtv = softplus_f(dl);
        float xv  = bf2f(xp[(size_t)t * DI]);
        float dtx = dtv * xv;
        float acc = 0.f;
        if (fast) {
            float e1 = __expf(dtv * A0);
            float e = e1;
            #pragma unroll
            for (int n = 0; n < DS; n++) {
                h[n] = e * h[n] + dtx * bc[16 + n];
                acc += h[n] * bc[32 + n];
                e *= e1;
            }
        } else {
            #pragma unroll
            for (int n = 0; n < DS; n++) {
                h[n] = __expf(dtv * Av[n]) * h[n] + dtx * bc[16 + n];
                acc += h[n] * bc[32 + n];
            }
        }
        float yv = acc + xv * Dd;
        float zv = bf2f(zp[(size_t)t * DI]);
        xp[(size_t)t * DI] = f2bf(silu_f(zv) * yv);
    }
}

// ---------------------------------------------------------------------------
extern "C" void kernel_launch(void* const* d_in, const int* in_sizes, int n_in,
                              void* d_out, int out_size, void* d_ws, size_t ws_size,
                              hipStream_t stream) {
    const float* x       = (const float*)d_in[0];
    const float* enc_w1  = (const float*)d_in[1];
    const float* enc_b1  = (const float*)d_in[2];
    const float* enc_w2  = (const float*)d_in[3];
    const float* enc_b2  = (const float*)d_in[4];
    const float* norm1_w = (const float*)d_in[5];
    const float* norm2_w = (const float*)d_in[6];
    const float* convd_w = (const float*)d_in[25];
    const float* convd_b = (const float*)d_in[26];
    const float* bn_g    = (const float*)d_in[27];
    const float* bn_b    = (const float*)d_in[28];
    const float* bn_mean = (const float*)d_in[29];
    const float* bn_var  = (const float*)d_in[30];
    const float* sp_w    = (const float*)d_in[31];
    const float* sp_b    = (const float*)d_in[32];
    float* out = (float*)d_out;

    const float* inW0   = (const float*)d_in[7];
    const float* cw0    = (const float*)d_in[8];
    const float* cb0    = (const float*)d_in[9];
    const float* xW0    = (const float*)d_in[10];
    const float* dtW0   = (const float*)d_in[11];
    const float* dtb0   = (const float*)d_in[12];
    const float* Alog0  = (const float*)d_in[13];
    const float* Dp0    = (const float*)d_in[14];
    const float* outW0  = (const float*)d_in[15];
    const float* inW1   = (const float*)d_in[16];
    const float* cw1    = (const float*)d_in[17];
    const float* cb1    = (const float*)d_in[18];
    const float* xW1    = (const float*)d_in[19];
    const float* dtW1   = (const float*)d_in[20];
    const float* dtb1   = (const float*)d_in[21];
    const float* Alog1  = (const float*)d_in[22];
    const float* Dp1    = (const float*)d_in[23];
    const float* outW1  = (const float*)d_in[24];

    // ---- workspace layout (float slots) ----
    float* ws = (float*)d_ws;
    size_t availf = ws_size / sizeof(float);
    size_t o = 0;
    float* t_buf  = ws + o; o += (size_t)BT * DM;       // enc f32; later mo1
    float* xn_buf = ws + o; o += (size_t)BT * DM;       // later: comb_bf overlay
    float* mo     = ws + o; o += (size_t)BT * DM;       // early: xt/e1t; late: d_bf overlay
    unsigned short* xn_bf = (unsigned short*)(ws + o); o += (size_t)BT * DM / 2;
    unsigned short* tb_bf = (unsigned short*)(ws + o); o += (size_t)BT * DM / 2;
    unsigned short* inW_bf2  = (unsigned short*)(ws + o); o += (size_t)1024 * DM;   // 2 dirs
    unsigned short* outW_bf2 = (unsigned short*)(ws + o); o += (size_t)DM * DI;     // 2 dirs
    unsigned short* xW_bc2   = (unsigned short*)(ws + o); o += (size_t)48 * DI;     // 2 dirs x 48x512
    unsigned short* W1r  = (unsigned short*)(ws + o); o += (3 * 128 * 64) / 2;
    unsigned short* W2r  = (unsigned short*)(ws + o); o += (3 * 256 * 128) / 2;
    unsigned short* Wdr  = (unsigned short*)(ws + o); o += (3 * 256 * 512) / 2;
    unsigned short* Wspr = (unsigned short*)(ws + o); o += (3 * 128 * 256) / 2;
    float* alpha_d = ws + o; o += 256;
    float* beta_d  = ws + o; o += 256;
    float* Aflag_d = ws + o; o += 4;
    size_t persist = o;
    float* scratch = ws + persist;
    size_t scratch_avail = (availf > persist) ? (availf - persist) : 0;
    // per-batch scratch for BOTH dirs (float slots): xcs bf16 + zb bf16 +
    // db f32(48) + hS + csum  (zb replaces the old ygb slot — same size)
    size_t per_b2 = 2 * ((size_t)T_LR * DI / 2 * 2 + (size_t)T_LR * 48
                         + (size_t)CH * DI * (DS + 1));
    int Bc = 16;
    while (Bc > 1 && (size_t)Bc * per_b2 > scratch_avail) Bc >>= 1;

    // encoder temporaries overlay mo (dead until out_proj)
    unsigned short* xt  = (unsigned short*)mo;                         // (b,T,64) bf16
    unsigned short* e1t = (unsigned short*)(mo + (size_t)BT * 64 / 2); // (b,T,128) bf16
    unsigned short* comb_bf = (unsigned short*)xn_buf;   // overlay after xn dead
    unsigned short* d_bf = (unsigned short*)mo;          // overlay after mo dead

    // single mega prep dispatch
    k_prep<<<4994, 256, 0, stream>>>(enc_w1, enc_w2, convd_w, sp_w,
                                     convd_b, bn_g, bn_b, bn_mean, bn_var,
                                     inW0, inW1, outW0, outW1, xW0, xW1,
                                     Alog0, Alog1,
                                     x, W1r, W2r, Wdr, Wspr, alpha_d, beta_d,
                                     inW_bf2, outW_bf2, xW_bc2, Aflag_d, xt);

    // encoder (M-tile = 128 rows)
    k_conv3_bf<<<dim3(BT / 128, 1), 256, 0, stream>>>(xt, 64, nullptr, 0, W1r,
                                                      nullptr, enc_b1, nullptr, e1t, 128, 1, 0);
    k_conv3_bf<<<dim3(BT / 128, 2), 256, 0, stream>>>(e1t, 128, nullptr, 0, W2r,
                                                      nullptr, enc_b2, t_buf, tb_bf, 256, 1, 0);
    k_rmsnorm<<<BT / 4, 256, 0, stream>>>(t_buf, nullptr, norm1_w, xn_buf, xn_bf, BT);

    // mamba: both directions per dispatch (dir = blockIdx.z / doubled bl).
    long long dsMo1 = (long long)(t_buf - mo);
    for (int b0 = 0; b0 < B_SZ; b0 += Bc) {
        int Tc = Bc * T_LR;
        long long TcDI = (long long)Tc * DI;
        unsigned short* xcs = (unsigned short*)scratch;              // [2][Tc][DI] bf16, later yg
        unsigned short* zb  = xcs + (size_t)2 * Tc * DI;             // [2][Tc][DI] bf16 raw z
        float* db   = (float*)(zb + (size_t)2 * Tc * DI);            // [2][Tc][48]
        float* hS   = db + (size_t)2 * Tc * 48;                      // [2Bc][CH][DI][DS]
        float* csum = hS + (size_t)2 * Bc * CH * DI * DS;            // [2Bc][CH][DI]
        const float*          xnC  = xn_buf + (size_t)b0 * T_LR * DM;
        const unsigned short* xnbC = xn_bf  + (size_t)b0 * T_LR * DM;
        float*                moC  = mo     + (size_t)b0 * T_LR * DM;
        // fused in_proj (xc + z halves) + causal dwconv + silu (both dirs)
        k_inproj_conv<<<dim3(Tc / 128, 1024 / 128, 2), 256, 0, stream>>>(
            xnbC, inW_bf2, cw0, cw1, cb0, cb1, xcs, zb, TcDI);
        // db (dt_low,B,C) = xcs @ xW[0:48]^T -> fp32 (both dirs)
        k_gemm_bf<<<dim3(Tc / 128, 1, 2), 256, 0, stream>>>(
            xcs, DI, TcDI, xW_bc2, (long long)48 * DI,
            db, (long long)Tc * 48, 48, nullptr, DI, 48, 0);
        // chunked scan (CH=64, CLEN=40), both dirs; p3 fuses z-gate -> yg in xcs
        k_scan_p1<<<(2 * Bc * CH * DI) / 256, 256, 0, stream>>>(
            xcs, db, dtW0, dtW1, dtb0, dtb1, Alog0, Alog1, Aflag_d, hS, csum, Bc);
        k_scan_p2<<<(2 * Bc * DI * DS) / 256, 256, 0, stream>>>(
            hS, csum, Alog0, Alog1, Bc);
        k_scan_p3<<<(2 * Bc * CH * DI) / 256, 256, 0, stream>>>(
            xcs, zb, db, dtW0, dtW1, dtb0, dtb1, Alog0, Alog1, Aflag_d, Dp0, Dp1, hS, Bc);
        // out_proj: dir0 -> mo = yg@outW^T + xn; dir1 -> mo1 (crev)
        k_gemm_bf<<<dim3(Tc / 128, DM / 128, 2), 256, 0, stream>>>(
            xcs, DI, TcDI, outW_bf2, (long long)DM * DI,
            moC, dsMo1, DM, xnC, DI, DM, 2);
    }

    // combined = rmsnorm(mo + mo1) -> comb_bf (xn_buf overlay)
    k_rmsnorm<<<BT / 4, 256, 0, stream>>>(mo, t_buf, norm2_w, nullptr, comb_bf, BT);
    // convd + bn + silu -> d_bf (mo overlay)
    k_conv3_bf<<<dim3(BT / 128, 2), 256, 0, stream>>>(comb_bf, 256, tb_bf, 256, Wdr,
                                                      alpha_d, beta_d, nullptr, d_bf, 256, 1, 0);
    // sp conv + pixel shuffle -> out
    k_conv3_bf<<<dim3(BT / 128, 1), 256, 0, stream>>>(d_bf, 256, nullptr, 0, Wspr,
                                                      nullptr, sp_b, out, nullptr, 128, 0, 1);
}

// Round 14
// 1108.368 us; speedup vs baseline: 1.0527x; 1.0046x over previous
//
#include <hip/hip_runtime.h>
#include <hip/hip_bf16.h>
#include <math.h>

#define B_SZ 16
#define T_LR 2560
#define BT (B_SZ * T_LR)     // 40960 tokens
#define DM 256               // d_model
#define DI 512               // d_inner
#define DS 16                // d_state
#define DTR 16               // dt_rank
#define CH 64                // scan chunks per sequence
#define CH_LOG2 6
#define CLEN (T_LR / CH)     // 40 steps per chunk

typedef __attribute__((ext_vector_type(8))) short bf16x8;
typedef __attribute__((ext_vector_type(4))) float f32x4;

__device__ __forceinline__ float silu_f(float x) {
    return x / (1.f + __expf(-x));
}
__device__ __forceinline__ unsigned short f2bf(float v) {
    __hip_bfloat16 h = __float2bfloat16(v);
    return *(unsigned short*)&h;
}
__device__ __forceinline__ float bf2f(unsigned short u) {
    union { unsigned int i; float f; } c;
    c.i = (unsigned int)u << 16;
    return c.f;
}
__device__ __forceinline__ int seqrev(int r) {
    int s = r / T_LR, t = r % T_LR;
    return s * T_LR + (T_LR - 1 - t);
}
// softplus: log(1+e). abs err ~1e-7 (vs log1pf) — negligible vs bf16 rounding.
__device__ __forceinline__ float softplus_f(float x) {
    return (x > 20.f) ? x : __logf(1.f + __expf(x));
}
// fragment-major weight swizzle: tile (tap, n/16, c/32) stores 64 lanes x 16B
// contiguously; lane (q=c5>>3, ml=n&15) gets W[n][c...c+7].
__device__ __forceinline__ size_t wswz_idx(int tap, int n, int c, int N, int Kt) {
    return ((size_t)((tap * (N >> 4) + (n >> 4)) * (Kt >> 5) + (c >> 5)) << 9)
         + (size_t)((((c >> 3) & 3) * 16 + (n & 15)) * 8 + (c & 7));
}

// ---------------------------------------------------------------------------
// mega prep kernel: all weight transforms + input transpose, one dispatch.
// ---------------------------------------------------------------------------
__global__ __launch_bounds__(256) void k_prep(
    const float* __restrict__ enc_w1, const float* __restrict__ enc_w2,
    const float* __restrict__ convd_w, const float* __restrict__ sp_w,
    const float* __restrict__ convd_b, const float* __restrict__ bn_g,
    const float* __restrict__ bn_b, const float* __restrict__ bn_mean,
    const float* __restrict__ bn_var,
    const float* __restrict__ inW0, const float* __restrict__ inW1,
    const float* __restrict__ outW0, const float* __restrict__ outW1,
    const float* __restrict__ xW0, const float* __restrict__ xW1,
    const float* __restrict__ Alog0, const float* __restrict__ Alog1,
    const float* __restrict__ x,
    unsigned short* __restrict__ W1r, unsigned short* __restrict__ W2r,
    unsigned short* __restrict__ Wdr, unsigned short* __restrict__ Wspr,
    float* __restrict__ alpha, float* __restrict__ beta,
    unsigned short* __restrict__ inW_bf2, unsigned short* __restrict__ outW_bf2,
    unsigned short* __restrict__ xW_bc2, float* __restrict__ Aflag,
    unsigned short* __restrict__ xt)
{
    __shared__ float ts[32][33];
    __shared__ int s_ok;
    int blk = blockIdx.x;
    int tid = threadIdx.x;
    if (blk < 32) {                         // W1r: (128,64,3) -> swizzled [N=128,Kt=64]
        int i = blk * 256 + tid;
        int n = i / 64, ci = i % 64;
        #pragma unroll
        for (int k = 0; k < 3; k++)
            W1r[wswz_idx(k, n, ci, 128, 64)] = f2bf(enc_w1[((size_t)n * 64 + ci) * 3 + k]);
    } else if (blk < 160) {                 // W2r: (256,128,3) -> [N=256,Kt=128]
        int i = (blk - 32) * 256 + tid;
        int n = i / 128, ci = i % 128;
        #pragma unroll
        for (int k = 0; k < 3; k++)
            W2r[wswz_idx(k, n, ci, 256, 128)] = f2bf(enc_w2[((size_t)n * 128 + ci) * 3 + k]);
    } else if (blk < 672) {                 // Wdr: (256,512,3) -> [N=256,Kt=512]
        int i = (blk - 160) * 256 + tid;
        int n = i / 512, ci = i % 512;
        #pragma unroll
        for (int k = 0; k < 3; k++)
            Wdr[wswz_idx(k, n, ci, 256, 512)] = f2bf(convd_w[((size_t)n * 512 + ci) * 3 + k]);
    } else if (blk < 800) {                 // Wspr: (128,256,3) -> [N=128,Kt=256]
        int i = (blk - 672) * 256 + tid;
        int n = i / 256, ci = i % 256;
        #pragma unroll
        for (int k = 0; k < 3; k++)
            Wspr[wswz_idx(k, n, ci, 128, 256)] = f2bf(sp_w[((size_t)n * 256 + ci) * 3 + k]);
    } else if (blk < 801) {                 // bnfold
        int c = tid;
        float a = bn_g[c] * rsqrtf(bn_var[c] + 1e-5f);
        alpha[c] = a;
        beta[c] = (convd_b[c] - bn_mean[c]) * a + bn_b[c];
    } else if (blk < 1825) {                // inW cast, both dirs (262144 each)
        int i = (blk - 801) * 256 + tid;
        inW_bf2[i] = f2bf(inW0[i]);
        inW_bf2[262144 + i] = f2bf(inW1[i]);
    } else if (blk < 2337) {                // outW cast (131072 each)
        int i = (blk - 1825) * 256 + tid;
        outW_bf2[i] = f2bf(outW0[i]);
        outW_bf2[131072 + i] = f2bf(outW1[i]);
    } else if (blk < 2433) {                // xW[0:48] cast (24576 each dir)
        int i = (blk - 2337) * 256 + tid;
        xW_bc2[i] = f2bf(xW0[i]);
        xW_bc2[24576 + i] = f2bf(xW1[i]);
    } else if (blk < 2434) {                // Alog structure check: A[d][n] == A[d][0]*(n+1)?
        if (tid == 0) s_ok = 1;
        __syncthreads();
        int ok = 1;
        for (int i = tid; i < DI * DS; i += 256) {
            int d = i >> 4, n = i & 15;
            float a0f = __expf(Alog0[d * DS]);
            float anf = __expf(Alog0[d * DS + n]);
            if (fabsf(anf - (float)(n + 1) * a0f) > 1e-3f * (float)(n + 1)) ok = 0;
            float a0b = __expf(Alog1[d * DS]);
            float anb = __expf(Alog1[d * DS + n]);
            if (fabsf(anb - (float)(n + 1) * a0b) > 1e-3f * (float)(n + 1)) ok = 0;
        }
        if (!ok) atomicAnd(&s_ok, 0);
        __syncthreads();
        if (tid == 0) Aflag[0] = s_ok ? 1.f : 0.f;
    } else {                                // transpose x (b,64,T) f32 -> xt (b,T,64) bf16
        int idx = blk - 2434;               // b(16) x c0(2) x t0(80)
        int t0 = (idx % 80) * 32;
        int c0 = ((idx / 80) & 1) * 32;
        int b = idx / 160;
        int tx = tid & 31, ty = tid >> 5;
        #pragma unroll
        for (int j = 0; j < 4; j++) {
            int c = c0 + ty + j * 8;
            ts[ty + j * 8][tx] = x[((size_t)b * 64 + c) * T_LR + t0 + tx];
        }
        __syncthreads();
        #pragma unroll
        for (int j = 0; j < 4; j++) {
            int t = t0 + ty + j * 8;
            xt[((size_t)b * T_LR + t) * 64 + c0 + tx] = f2bf(ts[tx][ty + j * 8]);
        }
    }
}

// ---------------------------------------------------------------------------
// implicit-GEMM k=3 "same" conv via MFMA, templated M-tile.
// TM=128 (convd/enc2: B-reuse-heavy) or TM=64 (enc1/sp: grid-starved at 320
// blocks; doubling block count costs only small L2 B-traffic since panels
// are <=192KB). As double-buffered, one barrier per k-step; fragment-major
// swizzled B (contiguous 1KB bursts); LDS-transposed coalesced epilogue.
// ---------------------------------------------------------------------------
template<int TM>
__global__ __launch_bounds__(256, 3) void k_conv3_bf(const unsigned short* __restrict__ A1, int K1,
                                                  const unsigned short* __restrict__ A2, int K2,
                                                  const unsigned short* __restrict__ Wz,
                                                  const float* __restrict__ alpha,
                                                  const float* __restrict__ beta,
                                                  float* __restrict__ outf,
                                                  unsigned short* __restrict__ outb,
                                                  int N, int dosilu, int pixsh) {
    constexpr int MI = TM / 32;                  // acc tiles per wave-pair (4 or 2)
    constexpr int NITEM = (TM + 2) * 4;          // staging items (520 or 264)
    constexpr int NIT = (NITEM + 255) / 256;     // unrolled staging slots (3 or 2)
    constexpr int SMEMB = (2 * (TM + 2) * 80 > 17920) ? 2 * (TM + 2) * 80 : 17920;
    int Kt = K1 + K2;
    __shared__ __align__(16) unsigned short smem[SMEMB / 2];
    unsigned short (*As)[TM + 2][40] = (unsigned short (*)[TM + 2][40])smem;
    float* sC = (float*)smem;                    // 32 x 140 f32 epilogue overlay
    int tid = threadIdx.x;
    int wave = tid >> 6, lane = tid & 63;
    int wm = (wave >> 1) * (TM / 2), wn = (wave & 1) * 64;
    int m0 = blockIdx.x * TM, n0 = blockIdx.y * 128;
    int b = m0 / T_LR, t0 = m0 % T_LR;
    int q = lane >> 4, ml = lane & 15;
    int Nb16 = N >> 4, Kb32 = Kt >> 5;
    int nb0 = (n0 + wn) >> 4;
    const unsigned short* wl = Wz + (size_t)lane * 8;
    f32x4 acc[MI][4] = {};
    int cq = tid & 3;
    int rr[NIT]; int ta[NIT]; bool va[NIT]; bool st[NIT];
    #pragma unroll
    for (int it = 0; it < NIT; it++) {
        int i = tid + it * 256;
        rr[it] = i >> 2;
        ta[it] = t0 - 1 + rr[it];
        st[it] = (i < NITEM);
        va[it] = st[it] && (ta[it] >= 0) && (ta[it] < T_LR);
    }
    uint4 v[NIT];
    #define LOADA(vv, valid, t, col) { vv = make_uint4(0u,0u,0u,0u); if (valid) { \
        const unsigned short* src = ((col) < K1) \
            ? A1 + (size_t)(b * T_LR + (t)) * K1 + (col) \
            : A2 + (size_t)(b * T_LR + (t)) * K2 + ((col) - K1); \
        vv = *(const uint4*)src; } }
    #pragma unroll
    for (int it = 0; it < NIT; it++) LOADA(v[it], va[it], ta[it], cq * 8);
    #pragma unroll
    for (int it = 0; it < NIT; it++)
        if (st[it]) *(uint4*)&As[0][rr[it]][cq * 8] = v[it];
    int nk = Kb32;
    for (int kk = 0; kk < nk; kk++) {
        __syncthreads();
        int cur = kk & 1;
        if (kk + 1 < nk) {
            int col = ((kk + 1) << 5) + cq * 8;
            #pragma unroll
            for (int it = 0; it < NIT; it++) LOADA(v[it], va[it], ta[it], col);
        }
        #pragma unroll
        for (int tap = 0; tap < 3; tap++) {
            int tb = tap * Nb16 + nb0;
            bf16x8 bfr[4];
            #pragma unroll
            for (int ni = 0; ni < 4; ni++)
                bfr[ni] = *(const bf16x8*)(wl + ((size_t)((tb + ni) * Kb32 + kk) << 9));
            #pragma unroll
            for (int mi = 0; mi < MI; mi++) {
                bf16x8 af = *(const bf16x8*)&As[cur][wm + mi * 16 + ml + tap][q * 8];
                #pragma unroll
                for (int ni = 0; ni < 4; ni++)
                    acc[mi][ni] = __builtin_amdgcn_mfma_f32_16x16x32_bf16(af, bfr[ni], acc[mi][ni], 0, 0, 0);
            }
        }
        if (kk + 1 < nk) {
            #pragma unroll
            for (int it = 0; it < NIT; it++)
                if (st[it]) *(uint4*)&As[cur ^ 1][rr[it]][cq * 8] = v[it];
        }
    }
    #undef LOADA
    // epilogue: TM/32 passes of 32 rows through LDS, coalesced stores.
    int rowoff = m0 - b * T_LR;   // local t of row 0
    #pragma unroll
    for (int p = 0; p < TM / 32; p++) {
        __syncthreads();
        int h = (p * 64) / TM;                      // writer wave-pair
        if ((wave >> 1) == h) {
            int mib = (p * 32 - h * (TM / 2)) / 16;
            #pragma unroll
            for (int m2 = 0; m2 < 2; m2++) {
                int mi = mib + m2;
                int rl = m2 * 16 + q * 4;
                #pragma unroll
                for (int r = 0; r < 4; r++)
                    #pragma unroll
                    for (int ni = 0; ni < 4; ni++)
                        sC[(rl + r) * 140 + wn + ni * 16 + ml] = acc[mi][ni][r];
            }
        }
        __syncthreads();
        if (pixsh) {
            // N=128, n0=0: col=2*c2+rr -> out[((b*64+c2)*T + t)*2 + rr]
            int row = tid & 31, c2g = tid >> 5;
            int t = rowoff + p * 32 + row;
            float* dst = outf + ((size_t)b * 64 * T_LR + t) * 2;
            #pragma unroll
            for (int j = 0; j < 8; j++) {
                int c2 = c2g + j * 8;
                float va2 = sC[row * 140 + 2 * c2]     + beta[2 * c2];
                float vb2 = sC[row * 140 + 2 * c2 + 1] + beta[2 * c2 + 1];
                *(float2*)&dst[(size_t)c2 * T_LR * 2] = make_float2(va2, vb2);
            }
        } else {
            #pragma unroll
            for (int gi = 0; gi < 2; gi++) {
                int g = tid + gi * 256;
                int row = g >> 4;
                int colg = (g & 15) * 8;
                int mr = m0 + p * 32 + row;
                const float* src = sC + row * 140 + colg;
                float vv[8];
                *(float4*)&vv[0] = *(const float4*)src;
                *(float4*)&vv[4] = *(const float4*)(src + 4);
                unsigned short ob[8];
                #pragma unroll
                for (int jj = 0; jj < 8; jj++) {
                    int col = n0 + colg + jj;
                    float a = alpha ? alpha[col] : 1.f;
                    float vx = vv[jj] * a + beta[col];
                    if (dosilu) vx = silu_f(vx);
                    vv[jj] = vx;
                    ob[jj] = f2bf(vx);
                }
                if (outf) {
                    *(float4*)(outf + (size_t)mr * N + n0 + colg) = *(float4*)&vv[0];
                    *(float4*)(outf + (size_t)mr * N + n0 + colg + 4) = *(float4*)&vv[4];
                }
                if (outb)
                    *(uint4*)(outb + (size_t)mr * N + n0 + colg) = *(uint4*)ob;
            }
        }
    }
}

// ---------------------------------------------------------------------------
// fused in_proj (FULL 1024 cols) + causal dwconv + silu.
// BOTH directions in one dispatch: dir = blockIdx.z.
// n0 <  512: xc half -> dwconv k=4 + silu -> xcs bf16.
// n0 >= 512: z  half -> raw bf16 z -> zb (gate applied later in scan p3).
// ---------------------------------------------------------------------------
__global__ __launch_bounds__(256) void k_inproj_conv(const unsigned short* __restrict__ xn,
                                                     const unsigned short* __restrict__ inW2,
                                                     const float* __restrict__ cw0,
                                                     const float* __restrict__ cw1,
                                                     const float* __restrict__ cb0,
                                                     const float* __restrict__ cb1,
                                                     unsigned short* __restrict__ xcs,
                                                     unsigned short* __restrict__ zb,
                                                     long long dsXcs) {
    __shared__ unsigned short As[128][40];
    __shared__ unsigned short Bs[128][40];
    __shared__ unsigned short Ct[131][136];   // rows: internal t0-3 .. t0+127
    int dir = blockIdx.z;
    int arev = dir;
    const unsigned short* inW = inW2 + (size_t)dir * 1024 * DM;
    xcs += (size_t)dir * dsXcs;
    zb  += (size_t)dir * dsXcs;
    int tid = threadIdx.x;
    int wave = tid >> 6, lane = tid & 63;
    int wm = (wave >> 1) * 64, wn = (wave & 1) * 64;
    int m0 = blockIdx.x * 128, n0 = blockIdx.y * 128;   // n0 in [0,1024)
    int b = m0 / T_LR, t0 = m0 % T_LR;
    int sc = tid & 3, sr = tid >> 2;
    int ar0 = m0 + sr, ar1 = m0 + sr + 64;
    if (arev) { ar0 = seqrev(ar0); ar1 = seqrev(ar1); }
    const unsigned short* ap0 = xn + (size_t)ar0 * DM + sc * 8;
    const unsigned short* ap1 = xn + (size_t)ar1 * DM + sc * 8;
    const unsigned short* bp0 = inW + (size_t)(n0 + sr) * DM + sc * 8;
    const unsigned short* bp1 = inW + (size_t)(n0 + sr + 64) * DM + sc * 8;
    f32x4 acc[4][4] = {};
    int q = lane >> 4, ml = lane & 15;
    for (int k0 = 0; k0 < DM; k0 += 32) {
        uint4 a0 = *(const uint4*)(ap0 + k0);
        uint4 a1 = *(const uint4*)(ap1 + k0);
        uint4 b0 = *(const uint4*)(bp0 + k0);
        uint4 b1 = *(const uint4*)(bp1 + k0);
        __syncthreads();
        *(uint4*)&As[sr][sc * 8]      = a0;
        *(uint4*)&As[sr + 64][sc * 8] = a1;
        *(uint4*)&Bs[sr][sc * 8]      = b0;
        *(uint4*)&Bs[sr + 64][sc * 8] = b1;
        __syncthreads();
        bf16x8 af[4], bfr[4];
        #pragma unroll
        for (int mi = 0; mi < 4; mi++)
            af[mi] = *(const bf16x8*)&As[wm + mi * 16 + ml][q * 8];
        #pragma unroll
        for (int ni = 0; ni < 4; ni++)
            bfr[ni] = *(const bf16x8*)&Bs[wn + ni * 16 + ml][q * 8];
        #pragma unroll
        for (int mi = 0; mi < 4; mi++)
            #pragma unroll
            for (int ni = 0; ni < 4; ni++)
                acc[mi][ni] = __builtin_amdgcn_mfma_f32_16x16x32_bf16(af[mi], bfr[ni], acc[mi][ni], 0, 0, 0);
    }
    if (n0 < DI) {
        const float* cw = dir ? cw1 : cw0;
        const float* cb = dir ? cb1 : cb0;
        // main tile -> Ct rows 3..130
        #pragma unroll
        for (int mi = 0; mi < 4; mi++)
            #pragma unroll
            for (int r = 0; r < 4; r++)
                #pragma unroll
                for (int ni = 0; ni < 4; ni++)
                    Ct[3 + wm + mi * 16 + q * 4 + r][wn + ni * 16 + ml] = f2bf(acc[mi][ni][r]);
        // halo rows 0..2 via direct dot — 384 items on 256 threads
        for (int i = tid; i < 384; i += 256) {
            int hr = i >> 7, c = i & 127;
            int tr = t0 - 3 + hr;
            float v = 0.f;
            if (tr >= 0) {
                int src = b * T_LR + (arev ? (T_LR - 1 - tr) : tr);
                const unsigned short* xr = xn + (size_t)src * DM;
                const unsigned short* wr = inW + (size_t)(n0 + c) * DM;
                for (int k = 0; k < DM; k += 8) {
                    uint4 xa = *(const uint4*)(xr + k);
                    uint4 wa = *(const uint4*)(wr + k);
                    const unsigned short* xs = (const unsigned short*)&xa;
                    const unsigned short* wsp = (const unsigned short*)&wa;
                    #pragma unroll
                    for (int j = 0; j < 8; j++) v += bf2f(xs[j]) * bf2f(wsp[j]);
                }
            }
            Ct[hr][c] = f2bf(v);
        }
        __syncthreads();
        // causal conv k=4 + silu, write xcs bf16
        int col = tid & 127;
        int d = n0 + col;
        float w0 = cw[d * 4 + 0], w1 = cw[d * 4 + 1], w2 = cw[d * 4 + 2], w3 = cw[d * 4 + 3];
        float bi = cb[d];
        int rbase = tid >> 7;
        for (int j = 0; j < 64; j++) {
            int row = rbase + 2 * j;
            float v = bi + bf2f(Ct[row][col]) * w0 + bf2f(Ct[row + 1][col]) * w1
                         + bf2f(Ct[row + 2][col]) * w2 + bf2f(Ct[row + 3][col]) * w3;
            xcs[(size_t)(m0 + row) * DI + d] = f2bf(silu_f(v));
        }
    } else {
        // z half: raw bf16 store via Ct staging, coalesced uint4 writes
        #pragma unroll
        for (int mi = 0; mi < 4; mi++)
            #pragma unroll
            for (int r = 0; r < 4; r++)
                #pragma unroll
                for (int ni = 0; ni < 4; ni++)
                    Ct[wm + mi * 16 + q * 4 + r][wn + ni * 16 + ml] = f2bf(acc[mi][ni][r]);
        __syncthreads();
        int zc0 = n0 - DI;
        #pragma unroll
        for (int gi = 0; gi < 2; gi++) {
            int g = tid + gi * 256;
            int row = g >> 2;              // 0..127
            int colg = (g & 3) * 32;       // 0,32,64,96
            unsigned short* dst = zb + (size_t)(m0 + row) * DI + zc0 + colg;
            const unsigned short* srcc = &Ct[row][colg];
            *(uint4*)(dst)      = *(const uint4*)(srcc);
            *(uint4*)(dst + 8)  = *(const uint4*)(srcc + 8);
            *(uint4*)(dst + 16) = *(const uint4*)(srcc + 16);
            *(uint4*)(dst + 24) = *(const uint4*)(srcc + 24);
        }
    }
}

// ---------------------------------------------------------------------------
// rmsnorm over last dim (256). One wave per token. Optional second input
// summed in (mo + mo1). fp32 and/or bf16 out.
// ---------------------------------------------------------------------------
__global__ __launch_bounds__(256) void k_rmsnorm(const float* __restrict__ in1,
                                                 const float* __restrict__ in2,
                                                 const float* __restrict__ w,
                                                 float* __restrict__ out,
                                                 unsigned short* __restrict__ out_bf,
                                                 int ntok) {
    int tok = (blockIdx.x * 256 + threadIdx.x) >> 6;
    int lane = threadIdx.x & 63;
    if (tok >= ntok) return;
    float4 v = ((const float4*)(in1 + (size_t)tok * DM))[lane];
    if (in2) {
        float4 u = ((const float4*)(in2 + (size_t)tok * DM))[lane];
        v.x += u.x; v.y += u.y; v.z += u.z; v.w += u.w;
    }
    float ss = v.x * v.x + v.y * v.y + v.z * v.z + v.w * v.w;
    #pragma unroll
    for (int off = 32; off > 0; off >>= 1) ss += __shfl_xor(ss, off);
    float sc = rsqrtf(ss * (1.f / 256.f) + 1e-6f);
    float4 wv = ((const float4*)w)[lane];
    float4 o;
    o.x = v.x * sc * wv.x; o.y = v.y * sc * wv.y;
    o.z = v.z * sc * wv.z; o.w = v.w * sc * wv.w;
    if (out) ((float4*)(out + (size_t)tok * DM))[lane] = o;
    if (out_bf) {
        ushort4 ob;
        ob.x = f2bf(o.x); ob.y = f2bf(o.y); ob.z = f2bf(o.z); ob.w = f2bf(o.w);
        ((ushort4*)(out_bf + (size_t)tok * DM))[lane] = ob;
    }
}

// ---------------------------------------------------------------------------
// bf16 MFMA GEMM, fp32 out + optional residual (db and out_proj).
// BOTH directions per dispatch: dir = blockIdx.z applies element strides.
// crevmode: 0 = never reverse output rows, 2 = reverse iff dir==1.
// ---------------------------------------------------------------------------
__global__ __launch_bounds__(256) void k_gemm_bf(const unsigned short* __restrict__ A, int lda, long long dsA,
                                                 const unsigned short* __restrict__ Bw, long long dsB,
                                                 float* Cf, long long dsCf, int ldc,
                                                 const float* __restrict__ res,
                                                 int K, int Nout, int crevmode) {
    __shared__ unsigned short As[128][40];
    __shared__ unsigned short Bs[128][40];
    int dir = blockIdx.z;
    A += (long long)dir * dsA;
    Bw += (long long)dir * dsB;
    Cf += (long long)dir * dsCf;
    int crev = (crevmode == 2) ? dir : crevmode;
    int tid = threadIdx.x;
    int wave = tid >> 6, lane = tid & 63;
    int wm = (wave >> 1) * 64, wn = (wave & 1) * 64;
    int m0 = blockIdx.x * 128, n0 = blockIdx.y * 128;
    int sc = tid & 3, sr = tid >> 2;
    const unsigned short* ap0 = A + (size_t)(m0 + sr) * lda + sc * 8;
    const unsigned short* ap1 = A + (size_t)(m0 + sr + 64) * lda + sc * 8;
    bool bv0 = (n0 + sr) < Nout;
    bool bv1 = (n0 + sr + 64) < Nout;
    const unsigned short* bp0 = Bw + (size_t)(n0 + sr) * K + sc * 8;
    const unsigned short* bp1 = Bw + (size_t)(n0 + sr + 64) * K + sc * 8;
    f32x4 acc[4][4] = {};
    int q = lane >> 4, ml = lane & 15;
    for (int k0 = 0; k0 < K; k0 += 32) {
        uint4 a0 = *(const uint4*)(ap0 + k0);
        uint4 a1 = *(const uint4*)(ap1 + k0);
        uint4 b0 = make_uint4(0u, 0u, 0u, 0u), b1 = make_uint4(0u, 0u, 0u, 0u);
        if (bv0) b0 = *(const uint4*)(bp0 + k0);
        if (bv1) b1 = *(const uint4*)(bp1 + k0);
        __syncthreads();
        *(uint4*)&As[sr][sc * 8]      = a0;
        *(uint4*)&As[sr + 64][sc * 8] = a1;
        *(uint4*)&Bs[sr][sc * 8]      = b0;
        *(uint4*)&Bs[sr + 64][sc * 8] = b1;
        __syncthreads();
        bf16x8 af[4], bfr[4];
        #pragma unroll
        for (int mi = 0; mi < 4; mi++)
            af[mi] = *(const bf16x8*)&As[wm + mi * 16 + ml][q * 8];
        #pragma unroll
        for (int ni = 0; ni < 4; ni++)
            bfr[ni] = *(const bf16x8*)&Bs[wn + ni * 16 + ml][q * 8];
        #pragma unroll
        for (int mi = 0; mi < 4; mi++)
            #pragma unroll
            for (int ni = 0; ni < 4; ni++)
                acc[mi][ni] = __builtin_amdgcn_mfma_f32_16x16x32_bf16(af[mi], bfr[ni], acc[mi][ni], 0, 0, 0);
    }
    #pragma unroll
    for (int mi = 0; mi < 4; mi++) {
        #pragma unroll
        for (int r = 0; r < 4; r++) {
            int mr = m0 + wm + mi * 16 + q * 4 + r;
            int orow = crev ? seqrev(mr) : mr;
            #pragma unroll
            for (int ni = 0; ni < 4; ni++) {
                int col = n0 + wn + ni * 16 + ml;
                if (col < Nout) {
                    float v = acc[mi][ni][r];
                    if (res) v += res[(size_t)orow * ldc + col];
                    Cf[(size_t)orow * ldc + col] = v;
                }
            }
        }
    }
}

// ---------------------------------------------------------------------------
// scan phase 1: per (dir*bl, chunk, d) thread. Both dirs in one dispatch:
// buffers laid [2*Bc][...]; dir = (bl >= Bc) selects the weight set.
// dt computed in-line (low-rank); fast path when Aflag set.
// ---------------------------------------------------------------------------
__global__ __launch_bounds__(256) void k_scan_p1(const unsigned short* __restrict__ x,
                                                 const float* __restrict__ db,
                                                 const float* __restrict__ dtW0, const float* __restrict__ dtW1,
                                                 const float* __restrict__ dtb0, const float* __restrict__ dtb1,
                                                 const float* __restrict__ Alog0, const float* __restrict__ Alog1,
                                                 const float* __restrict__ Aflag,
                                                 float* __restrict__ hS,
                                                 float* __restrict__ csum, int Bc) {
    __shared__ float dbs[CLEN * 48];
    int tid = threadIdx.x;
    int gid = blockIdx.x * 256 + tid;   // ((dir*Bc+bl)*CH + c)*DI + d
    int d = gid & (DI - 1);
    int bcix = gid >> 9;
    int c = bcix & (CH - 1);
    int bl = bcix >> CH_LOG2;           // [0, 2*Bc)
    int dir = (bl >= Bc) ? 1 : 0;
    const float* dtW  = dir ? dtW1  : dtW0;
    const float* dtb  = dir ? dtb1  : dtb0;
    const float* Alog = dir ? Alog1 : Alog0;
    int tbase = c * CLEN;
    const float* dbp = db + ((size_t)bl * T_LR + tbase) * 48;
    for (int i = tid; i < (CLEN * 48) / 4; i += 256)
        *(float4*)&dbs[i * 4] = *(const float4*)(dbp + i * 4);
    bool fast = (Aflag[0] != 0.f);
    float A0 = -__expf(Alog[d * DS]);
    float Av[DS], h[DS];
    #pragma unroll
    for (int n = 0; n < DS; n++) h[n] = 0.f;
    if (!fast) {
        #pragma unroll
        for (int n = 0; n < DS; n++) Av[n] = -__expf(Alog[d * DS + n]);
    }
    const float4* wp = (const float4*)(dtW + d * 16);
    float4 w0 = wp[0], w1 = wp[1], w2 = wp[2], w3 = wp[3];
    float bias = dtb[d];
    const unsigned short* xp = x + ((size_t)bl * T_LR + tbase) * DI + d;
    float S = 0.f;
    __syncthreads();
    for (int t = 0; t < CLEN; t++) {
        const float* bc = dbs + t * 48;
        float dl = bias
            + bc[0] * w0.x + bc[1] * w0.y + bc[2] * w0.z + bc[3] * w0.w
            + bc[4] * w1.x + bc[5] * w1.y + bc[6] * w1.z + bc[7] * w1.w
            + bc[8] * w2.x + bc[9] * w2.y + bc[10] * w2.z + bc[11] * w2.w
            + bc[12] * w3.x + bc[13] * w3.y + bc[14] * w3.z + bc[15] * w3.w;
        float dtv = softplus_f(dl);
        float xv  = bf2f(xp[(size_t)t * DI]);
        float dtx = dtv * xv;
        S += dtv;
        if (fast) {
            float e1 = __expf(dtv * A0);
            float e = e1;
            #pragma unroll
            for (int n = 0; n < DS; n++) {
                h[n] = e * h[n] + dtx * bc[16 + n];
                e *= e1;
            }
        } else {
            #pragma unroll
            for (int n = 0; n < DS; n++)
                h[n] = __expf(dtv * Av[n]) * h[n] + dtx * bc[16 + n];
        }
    }
    float* hp = hS + (size_t)gid * DS;
    #pragma unroll
    for (int n = 0; n < DS; n++) hp[n] = h[n];
    csum[gid] = S;
}

// ---------------------------------------------------------------------------
// scan phase 2: per (dir*bl, d, n) thread; sequential over CH chunks.
// ---------------------------------------------------------------------------
__global__ __launch_bounds__(256) void k_scan_p2(float* __restrict__ hS,
                                                 const float* __restrict__ csum,
                                                 const float* __restrict__ Alog0,
                                                 const float* __restrict__ Alog1, int Bc) {
    int gid = blockIdx.x * 256 + threadIdx.x;   // ((dir*Bc+bl)*DI + d)*DS + n
    int n = gid & (DS - 1);
    int d = (gid >> 4) & (DI - 1);
    int bl = gid >> 13;                         // [0, 2*Bc)
    const float* Alog = (bl >= Bc) ? Alog1 : Alog0;
    float An = -__expf(Alog[d * DS + n]);
    float hs = 0.f;
    for (int c = 0; c < CH; c++) {
        size_t base = ((size_t)(bl * CH + c) * DI + d);
        float he = hS[base * DS + n];
        float S  = csum[base];
        hS[base * DS + n] = hs;
        hs = __expf(An * S) * hs + he;
    }
}

// ---------------------------------------------------------------------------
// scan phase 3: corrected chunk-start state; fused z-gate:
// yg = silu(z) * (y + x*D) written bf16 in place over x.
// ---------------------------------------------------------------------------
__global__ __launch_bounds__(256) void k_scan_p3(unsigned short* __restrict__ x,
                                                 const unsigned short* __restrict__ zb,
                                                 const float* __restrict__ db,
                                                 const float* __restrict__ dtW0, const float* __restrict__ dtW1,
                                                 const float* __restrict__ dtb0, const float* __restrict__ dtb1,
                                                 const float* __restrict__ Alog0, const float* __restrict__ Alog1,
                                                 const float* __restrict__ Aflag,
                                                 const float* __restrict__ Dp0, const float* __restrict__ Dp1,
                                                 const float* __restrict__ hS, int Bc) {
    __shared__ float dbs[CLEN * 48];
    int tid = threadIdx.x;
    int gid = blockIdx.x * 256 + tid;
    int d = gid & (DI - 1);
    int bcix = gid >> 9;
    int c = bcix & (CH - 1);
    int bl = bcix >> CH_LOG2;
    int dir = (bl >= Bc) ? 1 : 0;
    const float* dtW  = dir ? dtW1  : dtW0;
    const float* dtb  = dir ? dtb1  : dtb0;
    const float* Alog = dir ? Alog1 : Alog0;
    const float* Dp   = dir ? Dp1   : Dp0;
    int tbase = c * CLEN;
    const float* dbp = db + ((size_t)bl * T_LR + tbase) * 48;
    for (int i = tid; i < (CLEN * 48) / 4; i += 256)
        *(float4*)&dbs[i * 4] = *(const float4*)(dbp + i * 4);
    bool fast = (Aflag[0] != 0.f);
    float A0 = -__expf(Alog[d * DS]);
    float Av[DS], h[DS];
    const float* hp = hS + (size_t)gid * DS;
    #pragma unroll
    for (int n = 0; n < DS; n++) h[n] = hp[n];
    if (!fast) {
        #pragma unroll
        for (int n = 0; n < DS; n++) Av[n] = -__expf(Alog[d * DS + n]);
    }
    const float4* wp = (const float4*)(dtW + d * 16);
    float4 w0 = wp[0], w1 = wp[1], w2 = wp[2], w3 = wp[3];
    float bias = dtb[d];
    float Dd = Dp[d];
    unsigned short* xp = x + ((size_t)bl * T_LR + tbase) * DI + d;
    const unsigned short* zp = zb + ((size_t)bl * T_LR + tbase) * DI + d;
    __syncthreads();
    for (int t = 0; t < CLEN; t++) {
        const float* bc = dbs + t * 48;
        float dl = bias
            + bc[0] * w0.x + bc[1] * w0.y + bc[2] * w0.z + bc[3] * w0.w
            + bc[4] * w1.x + bc[5] * w1.y + bc[6] * w1.z + bc[7] * w1.w
            + bc[8] * w2.x + bc[9] * w2.y + bc[10] * w2.z + bc[11] * w2.w
            + bc[12] * w3.x + bc[13] * w3.y + bc[14] * w3.z + bc[15] * w3.w;
        float dtv = softplus_f(dl);
        float xv  = bf2f(xp[(size_t)t * DI]);
        float dtx = dtv * xv;
        float acc = 0.f;
        if (fast) {
            float e1 = __expf(dtv * A0);
            float e = e1;
            #pragma unroll
            for (int n = 0; n < DS; n++) {
                h[n] = e * h[n] + dtx * bc[16 + n];
                acc += h[n] * bc[32 + n];
                e *= e1;
            }
        } else {
            #pragma unroll
            for (int n = 0; n < DS; n++) {
                h[n] = __expf(dtv * Av[n]) * h[n] + dtx * bc[16 + n];
                acc += h[n] * bc[32 + n];
            }
        }
        float yv = acc + xv * Dd;
        float zv = bf2f(zp[(size_t)t * DI]);
        xp[(size_t)t * DI] = f2bf(silu_f(zv) * yv);
    }
}

// ---------------------------------------------------------------------------
extern "C" void kernel_launch(void* const* d_in, const int* in_sizes, int n_in,
                              void* d_out, int out_size, void* d_ws, size_t ws_size,
                              hipStream_t stream) {
    const float* x       = (const float*)d_in[0];
    const float* enc_w1  = (const float*)d_in[1];
    const float* enc_b1  = (const float*)d_in[2];
    const float* enc_w2  = (const float*)d_in[3];
    const float* enc_b2  = (const float*)d_in[4];
    const float* norm1_w = (const float*)d_in[5];
    const float* norm2_w = (const float*)d_in[6];
    const float* convd_w = (const float*)d_in[25];
    const float* convd_b = (const float*)d_in[26];
    const float* bn_g    = (const float*)d_in[27];
    const float* bn_b    = (const float*)d_in[28];
    const float* bn_mean = (const float*)d_in[29];
    const float* bn_var  = (const float*)d_in[30];
    const float* sp_w    = (const float*)d_in[31];
    const float* sp_b    = (const float*)d_in[32];
    float* out = (float*)d_out;

    const float* inW0   = (const float*)d_in[7];
    const float* cw0    = (const float*)d_in[8];
    const float* cb0    = (const float*)d_in[9];
    const float* xW0    = (const float*)d_in[10];
    const float* dtW0   = (const float*)d_in[11];
    const float* dtb0   = (const float*)d_in[12];
    const float* Alog0  = (const float*)d_in[13];
    const float* Dp0    = (const float*)d_in[14];
    const float* outW0  = (const float*)d_in[15];
    const float* inW1   = (const float*)d_in[16];
    const float* cw1    = (const float*)d_in[17];
    const float* cb1    = (const float*)d_in[18];
    const float* xW1    = (const float*)d_in[19];
    const float* dtW1   = (const float*)d_in[20];
    const float* dtb1   = (const float*)d_in[21];
    const float* Alog1  = (const float*)d_in[22];
    const float* Dp1    = (const float*)d_in[23];
    const float* outW1  = (const float*)d_in[24];

    // ---- workspace layout (float slots) ----
    float* ws = (float*)d_ws;
    size_t availf = ws_size / sizeof(float);
    size_t o = 0;
    float* t_buf  = ws + o; o += (size_t)BT * DM;       // enc f32; later mo1
    float* xn_buf = ws + o; o += (size_t)BT * DM;       // later: comb_bf overlay
    float* mo     = ws + o; o += (size_t)BT * DM;       // early: xt/e1t; late: d_bf overlay
    unsigned short* xn_bf = (unsigned short*)(ws + o); o += (size_t)BT * DM / 2;
    unsigned short* tb_bf = (unsigned short*)(ws + o); o += (size_t)BT * DM / 2;
    unsigned short* inW_bf2  = (unsigned short*)(ws + o); o += (size_t)1024 * DM;   // 2 dirs
    unsigned short* outW_bf2 = (unsigned short*)(ws + o); o += (size_t)DM * DI;     // 2 dirs
    unsigned short* xW_bc2   = (unsigned short*)(ws + o); o += (size_t)48 * DI;     // 2 dirs x 48x512
    unsigned short* W1r  = (unsigned short*)(ws + o); o += (3 * 128 * 64) / 2;
    unsigned short* W2r  = (unsigned short*)(ws + o); o += (3 * 256 * 128) / 2;
    unsigned short* Wdr  = (unsigned short*)(ws + o); o += (3 * 256 * 512) / 2;
    unsigned short* Wspr = (unsigned short*)(ws + o); o += (3 * 128 * 256) / 2;
    float* alpha_d = ws + o; o += 256;
    float* beta_d  = ws + o; o += 256;
    float* Aflag_d = ws + o; o += 4;
    size_t persist = o;
    float* scratch = ws + persist;
    size_t scratch_avail = (availf > persist) ? (availf - persist) : 0;
    // per-batch scratch for BOTH dirs (float slots): xcs bf16 + zb bf16 +
    // db f32(48) + hS + csum
    size_t per_b2 = 2 * ((size_t)T_LR * DI / 2 * 2 + (size_t)T_LR * 48
                         + (size_t)CH * DI * (DS + 1));
    int Bc = 16;
    while (Bc > 1 && (size_t)Bc * per_b2 > scratch_avail) Bc >>= 1;

    // encoder temporaries overlay mo (dead until out_proj)
    unsigned short* xt  = (unsigned short*)mo;                         // (b,T,64) bf16
    unsigned short* e1t = (unsigned short*)(mo + (size_t)BT * 64 / 2); // (b,T,128) bf16
    unsigned short* comb_bf = (unsigned short*)xn_buf;   // overlay after xn dead
    unsigned short* d_bf = (unsigned short*)mo;          // overlay after mo dead

    // single mega prep dispatch
    k_prep<<<4994, 256, 0, stream>>>(enc_w1, enc_w2, convd_w, sp_w,
                                     convd_b, bn_g, bn_b, bn_mean, bn_var,
                                     inW0, inW1, outW0, outW1, xW0, xW1,
                                     Alog0, Alog1,
                                     x, W1r, W2r, Wdr, Wspr, alpha_d, beta_d,
                                     inW_bf2, outW_bf2, xW_bc2, Aflag_d, xt);

    // encoder: enc1 at TM=64 (grid-starved at 320 blocks), enc2 at TM=128
    k_conv3_bf<64><<<dim3(BT / 64, 1), 256, 0, stream>>>(xt, 64, nullptr, 0, W1r,
                                                      nullptr, enc_b1, nullptr, e1t, 128, 1, 0);
    k_conv3_bf<128><<<dim3(BT / 128, 2), 256, 0, stream>>>(e1t, 128, nullptr, 0, W2r,
                                                      nullptr, enc_b2, t_buf, tb_bf, 256, 1, 0);
    k_rmsnorm<<<BT / 4, 256, 0, stream>>>(t_buf, nullptr, norm1_w, xn_buf, xn_bf, BT);

    // mamba: both directions per dispatch (dir = blockIdx.z / doubled bl).
    long long dsMo1 = (long long)(t_buf - mo);
    for (int b0 = 0; b0 < B_SZ; b0 += Bc) {
        int Tc = Bc * T_LR;
        long long TcDI = (long long)Tc * DI;
        unsigned short* xcs = (unsigned short*)scratch;              // [2][Tc][DI] bf16, later yg
        unsigned short* zb  = xcs + (size_t)2 * Tc * DI;             // [2][Tc][DI] bf16 raw z
        float* db   = (float*)(zb + (size_t)2 * Tc * DI);            // [2][Tc][48]
        float* hS   = db + (size_t)2 * Tc * 48;                      // [2Bc][CH][DI][DS]
        float* csum = hS + (size_t)2 * Bc * CH * DI * DS;            // [2Bc][CH][DI]
        const float*          xnC  = xn_buf + (size_t)b0 * T_LR * DM;
        const unsigned short* xnbC = xn_bf  + (size_t)b0 * T_LR * DM;
        float*                moC  = mo     + (size_t)b0 * T_LR * DM;
        // fused in_proj (xc + z halves) + causal dwconv + silu (both dirs)
        k_inproj_conv<<<dim3(Tc / 128, 1024 / 128, 2), 256, 0, stream>>>(
            xnbC, inW_bf2, cw0, cw1, cb0, cb1, xcs, zb, TcDI);
        // db (dt_low,B,C) = xcs @ xW[0:48]^T -> fp32 (both dirs)
        k_gemm_bf<<<dim3(Tc / 128, 1, 2), 256, 0, stream>>>(
            xcs, DI, TcDI, xW_bc2, (long long)48 * DI,
            db, (long long)Tc * 48, 48, nullptr, DI, 48, 0);
        // chunked scan (CH=64, CLEN=40), both dirs; p3 fuses z-gate -> yg in xcs
        k_scan_p1<<<(2 * Bc * CH * DI) / 256, 256, 0, stream>>>(
            xcs, db, dtW0, dtW1, dtb0, dtb1, Alog0, Alog1, Aflag_d, hS, csum, Bc);
        k_scan_p2<<<(2 * Bc * DI * DS) / 256, 256, 0, stream>>>(
            hS, csum, Alog0, Alog1, Bc);
        k_scan_p3<<<(2 * Bc * CH * DI) / 256, 256, 0, stream>>>(
            xcs, zb, db, dtW0, dtW1, dtb0, dtb1, Alog0, Alog1, Aflag_d, Dp0, Dp1, hS, Bc);
        // out_proj: dir0 -> mo = yg@outW^T + xn; dir1 -> mo1 (crev)
        k_gemm_bf<<<dim3(Tc / 128, DM / 128, 2), 256, 0, stream>>>(
            xcs, DI, TcDI, outW_bf2, (long long)DM * DI,
            moC, dsMo1, DM, xnC, DI, DM, 2);
    }

    // combined = rmsnorm(mo + mo1) -> comb_bf (xn_buf overlay)
    k_rmsnorm<<<BT / 4, 256, 0, stream>>>(mo, t_buf, norm2_w, nullptr, comb_bf, BT);
    // convd + bn + silu -> d_bf (mo overlay); TM=128 (B-reuse-heavy)
    k_conv3_bf<128><<<dim3(BT / 128, 2), 256, 0, stream>>>(comb_bf, 256, tb_bf, 256, Wdr,
                                                      alpha_d, beta_d, nullptr, d_bf, 256, 1, 0);
    // sp conv + pixel shuffle -> out; TM=64 (grid-starved at 320 blocks)
    k_conv3_bf<64><<<dim3(BT / 64, 1), 256, 0, stream>>>(d_bf, 256, nullptr, 0, Wspr,
                                                      nullptr, sp_b, out, nullptr, 128, 0, 1);
}